// Round 1
// baseline (13887.715 us; speedup 1.0000x reference)
//
#include <hip/hip_runtime.h>
#include <hip/hip_bf16.h>

#define BB 2
#define SS 2048
#define EE 1024
#define HH 16
#define DD 64
#define FF 4096
#define VV 32000
#define LL 2
#define BS (BB*SS)

#define NEG_HUGE (-3.402823466e+38f)

// ---------------------------------------------------------------------------
// last_start (forced at s=0): ls[b,s] = largest j<=s with (j==0 || tokens[j]==1)
// Serves both rel_pos (s - ls) and attention window [ls, s].
// ---------------------------------------------------------------------------
__global__ void lastart_kernel(const int* __restrict__ tokens, int* __restrict__ ls) {
  int b = threadIdx.x;
  if (b >= BB) return;
  int cur = 0;
  for (int s = 0; s < SS; ++s) {
    if (s > 0 && tokens[b*SS + s] == 1) cur = s;
    ls[b*SS + s] = cur;
  }
}

// x[b,s,:] = word_embed[tok] + pos_embed[s - ls]
__global__ __launch_bounds__(256) void embed_kernel(
    const int* __restrict__ tokens, const int* __restrict__ ls,
    const float* __restrict__ we, const float* __restrict__ pe,
    float* __restrict__ x) {
  int row = blockIdx.x;            // b*SS + s
  int s = row & (SS - 1);
  int tok = tokens[row];
  int rp = s - ls[row];
  const float4* w4 = (const float4*)(we + (size_t)tok * EE);
  const float4* p4 = (const float4*)(pe + (size_t)rp * EE);
  float4 a = w4[threadIdx.x];
  float4 b = p4[threadIdx.x];
  float4 o; o.x = a.x + b.x; o.y = a.y + b.y; o.z = a.z + b.z; o.w = a.w + b.w;
  ((float4*)(x + (size_t)row * EE))[threadIdx.x] = o;
}

// ---------------------------------------------------------------------------
// C[M,N] = A[M,K] @ W[N,K]^T (+bias)(+relu). fp32, 64x64 tile, 4x4 per thread.
// ---------------------------------------------------------------------------
template<bool BIAS, bool RELU>
__global__ __launch_bounds__(256) void gemm_bt(
    const float* __restrict__ A, const float* __restrict__ W,
    const float* __restrict__ bias, float* __restrict__ C, int N, int K) {
  __shared__ float As[16][72];   // [k][m], stride 72 floats = 288B (16B aligned rows)
  __shared__ float Bs[16][72];   // [k][n]
  const int t  = threadIdx.x;
  const int m0 = blockIdx.y * 64, n0 = blockIdx.x * 64;
  const int tm = t >> 4, tn = t & 15;     // 16x16 threads, 4x4 outputs each
  const int lr = t >> 2;                  // staging: row within tile (0..63)
  const int lc = (t & 3) * 4;             // staging: k offset (0,4,8,12)
  float acc[4][4] = {};
  const float* Ar = A + (size_t)(m0 + lr) * K + lc;
  const float* Wr = W + (size_t)(n0 + lr) * K + lc;
  for (int k0 = 0; k0 < K; k0 += 16) {
    float4 a = *(const float4*)(Ar + k0);
    float4 b = *(const float4*)(Wr + k0);
    __syncthreads();   // protect previous iteration's LDS reads
    As[lc+0][lr] = a.x; As[lc+1][lr] = a.y; As[lc+2][lr] = a.z; As[lc+3][lr] = a.w;
    Bs[lc+0][lr] = b.x; Bs[lc+1][lr] = b.y; Bs[lc+2][lr] = b.z; Bs[lc+3][lr] = b.w;
    __syncthreads();
#pragma unroll
    for (int kk = 0; kk < 16; ++kk) {
      float4 av = *(const float4*)(&As[kk][tm*4]);
      float4 bv = *(const float4*)(&Bs[kk][tn*4]);
      float aa[4] = {av.x, av.y, av.z, av.w};
      float bb[4] = {bv.x, bv.y, bv.z, bv.w};
#pragma unroll
      for (int i = 0; i < 4; ++i)
#pragma unroll
        for (int j = 0; j < 4; ++j) acc[i][j] = fmaf(aa[i], bb[j], acc[i][j]);
    }
  }
#pragma unroll
  for (int i = 0; i < 4; ++i) {
    float4 o;
    float* op = &o.x;
#pragma unroll
    for (int j = 0; j < 4; ++j) {
      float v = acc[i][j];
      if (BIAS) v += bias[n0 + tn*4 + j];
      if (RELU) v = fmaxf(v, 0.0f);
      op[j] = v;
    }
    *(float4*)(C + (size_t)(m0 + tm*4 + i) * N + n0 + tn*4) = o;
  }
}

// ---------------------------------------------------------------------------
// x = LN(y + x) * s + b    (row = 1024 elems, 256 threads)
// ---------------------------------------------------------------------------
__global__ __launch_bounds__(256) void ln_res_kernel(
    const float* __restrict__ y, float* __restrict__ x,
    const float* __restrict__ sc, const float* __restrict__ bs) {
  __shared__ float red[8];
  int row = blockIdx.x, t = threadIdx.x;
  const float4* y4 = (const float4*)(y + (size_t)row * EE);
  float4* x4 = (float4*)(x + (size_t)row * EE);
  float4 a = y4[t], c = x4[t];
  float v0 = a.x + c.x, v1 = a.y + c.y, v2 = a.z + c.z, v3 = a.w + c.w;
  float s = v0 + v1 + v2 + v3;
  float q = v0*v0 + v1*v1 + v2*v2 + v3*v3;
#pragma unroll
  for (int off = 32; off; off >>= 1) {
    s += __shfl_xor(s, off);
    q += __shfl_xor(q, off);
  }
  int w = t >> 6;
  if ((t & 63) == 0) { red[w] = s; red[4 + w] = q; }
  __syncthreads();
  s = red[0] + red[1] + red[2] + red[3];
  q = red[4] + red[5] + red[6] + red[7];
  float mean = s * (1.0f / EE);
  float var  = q * (1.0f / EE) - mean * mean;
  float r = 1.0f / sqrtf(var + 1e-6f);
  float4 ss = ((const float4*)sc)[t];
  float4 bb = ((const float4*)bs)[t];
  float4 o;
  o.x = (v0 - mean) * r * ss.x + bb.x;
  o.y = (v1 - mean) * r * ss.y + bb.y;
  o.z = (v2 - mean) * r * ss.z + bb.z;
  o.w = (v3 - mean) * r * ss.w + bb.w;
  x4[t] = o;
}

// ---------------------------------------------------------------------------
// Attention. qkv rows are [3][H][D] (c=0:K, c=1:Q, c=2:V). Block = one
// (b, h, 64-query tile); 8 waves x 8 queries. Online softmax, window [Lq, q].
// ---------------------------------------------------------------------------
__global__ __launch_bounds__(512) void attn_kernel(
    const float* __restrict__ qkv, const int* __restrict__ ls,
    float* __restrict__ out) {
  const int qt = blockIdx.x, h = blockIdx.y, b = blockIdx.z;
  __shared__ float Qt[64][65], Kt[64][65], Vt[64][65];
  const int t = threadIdx.x;
  const int w = t >> 6, lane = t & 63;
  const int r = t >> 3, c0 = (t & 7) * 8;     // staging: 8 floats per thread
  const size_t rs = 3 * EE;

  {  // stage Q tile
    const float* src = qkv + (size_t)(b*SS + qt*64 + r) * rs + EE + h*DD + c0;
#pragma unroll
    for (int i = 0; i < 2; ++i) {
      float4 v = *(const float4*)(src + i*4);
      Qt[r][c0+i*4+0] = v.x; Qt[r][c0+i*4+1] = v.y;
      Qt[r][c0+i*4+2] = v.z; Qt[r][c0+i*4+3] = v.w;
    }
  }

  float m_i[8], l_i[8], o_i[8];
  int Lq[8], qg[8];
#pragma unroll
  for (int i = 0; i < 8; ++i) {
    m_i[i] = NEG_HUGE; l_i[i] = 0.f; o_i[i] = 0.f;
    qg[i] = qt*64 + w*8 + i;
    Lq[i] = ls[b*SS + qg[i]];
  }

  for (int kt = 0; kt <= qt; ++kt) {
    __syncthreads();   // prev tile fully consumed (also covers Q staging)
    {  // stage K and V tiles
      const float* kf = qkv + (size_t)(b*SS + kt*64 + r) * rs + h*DD + c0;
      const float* vf = kf + 2*EE;
#pragma unroll
      for (int i = 0; i < 2; ++i) {
        float4 kv = *(const float4*)(kf + i*4);
        float4 vv = *(const float4*)(vf + i*4);
        Kt[r][c0+i*4+0] = kv.x; Kt[r][c0+i*4+1] = kv.y;
        Kt[r][c0+i*4+2] = kv.z; Kt[r][c0+i*4+3] = kv.w;
        Vt[r][c0+i*4+0] = vv.x; Vt[r][c0+i*4+1] = vv.y;
        Vt[r][c0+i*4+2] = vv.z; Vt[r][c0+i*4+3] = vv.w;
      }
    }
    __syncthreads();
    const int kkey = kt*64 + lane;
#pragma unroll
    for (int i = 0; i < 8; ++i) {
      const int qrow = w*8 + i;
      float scv = 0.f;
#pragma unroll
      for (int d = 0; d < 64; ++d) scv = fmaf(Qt[qrow][d], Kt[lane][d], scv);
      scv *= 0.125f;
      bool valid = (kkey <= qg[i]) && (kkey >= Lq[i]);
      scv = valid ? scv : NEG_HUGE;
      float mt = scv;
#pragma unroll
      for (int off = 32; off; off >>= 1) mt = fmaxf(mt, __shfl_xor(mt, off));
      float m_new = fmaxf(m_i[i], mt);
      if (m_new == NEG_HUGE) continue;      // tile fully masked, uniform branch
      float p = expf(scv - m_new);          // masked lanes underflow to 0
      float alpha = expf(m_i[i] - m_new);   // first tile: exp(-huge) = 0
      float psum = p;
#pragma unroll
      for (int off = 32; off; off >>= 1) psum += __shfl_xor(psum, off);
      l_i[i] = l_i[i] * alpha + psum;
      float o = o_i[i] * alpha;
#pragma unroll
      for (int k2 = 0; k2 < 64; ++k2)
        o = fmaf(__shfl(p, k2), Vt[k2][lane], o);
      o_i[i] = o;
      m_i[i] = m_new;
    }
  }
#pragma unroll
  for (int i = 0; i < 8; ++i)
    out[(size_t)(b*SS + qg[i]) * EE + h*DD + lane] = o_i[i] / l_i[i];
}

// ---------------------------------------------------------------------------
extern "C" void kernel_launch(void* const* d_in, const int* in_sizes, int n_in,
                              void* d_out, int out_size, void* d_ws, size_t ws_size,
                              hipStream_t stream) {
  const int*   tokens     = (const int*)  d_in[0];
  const float* word_embed = (const float*)d_in[1];
  const float* pos_embed  = (const float*)d_in[2];
  const float* unembed_b  = (const float*)d_in[3];
  const float* kqv_w      = (const float*)d_in[4];
  const float* wo_w       = (const float*)d_in[5];
  const float* up_w       = (const float*)d_in[6];
  const float* up_b       = (const float*)d_in[7];
  const float* down_w     = (const float*)d_in[8];
  const float* down_b     = (const float*)d_in[9];
  const float* ln1_s      = (const float*)d_in[10];
  const float* ln1_b      = (const float*)d_in[11];
  const float* ln2_s      = (const float*)d_in[12];
  const float* ln2_b      = (const float*)d_in[13];
  float* logits = (float*)d_out;

  // d_out (524 MB) doubles as scratch until the final unembed GEMM overwrites it.
  char* ob = (char*)d_out;
  float* qkv  = (float*)ob;                                // 48 MB (also t1 reuse)
  float* hbuf = (float*)(ob + (size_t)48  * 1024 * 1024);  // 64 MB
  float* t0   = (float*)(ob + (size_t)112 * 1024 * 1024);  // 16 MB
  // ws: only what must survive the final GEMM's writes to d_out.
  char* wsb = (char*)d_ws;
  int*   ls = (int*)wsb;                       // 16 KB
  float* x  = (float*)(wsb + 65536);           // 16 MB

  lastart_kernel<<<1, 64, 0, stream>>>(tokens, ls);
  embed_kernel<<<BS, 256, 0, stream>>>(tokens, ls, word_embed, pos_embed, x);

  for (int l = 0; l < LL; ++l) {
    gemm_bt<false,false><<<dim3(3*EE/64, BS/64), 256, 0, stream>>>(
        x, kqv_w + (size_t)l*3*EE*EE, nullptr, qkv, 3*EE, EE);
    attn_kernel<<<dim3(SS/64, HH, BB), 512, 0, stream>>>(qkv, ls, t0);
    gemm_bt<false,false><<<dim3(EE/64, BS/64), 256, 0, stream>>>(
        t0, wo_w + (size_t)l*EE*EE, nullptr, qkv, EE, EE);
    ln_res_kernel<<<BS, 256, 0, stream>>>(qkv, x, ln1_s + l*EE, ln1_b + l*EE);
    gemm_bt<true,true><<<dim3(FF/64, BS/64), 256, 0, stream>>>(
        x, up_w + (size_t)l*FF*EE, up_b + (size_t)l*FF, hbuf, FF, EE);
    gemm_bt<true,false><<<dim3(EE/64, BS/64), 256, 0, stream>>>(
        hbuf, down_w + (size_t)l*EE*FF, down_b + (size_t)l*EE, qkv, EE, FF);
    ln_res_kernel<<<BS, 256, 0, stream>>>(qkv, x, ln2_s + l*EE, ln2_b + l*EE);
  }

  gemm_bt<true,false><<<dim3(VV/64, BS/64), 256, 0, stream>>>(
      x, word_embed, unembed_b, logits, VV, EE);
}

// Round 2
// 7997.201 us; speedup vs baseline: 1.7366x; 1.7366x over previous
//
#include <hip/hip_runtime.h>
#include <hip/hip_bf16.h>

#define BB 2
#define SS 2048
#define EE 1024
#define HH 16
#define DD 64
#define FF 4096
#define VV 32000
#define LL 2
#define BS (BB*SS)

#define NEG_HUGE (-3.402823466e+38f)

typedef __attribute__((ext_vector_type(4))) float f32x4;
typedef __attribute__((ext_vector_type(8))) __bf16 bf16x8;

// ---------------------------------------------------------------------------
// last_start (forced at s=0): ls[b,s] = largest j<=s with (j==0 || tokens[j]==1)
// ---------------------------------------------------------------------------
__global__ void lastart_kernel(const int* __restrict__ tokens, int* __restrict__ ls) {
  int b = threadIdx.x;
  if (b >= BB) return;
  int cur = 0;
  for (int s = 0; s < SS; ++s) {
    if (s > 0 && tokens[b*SS + s] == 1) cur = s;
    ls[b*SS + s] = cur;
  }
}

// x[b,s,:] = word_embed[tok] + pos_embed[s - ls]
__global__ __launch_bounds__(256) void embed_kernel(
    const int* __restrict__ tokens, const int* __restrict__ ls,
    const float* __restrict__ we, const float* __restrict__ pe,
    float* __restrict__ x) {
  int row = blockIdx.x;            // b*SS + s
  int s = row & (SS - 1);
  int tok = tokens[row];
  int rp = s - ls[row];
  const float4* w4 = (const float4*)(we + (size_t)tok * EE);
  const float4* p4 = (const float4*)(pe + (size_t)rp * EE);
  float4 a = w4[threadIdx.x];
  float4 b = p4[threadIdx.x];
  float4 o; o.x = a.x + b.x; o.y = a.y + b.y; o.z = a.z + b.z; o.w = a.w + b.w;
  ((float4*)(x + (size_t)row * EE))[threadIdx.x] = o;
}

// ---------------------------------------------------------------------------
// C[M,N] = A[M,K] @ W[N,K]^T (+bias)(+relu).  fp32 in/out, bf16 MFMA compute.
// 128x128 tile, BK=32, 256 threads (4 waves, 2x2), 4x4 16x16x32 frags/wave.
// Reg-staging: load fp32, convert to bf16 in regs, ds_write_b128 contiguous.
// ---------------------------------------------------------------------------
__device__ inline bf16x8 to_bf8(float4 a, float4 b) {
  bf16x8 r;
  r[0] = (__bf16)a.x; r[1] = (__bf16)a.y; r[2] = (__bf16)a.z; r[3] = (__bf16)a.w;
  r[4] = (__bf16)b.x; r[5] = (__bf16)b.y; r[6] = (__bf16)b.z; r[7] = (__bf16)b.w;
  return r;
}

template<bool BIAS, bool RELU>
__global__ __launch_bounds__(256) void gemm_mfma(
    const float* __restrict__ A, const float* __restrict__ W,
    const float* __restrict__ bias, float* __restrict__ C, int N, int K) {
  __shared__ __bf16 As[128][32];   // 8 KB
  __shared__ __bf16 Bs[128][32];   // 8 KB
  const int t = threadIdx.x;
  const int m0 = blockIdx.y * 128, n0 = blockIdx.x * 128;
  const int lane = t & 63;
  const int wave = t >> 6;
  const int wm = (wave >> 1) * 64, wn = (wave & 1) * 64;
  const int fr = lane & 15;            // fragment row (A-M / B-N)
  const int fk = (lane >> 4) * 8;      // fragment k offset

  // staging: thread covers rows r0 (pass 0) and r1 (pass 1), 8 floats each.
  // LDS write address = t*16 bytes per pass -> fully contiguous, conflict-free.
  const int r0 = t >> 2;
  const int r1 = 64 + (t >> 2);
  const int kc = (t & 3) * 8;

  f32x4 acc[4][4] = {};

  const float* Ap0 = A + (size_t)(m0 + r0) * K + kc;
  const float* Ap1 = A + (size_t)(m0 + r1) * K + kc;
  const float* Wp0 = W + (size_t)(n0 + r0) * K + kc;
  const float* Wp1 = W + (size_t)(n0 + r1) * K + kc;

  for (int k0 = 0; k0 < K; k0 += 32) {
    float4 a0 = *(const float4*)(Ap0 + k0);
    float4 a1 = *(const float4*)(Ap0 + k0 + 4);
    float4 a2 = *(const float4*)(Ap1 + k0);
    float4 a3 = *(const float4*)(Ap1 + k0 + 4);
    float4 w0 = *(const float4*)(Wp0 + k0);
    float4 w1 = *(const float4*)(Wp0 + k0 + 4);
    float4 w2 = *(const float4*)(Wp1 + k0);
    float4 w3 = *(const float4*)(Wp1 + k0 + 4);
    __syncthreads();                       // previous iteration's reads done
    *(bf16x8*)&As[r0][kc] = to_bf8(a0, a1);
    *(bf16x8*)&As[r1][kc] = to_bf8(a2, a3);
    *(bf16x8*)&Bs[r0][kc] = to_bf8(w0, w1);
    *(bf16x8*)&Bs[r1][kc] = to_bf8(w2, w3);
    __syncthreads();
    bf16x8 af[4], bf[4];
#pragma unroll
    for (int i = 0; i < 4; ++i) af[i] = *(const bf16x8*)&As[wm + i*16 + fr][fk];
#pragma unroll
    for (int j = 0; j < 4; ++j) bf[j] = *(const bf16x8*)&Bs[wn + j*16 + fr][fk];
#pragma unroll
    for (int i = 0; i < 4; ++i)
#pragma unroll
      for (int j = 0; j < 4; ++j)
        acc[i][j] = __builtin_amdgcn_mfma_f32_16x16x32_bf16(af[i], bf[j], acc[i][j], 0, 0, 0);
  }

  // C/D layout: col = lane&15, row = (lane>>4)*4 + reg
  const int orow = m0 + wm + (lane >> 4) * 4;
  const int ocol = n0 + wn + fr;
#pragma unroll
  for (int i = 0; i < 4; ++i)
#pragma unroll
    for (int j = 0; j < 4; ++j) {
      const int col = ocol + j * 16;
      const float bv = BIAS ? bias[col] : 0.0f;
#pragma unroll
      for (int r = 0; r < 4; ++r) {
        float v = acc[i][j][r] + bv;
        if (RELU) v = fmaxf(v, 0.0f);
        C[(size_t)(orow + i * 16 + r) * N + col] = v;
      }
    }
}

// ---------------------------------------------------------------------------
// x = LN(y + x) * s + b    (row = 1024 elems, 256 threads)
// ---------------------------------------------------------------------------
__global__ __launch_bounds__(256) void ln_res_kernel(
    const float* __restrict__ y, float* __restrict__ x,
    const float* __restrict__ sc, const float* __restrict__ bs) {
  __shared__ float red[8];
  int row = blockIdx.x, t = threadIdx.x;
  const float4* y4 = (const float4*)(y + (size_t)row * EE);
  float4* x4 = (float4*)(x + (size_t)row * EE);
  float4 a = y4[t], c = x4[t];
  float v0 = a.x + c.x, v1 = a.y + c.y, v2 = a.z + c.z, v3 = a.w + c.w;
  float s = v0 + v1 + v2 + v3;
  float q = v0*v0 + v1*v1 + v2*v2 + v3*v3;
#pragma unroll
  for (int off = 32; off; off >>= 1) {
    s += __shfl_xor(s, off);
    q += __shfl_xor(q, off);
  }
  int w = t >> 6;
  if ((t & 63) == 0) { red[w] = s; red[4 + w] = q; }
  __syncthreads();
  s = red[0] + red[1] + red[2] + red[3];
  q = red[4] + red[5] + red[6] + red[7];
  float mean = s * (1.0f / EE);
  float var  = q * (1.0f / EE) - mean * mean;
  float r = 1.0f / sqrtf(var + 1e-6f);
  float4 ss = ((const float4*)sc)[t];
  float4 bb = ((const float4*)bs)[t];
  float4 o;
  o.x = (v0 - mean) * r * ss.x + bb.x;
  o.y = (v1 - mean) * r * ss.y + bb.y;
  o.z = (v2 - mean) * r * ss.z + bb.z;
  o.w = (v3 - mean) * r * ss.w + bb.w;
  x4[t] = o;
}

// ---------------------------------------------------------------------------
// Attention. qkv rows are [3][H][D] (c=0:K, c=1:Q, c=2:V). Block = one
// (b, h, 64-query tile); 8 waves x 8 queries. Online softmax, window [Lq, q].
// ---------------------------------------------------------------------------
__global__ __launch_bounds__(512) void attn_kernel(
    const float* __restrict__ qkv, const int* __restrict__ ls,
    float* __restrict__ out) {
  const int qt = blockIdx.x, h = blockIdx.y, b = blockIdx.z;
  __shared__ float Qt[64][65], Kt[64][65], Vt[64][65];
  const int t = threadIdx.x;
  const int w = t >> 6, lane = t & 63;
  const int r = t >> 3, c0 = (t & 7) * 8;
  const size_t rs = 3 * EE;

  {  // stage Q tile
    const float* src = qkv + (size_t)(b*SS + qt*64 + r) * rs + EE + h*DD + c0;
#pragma unroll
    for (int i = 0; i < 2; ++i) {
      float4 v = *(const float4*)(src + i*4);
      Qt[r][c0+i*4+0] = v.x; Qt[r][c0+i*4+1] = v.y;
      Qt[r][c0+i*4+2] = v.z; Qt[r][c0+i*4+3] = v.w;
    }
  }

  float m_i[8], l_i[8], o_i[8];
  int Lq[8], qg[8];
#pragma unroll
  for (int i = 0; i < 8; ++i) {
    m_i[i] = NEG_HUGE; l_i[i] = 0.f; o_i[i] = 0.f;
    qg[i] = qt*64 + w*8 + i;
    Lq[i] = ls[b*SS + qg[i]];
  }

  for (int kt = 0; kt <= qt; ++kt) {
    __syncthreads();
    {  // stage K and V tiles
      const float* kf = qkv + (size_t)(b*SS + kt*64 + r) * rs + h*DD + c0;
      const float* vf = kf + 2*EE;
#pragma unroll
      for (int i = 0; i < 2; ++i) {
        float4 kv = *(const float4*)(kf + i*4);
        float4 vv = *(const float4*)(vf + i*4);
        Kt[r][c0+i*4+0] = kv.x; Kt[r][c0+i*4+1] = kv.y;
        Kt[r][c0+i*4+2] = kv.z; Kt[r][c0+i*4+3] = kv.w;
        Vt[r][c0+i*4+0] = vv.x; Vt[r][c0+i*4+1] = vv.y;
        Vt[r][c0+i*4+2] = vv.z; Vt[r][c0+i*4+3] = vv.w;
      }
    }
    __syncthreads();
    const int kkey = kt*64 + lane;
#pragma unroll
    for (int i = 0; i < 8; ++i) {
      const int qrow = w*8 + i;
      float scv = 0.f;
#pragma unroll
      for (int d = 0; d < 64; ++d) scv = fmaf(Qt[qrow][d], Kt[lane][d], scv);
      scv *= 0.125f;
      bool valid = (kkey <= qg[i]) && (kkey >= Lq[i]);
      scv = valid ? scv : NEG_HUGE;
      float mt = scv;
#pragma unroll
      for (int off = 32; off; off >>= 1) mt = fmaxf(mt, __shfl_xor(mt, off));
      float m_new = fmaxf(m_i[i], mt);
      if (m_new == NEG_HUGE) continue;
      float p = expf(scv - m_new);
      float alpha = expf(m_i[i] - m_new);
      float psum = p;
#pragma unroll
      for (int off = 32; off; off >>= 1) psum += __shfl_xor(psum, off);
      l_i[i] = l_i[i] * alpha + psum;
      float o = o_i[i] * alpha;
#pragma unroll
      for (int k2 = 0; k2 < 64; ++k2)
        o = fmaf(__shfl(p, k2), Vt[k2][lane], o);
      o_i[i] = o;
      m_i[i] = m_new;
    }
  }
#pragma unroll
  for (int i = 0; i < 8; ++i)
    out[(size_t)(b*SS + qg[i]) * EE + h*DD + lane] = o_i[i] / l_i[i];
}

// ---------------------------------------------------------------------------
extern "C" void kernel_launch(void* const* d_in, const int* in_sizes, int n_in,
                              void* d_out, int out_size, void* d_ws, size_t ws_size,
                              hipStream_t stream) {
  const int*   tokens     = (const int*)  d_in[0];
  const float* word_embed = (const float*)d_in[1];
  const float* pos_embed  = (const float*)d_in[2];
  const float* unembed_b  = (const float*)d_in[3];
  const float* kqv_w      = (const float*)d_in[4];
  const float* wo_w       = (const float*)d_in[5];
  const float* up_w       = (const float*)d_in[6];
  const float* up_b       = (const float*)d_in[7];
  const float* down_w     = (const float*)d_in[8];
  const float* down_b     = (const float*)d_in[9];
  const float* ln1_s      = (const float*)d_in[10];
  const float* ln1_b      = (const float*)d_in[11];
  const float* ln2_s      = (const float*)d_in[12];
  const float* ln2_b      = (const float*)d_in[13];
  float* logits = (float*)d_out;

  // d_out (524 MB) doubles as scratch until the final unembed GEMM overwrites it.
  char* ob = (char*)d_out;
  float* qkv  = (float*)ob;                                // 48 MB
  float* hbuf = (float*)(ob + (size_t)48  * 1024 * 1024);  // 64 MB
  float* t0   = (float*)(ob + (size_t)112 * 1024 * 1024);  // 16 MB
  // ws: only what must survive the final GEMM's writes to d_out.
  char* wsb = (char*)d_ws;
  int*   ls = (int*)wsb;                       // 16 KB
  float* x  = (float*)(wsb + 65536);           // 16 MB

  lastart_kernel<<<1, 64, 0, stream>>>(tokens, ls);
  embed_kernel<<<BS, 256, 0, stream>>>(tokens, ls, word_embed, pos_embed, x);

  for (int l = 0; l < LL; ++l) {
    gemm_mfma<false,false><<<dim3(3*EE/128, BS/128), 256, 0, stream>>>(
        x, kqv_w + (size_t)l*3*EE*EE, nullptr, qkv, 3*EE, EE);
    attn_kernel<<<dim3(SS/64, HH, BB), 512, 0, stream>>>(qkv, ls, t0);
    gemm_mfma<false,false><<<dim3(EE/128, BS/128), 256, 0, stream>>>(
        t0, wo_w + (size_t)l*EE*EE, nullptr, qkv, EE, EE);
    ln_res_kernel<<<BS, 256, 0, stream>>>(qkv, x, ln1_s + l*EE, ln1_b + l*EE);
    gemm_mfma<true,true><<<dim3(FF/128, BS/128), 256, 0, stream>>>(
        x, up_w + (size_t)l*FF*EE, up_b + (size_t)l*FF, hbuf, FF, EE);
    gemm_mfma<true,false><<<dim3(EE/128, BS/128), 256, 0, stream>>>(
        hbuf, down_w + (size_t)l*EE*FF, down_b + (size_t)l*EE, qkv, EE, FF);
    ln_res_kernel<<<BS, 256, 0, stream>>>(qkv, x, ln2_s + l*EE, ln2_b + l*EE);
  }

  gemm_mfma<true,false><<<dim3(VV/128, BS/128), 256, 0, stream>>>(
      x, word_embed, unembed_b, logits, VV, EE);
}

// Round 3
// 1702.159 us; speedup vs baseline: 8.1589x; 4.6983x over previous
//
#include <hip/hip_runtime.h>
#include <hip/hip_bf16.h>

#define BB 2
#define SS 2048
#define EE 1024
#define HH 16
#define DD 64
#define FF 4096
#define VV 32000
#define LL 2
#define BS (BB*SS)

#define NEG_HUGE (-3.402823466e+38f)

typedef __attribute__((ext_vector_type(4)))  float  f32x4;
typedef __attribute__((ext_vector_type(16))) float  f32x16;
typedef __attribute__((ext_vector_type(8)))  __bf16 bf16x8;
typedef __attribute__((ext_vector_type(4)))  __bf16 bf16x4;

// ---------------------------------------------------------------------------
// last_start (forced at s=0)
// ---------------------------------------------------------------------------
__global__ void lastart_kernel(const int* __restrict__ tokens, int* __restrict__ ls) {
  int b = threadIdx.x;
  if (b >= BB) return;
  int cur = 0;
  for (int s = 0; s < SS; ++s) {
    if (s > 0 && tokens[b*SS + s] == 1) cur = s;
    ls[b*SS + s] = cur;
  }
}

__global__ __launch_bounds__(256) void embed_kernel(
    const int* __restrict__ tokens, const int* __restrict__ ls,
    const float* __restrict__ we, const float* __restrict__ pe,
    float* __restrict__ x) {
  int row = blockIdx.x;
  int s = row & (SS - 1);
  int tok = tokens[row];
  int rp = s - ls[row];
  const float4* w4 = (const float4*)(we + (size_t)tok * EE);
  const float4* p4 = (const float4*)(pe + (size_t)rp * EE);
  float4 a = w4[threadIdx.x];
  float4 b = p4[threadIdx.x];
  float4 o; o.x = a.x + b.x; o.y = a.y + b.y; o.z = a.z + b.z; o.w = a.w + b.w;
  ((float4*)(x + (size_t)row * EE))[threadIdx.x] = o;
}

// ---------------------------------------------------------------------------
// GEMM: C[M,N] = A[M,K] @ W[N,K]^T (+bias)(+relu). bf16 MFMA, fp32 I/O.
// ---------------------------------------------------------------------------
__device__ inline bf16x8 to_bf8(float4 a, float4 b) {
  bf16x8 r;
  r[0] = (__bf16)a.x; r[1] = (__bf16)a.y; r[2] = (__bf16)a.z; r[3] = (__bf16)a.w;
  r[4] = (__bf16)b.x; r[5] = (__bf16)b.y; r[6] = (__bf16)b.z; r[7] = (__bf16)b.w;
  return r;
}

template<bool BIAS, bool RELU>
__global__ __launch_bounds__(256) void gemm_mfma(
    const float* __restrict__ A, const float* __restrict__ W,
    const float* __restrict__ bias, float* __restrict__ C, int N, int K) {
  __shared__ __bf16 As[128][32];
  __shared__ __bf16 Bs[128][32];
  const int t = threadIdx.x;
  const int m0 = blockIdx.y * 128, n0 = blockIdx.x * 128;
  const int lane = t & 63;
  const int wave = t >> 6;
  const int wm = (wave >> 1) * 64, wn = (wave & 1) * 64;
  const int fr = lane & 15;
  const int fk = (lane >> 4) * 8;
  const int r0 = t >> 2;
  const int r1 = 64 + (t >> 2);
  const int kc = (t & 3) * 8;

  f32x4 acc[4][4] = {};

  const float* Ap0 = A + (size_t)(m0 + r0) * K + kc;
  const float* Ap1 = A + (size_t)(m0 + r1) * K + kc;
  const float* Wp0 = W + (size_t)(n0 + r0) * K + kc;
  const float* Wp1 = W + (size_t)(n0 + r1) * K + kc;

  for (int k0 = 0; k0 < K; k0 += 32) {
    float4 a0 = *(const float4*)(Ap0 + k0);
    float4 a1 = *(const float4*)(Ap0 + k0 + 4);
    float4 a2 = *(const float4*)(Ap1 + k0);
    float4 a3 = *(const float4*)(Ap1 + k0 + 4);
    float4 w0 = *(const float4*)(Wp0 + k0);
    float4 w1 = *(const float4*)(Wp0 + k0 + 4);
    float4 w2 = *(const float4*)(Wp1 + k0);
    float4 w3 = *(const float4*)(Wp1 + k0 + 4);
    __syncthreads();
    *(bf16x8*)&As[r0][kc] = to_bf8(a0, a1);
    *(bf16x8*)&As[r1][kc] = to_bf8(a2, a3);
    *(bf16x8*)&Bs[r0][kc] = to_bf8(w0, w1);
    *(bf16x8*)&Bs[r1][kc] = to_bf8(w2, w3);
    __syncthreads();
    bf16x8 af[4], bf[4];
#pragma unroll
    for (int i = 0; i < 4; ++i) af[i] = *(const bf16x8*)&As[wm + i*16 + fr][fk];
#pragma unroll
    for (int j = 0; j < 4; ++j) bf[j] = *(const bf16x8*)&Bs[wn + j*16 + fr][fk];
#pragma unroll
    for (int i = 0; i < 4; ++i)
#pragma unroll
      for (int j = 0; j < 4; ++j)
        acc[i][j] = __builtin_amdgcn_mfma_f32_16x16x32_bf16(af[i], bf[j], acc[i][j], 0, 0, 0);
  }

  const int orow = m0 + wm + (lane >> 4) * 4;
  const int ocol = n0 + wn + fr;
#pragma unroll
  for (int i = 0; i < 4; ++i)
#pragma unroll
    for (int j = 0; j < 4; ++j) {
      const int col = ocol + j * 16;
      const float bv = BIAS ? bias[col] : 0.0f;
#pragma unroll
      for (int r = 0; r < 4; ++r) {
        float v = acc[i][j][r] + bv;
        if (RELU) v = fmaxf(v, 0.0f);
        C[(size_t)(orow + i * 16 + r) * N + col] = v;
      }
    }
}

// ---------------------------------------------------------------------------
// x = LN(y + x) * s + b
// ---------------------------------------------------------------------------
__global__ __launch_bounds__(256) void ln_res_kernel(
    const float* __restrict__ y, float* __restrict__ x,
    const float* __restrict__ sc, const float* __restrict__ bs) {
  __shared__ float red[8];
  int row = blockIdx.x, t = threadIdx.x;
  const float4* y4 = (const float4*)(y + (size_t)row * EE);
  float4* x4 = (float4*)(x + (size_t)row * EE);
  float4 a = y4[t], c = x4[t];
  float v0 = a.x + c.x, v1 = a.y + c.y, v2 = a.z + c.z, v3 = a.w + c.w;
  float s = v0 + v1 + v2 + v3;
  float q = v0*v0 + v1*v1 + v2*v2 + v3*v3;
#pragma unroll
  for (int off = 32; off; off >>= 1) {
    s += __shfl_xor(s, off);
    q += __shfl_xor(q, off);
  }
  int w = t >> 6;
  if ((t & 63) == 0) { red[w] = s; red[4 + w] = q; }
  __syncthreads();
  s = red[0] + red[1] + red[2] + red[3];
  q = red[4] + red[5] + red[6] + red[7];
  float mean = s * (1.0f / EE);
  float var  = q * (1.0f / EE) - mean * mean;
  float r = 1.0f / sqrtf(var + 1e-6f);
  float4 ss = ((const float4*)sc)[t];
  float4 bb = ((const float4*)bs)[t];
  float4 o;
  o.x = (v0 - mean) * r * ss.x + bb.x;
  o.y = (v1 - mean) * r * ss.y + bb.y;
  o.z = (v2 - mean) * r * ss.z + bb.z;
  o.w = (v3 - mean) * r * ss.w + bb.w;
  x4[t] = o;
}

// ---------------------------------------------------------------------------
// MFMA flash attention (swapped-operand 32x32x16 structure).
// Block: 256 thr = 4 waves, 128-query tile; wave owns 32 queries (q = lane&31).
// S^T = mfma(K, Q) -> lane holds 32 key-scores for ONE query -> scalar online
// softmax state per lane. P -> per-wave LDS [q][key]. O^T = mfma(V^T, P) with
// V transposed+rotated in LDS. Epilogue: O^T -> LDS -> coalesced writes.
// ---------------------------------------------------------------------------
__global__ __launch_bounds__(256) void attn_mfma(
    const float* __restrict__ qkv, const int* __restrict__ ls,
    float* __restrict__ out) {
  const int qt = 15 - blockIdx.x;          // descending: long blocks first
  const int h = blockIdx.y, b = blockIdx.z;
  __shared__ f32x4 lds4[2304];             // 36864 B
  char* lds = (char*)lds4;
  __bf16* Ks = (__bf16*)lds;               // [64][72] = 9216 B
  __bf16* Vs = (__bf16*)(lds + 9216);      // [64][72] transposed (d-major)
  __shared__ int redmin[4];
  const int t = threadIdx.x, w = t >> 6, l = t & 63;
  __bf16* Pq = (__bf16*)(lds + 18432 + w * 4608);  // [32][72] per wave
  const int r = l & 31, hi = l >> 5;
  const int qb = qt * 128, qw = qb + w * 32, qg = qw + r;
  const int Lq = ls[b*SS + qg];

  {  // block-wide min(Lq) -> ktmin
    int mn = Lq;
#pragma unroll
    for (int off = 1; off < 64; off <<= 1) mn = min(mn, __shfl_xor(mn, off));
    if (l == 0) redmin[w] = mn;
  }

  // Q fragments (B-operand): lane holds Q[q = r][d = 16*ds + 8*hi + i]
  bf16x8 qf[4];
  {
    const float* qrow = qkv + (size_t)(b*SS + qg) * 3*EE + EE + h*DD + 8*hi;
#pragma unroll
    for (int ds = 0; ds < 4; ++ds) {
      float4 x0 = *(const float4*)(qrow + 16*ds);
      float4 x1 = *(const float4*)(qrow + 16*ds + 4);
      qf[ds] = to_bf8(x0, x1);
    }
  }
  __syncthreads();
  const int ktmin = min(min(redmin[0], redmin[1]), min(redmin[2], redmin[3])) >> 6;
  const int ktmax = 2*qt + 1;

  f32x16 oacc[2] = {};
  float m_r = NEG_HUGE, lsum = 0.0f;

  for (int kt = ktmin; kt <= ktmax; ++kt) {
    __syncthreads();   // previous tile fully consumed
    {  // cooperative staging: K rows + transposed V
      const int kr = t >> 2, c0 = (t & 3) * 16;
      const float* kg = qkv + (size_t)(b*SS + kt*64 + kr) * 3*EE + h*DD + c0;
      const float* vg = kg + 2*EE;
      float4 k0 = *(const float4*)(kg);
      float4 k1 = *(const float4*)(kg + 4);
      float4 k2 = *(const float4*)(kg + 8);
      float4 k3 = *(const float4*)(kg + 12);
      float4 v0 = *(const float4*)(vg);
      float4 v1 = *(const float4*)(vg + 4);
      float4 v2 = *(const float4*)(vg + 8);
      float4 v3 = *(const float4*)(vg + 12);
      *(bf16x8*)&Ks[kr*72 + c0]     = to_bf8(k0, k1);
      *(bf16x8*)&Ks[kr*72 + c0 + 8] = to_bf8(k2, k3);
      const int vc = (kr + 8*(t & 3)) & 63;   // rotation = 8*((d>>4)&3), d>>4 = t&3
      float vv[16] = {v0.x,v0.y,v0.z,v0.w, v1.x,v1.y,v1.z,v1.w,
                      v2.x,v2.y,v2.z,v2.w, v3.x,v3.y,v3.z,v3.w};
#pragma unroll
      for (int j = 0; j < 16; ++j) Vs[(c0 + j)*72 + vc] = (__bf16)vv[j];
    }
    __syncthreads();

    // which 32-key / 16-key sub-tiles are causally live for this wave
    bool act0 = (kt*64)      <= (qw + 31);
    bool act1 = (kt*64 + 32) <= (qw + 31);
    if (!act0) continue;                      // wave-uniform: tile fully future

    // S^T = K . Q^T
    f32x16 st[2];
    st[0] = (f32x16){};
    st[1] = (f32x16){};
#pragma unroll
    for (int ds = 0; ds < 4; ++ds) {
      bf16x8 kf = *(const bf16x8*)&Ks[(r)*72 + 16*ds + 8*hi];
      st[0] = __builtin_amdgcn_mfma_f32_32x32x16_bf16(kf, qf[ds], st[0], 0, 0, 0);
    }
    if (act1) {
#pragma unroll
      for (int ds = 0; ds < 4; ++ds) {
        bf16x8 kf = *(const bf16x8*)&Ks[(32 + r)*72 + 16*ds + 8*hi];
        st[1] = __builtin_amdgcn_mfma_f32_32x32x16_bf16(kf, qf[ds], st[1], 0, 0, 0);
      }
    }

    // mask + row max (all in-lane; lane's query col = r, partner l^32 has
    // the complementary key halves of the SAME query)
    float tmax = NEG_HUGE;
#pragma unroll
    for (int kt2 = 0; kt2 < 2; ++kt2) {
#pragma unroll
      for (int reg = 0; reg < 16; ++reg) {
        const int key = kt*64 + 32*kt2 + (reg & 3) + 8*(reg >> 2) + 4*hi;
        float s = (kt2 == 0 || act1) ? st[kt2][reg] * 0.125f : NEG_HUGE;
        const bool valid = (key >= Lq) && (key <= qg);
        s = valid ? s : NEG_HUGE;
        st[kt2][reg] = s;
        tmax = fmaxf(tmax, s);
      }
    }
    tmax = fmaxf(tmax, __shfl_xor(tmax, 32));
    const float m_new = fmaxf(m_r, tmax);
    const float alpha = __expf(m_r - m_new);
    m_r = m_new;

    // P = exp(S - m), write per-wave LDS P[q][key] (b64, 4 consecutive keys)
    float psum = 0.0f;
#pragma unroll
    for (int kt2 = 0; kt2 < 2; ++kt2) {
#pragma unroll
      for (int g2 = 0; g2 < 4; ++g2) {
        bf16x4 pk;
#pragma unroll
        for (int j = 0; j < 4; ++j) {
          float p = __expf(st[kt2][g2*4 + j] - m_new);
          psum += p;
          pk[j] = (__bf16)p;
        }
        *(bf16x4*)&Pq[r*72 + 32*kt2 + 8*g2 + 4*hi] = pk;
      }
    }
    psum += __shfl_xor(psum, 32);
    lsum = lsum * alpha + psum;
    oacc[0] *= alpha;
    oacc[1] *= alpha;

    // O^T += V^T . P^T  (A = V^T from transposed Vs, B = P rows)
#pragma unroll
    for (int ks = 0; ks < 4; ++ks) {
      if (kt*64 + 16*ks > qw + 31) continue;   // wave-uniform causal skip
      bf16x8 pf = *(const bf16x8*)&Pq[r*72 + 16*ks + 8*hi];
#pragma unroll
      for (int mt = 0; mt < 2; ++mt) {
        const int d = 32*mt + r;
        const int vcol = (16*ks + 8*hi + 8*((d >> 4) & 3)) & 63;
        bf16x8 vf = *(const bf16x8*)&Vs[d*72 + vcol];
        oacc[mt] = __builtin_amdgcn_mfma_f32_32x32x16_bf16(vf, pf, oacc[mt], 0, 0, 0);
      }
    }
  }

  // epilogue: O^T -> LDS transpose -> coalesced global write
  __syncthreads();
  float* Ot = (float*)(lds + w * 8448);        // [64][33] f32 per wave
  const float rinv = 1.0f / lsum;
#pragma unroll
  for (int mt = 0; mt < 2; ++mt)
#pragma unroll
    for (int reg = 0; reg < 16; ++reg) {
      const int d = 32*mt + (reg & 3) + 8*(reg >> 2) + 4*hi;
      Ot[d*33 + r] = oacc[mt][reg] * rinv;
    }
  __syncthreads();
  const int qr0 = l >> 4, dc = (l & 15) * 4;
#pragma unroll
  for (int it = 0; it < 8; ++it) {
    const int qr = qr0 + 4*it;
    float4 o;
    o.x = Ot[(dc+0)*33 + qr];
    o.y = Ot[(dc+1)*33 + qr];
    o.z = Ot[(dc+2)*33 + qr];
    o.w = Ot[(dc+3)*33 + qr];
    *(float4*)(out + (size_t)(b*SS + qw + qr) * EE + h*DD + dc) = o;
  }
}

// ---------------------------------------------------------------------------
extern "C" void kernel_launch(void* const* d_in, const int* in_sizes, int n_in,
                              void* d_out, int out_size, void* d_ws, size_t ws_size,
                              hipStream_t stream) {
  const int*   tokens     = (const int*)  d_in[0];
  const float* word_embed = (const float*)d_in[1];
  const float* pos_embed  = (const float*)d_in[2];
  const float* unembed_b  = (const float*)d_in[3];
  const float* kqv_w      = (const float*)d_in[4];
  const float* wo_w       = (const float*)d_in[5];
  const float* up_w       = (const float*)d_in[6];
  const float* up_b       = (const float*)d_in[7];
  const float* down_w     = (const float*)d_in[8];
  const float* down_b     = (const float*)d_in[9];
  const float* ln1_s      = (const float*)d_in[10];
  const float* ln1_b      = (const float*)d_in[11];
  const float* ln2_s      = (const float*)d_in[12];
  const float* ln2_b      = (const float*)d_in[13];
  float* logits = (float*)d_out;

  char* ob = (char*)d_out;
  float* qkv  = (float*)ob;                                // 48 MB
  float* hbuf = (float*)(ob + (size_t)48  * 1024 * 1024);  // 64 MB
  float* t0   = (float*)(ob + (size_t)112 * 1024 * 1024);  // 16 MB
  char* wsb = (char*)d_ws;
  int*   ls = (int*)wsb;                       // 16 KB
  float* x  = (float*)(wsb + 65536);           // 16 MB

  lastart_kernel<<<1, 64, 0, stream>>>(tokens, ls);
  embed_kernel<<<BS, 256, 0, stream>>>(tokens, ls, word_embed, pos_embed, x);

  for (int l = 0; l < LL; ++l) {
    gemm_mfma<false,false><<<dim3(3*EE/128, BS/128), 256, 0, stream>>>(
        x, kqv_w + (size_t)l*3*EE*EE, nullptr, qkv, 3*EE, EE);
    attn_mfma<<<dim3(16, HH, BB), 256, 0, stream>>>(qkv, ls, t0);
    gemm_mfma<false,false><<<dim3(EE/128, BS/128), 256, 0, stream>>>(
        t0, wo_w + (size_t)l*EE*EE, nullptr, qkv, EE, EE);
    ln_res_kernel<<<BS, 256, 0, stream>>>(qkv, x, ln1_s + l*EE, ln1_b + l*EE);
    gemm_mfma<true,true><<<dim3(FF/128, BS/128), 256, 0, stream>>>(
        x, up_w + (size_t)l*FF*EE, up_b + (size_t)l*FF, hbuf, FF, EE);
    gemm_mfma<true,false><<<dim3(EE/128, BS/128), 256, 0, stream>>>(
        hbuf, down_w + (size_t)l*EE*FF, down_b + (size_t)l*EE, qkv, EE, FF);
    ln_res_kernel<<<BS, 256, 0, stream>>>(qkv, x, ln2_s + l*EE, ln2_b + l*EE);
  }

  gemm_mfma<true,false><<<dim3(VV/128, BS/128), 256, 0, stream>>>(
      x, word_embed, unembed_b, logits, VV, EE);
}

// Round 4
// 1308.759 us; speedup vs baseline: 10.6114x; 1.3006x over previous
//
#include <hip/hip_runtime.h>
#include <hip/hip_bf16.h>

#define BB 2
#define SS 2048
#define EE 1024
#define HH 16
#define DD 64
#define FF 4096
#define VV 32000
#define LL 2
#define BS (BB*SS)

#define NEG_HUGE (-3.402823466e+38f)

typedef __attribute__((ext_vector_type(4)))  float  f32x4;
typedef __attribute__((ext_vector_type(16))) float  f32x16;
typedef __attribute__((ext_vector_type(8)))  __bf16 bf16x8;
typedef __attribute__((ext_vector_type(4)))  __bf16 bf16x4;

__device__ inline bf16x8 to_bf8(float4 a, float4 b) {
  bf16x8 r;
  r[0] = (__bf16)a.x; r[1] = (__bf16)a.y; r[2] = (__bf16)a.z; r[3] = (__bf16)a.w;
  r[4] = (__bf16)b.x; r[5] = (__bf16)b.y; r[6] = (__bf16)b.z; r[7] = (__bf16)b.w;
  return r;
}

typedef const unsigned int __attribute__((address_space(1)))* gptr_t;
typedef unsigned int __attribute__((address_space(3)))* lptr_t;
__device__ inline void gload16(const void* g, void* l) {
  __builtin_amdgcn_global_load_lds((gptr_t)g, (lptr_t)l, 16, 0, 0);
}

// ---------------------------------------------------------------------------
__global__ void lastart_kernel(const int* __restrict__ tokens, int* __restrict__ ls) {
  int b = threadIdx.x;
  if (b >= BB) return;
  int cur = 0;
  for (int s = 0; s < SS; ++s) {
    if (s > 0 && tokens[b*SS + s] == 1) cur = s;
    ls[b*SS + s] = cur;
  }
}

__global__ __launch_bounds__(256) void embed_kernel(
    const int* __restrict__ tokens, const int* __restrict__ ls,
    const float* __restrict__ we, const float* __restrict__ pe,
    float* __restrict__ x, __bf16* __restrict__ xb) {
  int row = blockIdx.x;
  int s = row & (SS - 1);
  int tok = tokens[row];
  int rp = s - ls[row];
  const float4* w4 = (const float4*)(we + (size_t)tok * EE);
  const float4* p4 = (const float4*)(pe + (size_t)rp * EE);
  float4 a = w4[threadIdx.x];
  float4 b = p4[threadIdx.x];
  float4 o; o.x = a.x + b.x; o.y = a.y + b.y; o.z = a.z + b.z; o.w = a.w + b.w;
  ((float4*)(x + (size_t)row * EE))[threadIdx.x] = o;
  bf16x4 ob4;
  ob4[0] = (__bf16)o.x; ob4[1] = (__bf16)o.y; ob4[2] = (__bf16)o.z; ob4[3] = (__bf16)o.w;
  *(bf16x4*)(xb + (size_t)row * EE + threadIdx.x * 4) = ob4;
}

// ---------------------------------------------------------------------------
__global__ __launch_bounds__(256) void cvt_bf16_kernel(
    const float* __restrict__ src, __bf16* __restrict__ dst, int n) {
  int i = (blockIdx.x * 256 + threadIdx.x) * 8;
  if (i + 8 > n) return;
  float4 a = *(const float4*)(src + i);
  float4 b = *(const float4*)(src + i + 4);
  *(bf16x8*)(dst + i) = to_bf8(a, b);
}

// ---------------------------------------------------------------------------
// GEMM: C[M,N] = A[M,K] @ W[N,K]^T (+bias)(+relu).
// A bf16 staged via global_load_lds width-16 (m97 structure); W bf16 same, or
// fp32 reg-staged+cvt when WBF16=false. 128x128 tile, BK=32, 4 waves 2x2,
// 4x4 mfma_f32_16x16x32_bf16 per wave. blockIdx.x walks M (W-strip L2 reuse).
// ---------------------------------------------------------------------------
template<bool WBF16, bool BIAS, bool RELU, bool OUTBF16>
__global__ __launch_bounds__(256) void gemm_fast(
    const __bf16* __restrict__ A, const void* __restrict__ Wv,
    const float* __restrict__ bias, void* __restrict__ Cv, int N, int K) {
  __shared__ __bf16 As[128][32];
  __shared__ __bf16 Bs[128][32];
  const int t = threadIdx.x;
  const int m0 = blockIdx.x * 128, n0 = blockIdx.y * 128;
  const int l = t & 63, w = t >> 6;
  const int wm = (w >> 1) * 64, wn = (w & 1) * 64;
  const int fr = l & 15, fk = (l >> 4) * 8;
  const int crow = l >> 2, ccol = (l & 3) * 8;     // gload: row-in-chunk, col
  const int wrow = t >> 1, wcol = (t & 1) * 16;    // fp32-W staging coords

  const __bf16* Wb = (const __bf16*)Wv;
  const float*  Wf = (const float*)Wv;

  f32x4 acc[4][4] = {};

  for (int k0 = 0; k0 < K; k0 += 32) {
    float4 wf0, wf1, wf2, wf3;
    if (!WBF16) {
      const float* wp = Wf + (size_t)(n0 + wrow) * K + k0 + wcol;
      wf0 = *(const float4*)(wp);
      wf1 = *(const float4*)(wp + 4);
      wf2 = *(const float4*)(wp + 8);
      wf3 = *(const float4*)(wp + 12);
    }
    __syncthreads();               // previous iteration's LDS reads complete
#pragma unroll
    for (int i = 0; i < 2; ++i) {
      const int c = 2 * w + i;     // wave-uniform chunk id (16 rows / 1 KB)
      gload16(A + (size_t)(m0 + c*16 + crow) * K + k0 + ccol, (__bf16*)As + c*512);
      if (WBF16)
        gload16(Wb + (size_t)(n0 + c*16 + crow) * K + k0 + ccol, (__bf16*)Bs + c*512);
    }
    if (!WBF16) {
      *(bf16x8*)&Bs[wrow][wcol]     = to_bf8(wf0, wf1);
      *(bf16x8*)&Bs[wrow][wcol + 8] = to_bf8(wf2, wf3);
    }
    __syncthreads();               // implies vmcnt(0): gloads landed
    bf16x8 af[4], bf[4];
#pragma unroll
    for (int i = 0; i < 4; ++i) af[i] = *(const bf16x8*)&As[wm + i*16 + fr][fk];
#pragma unroll
    for (int j = 0; j < 4; ++j) bf[j] = *(const bf16x8*)&Bs[wn + j*16 + fr][fk];
#pragma unroll
    for (int i = 0; i < 4; ++i)
#pragma unroll
      for (int j = 0; j < 4; ++j)
        acc[i][j] = __builtin_amdgcn_mfma_f32_16x16x32_bf16(af[i], bf[j], acc[i][j], 0, 0, 0);
  }

  const int orow = m0 + wm + (l >> 4) * 4;
  const int ocol = n0 + wn + fr;
#pragma unroll
  for (int i = 0; i < 4; ++i)
#pragma unroll
    for (int j = 0; j < 4; ++j) {
      const int col = ocol + j * 16;
      const float bv = BIAS ? bias[col] : 0.0f;
#pragma unroll
      for (int r = 0; r < 4; ++r) {
        float v = acc[i][j][r] + bv;
        if (RELU) v = fmaxf(v, 0.0f);
        if (OUTBF16)
          ((__bf16*)Cv)[(size_t)(orow + i*16 + r) * N + col] = (__bf16)v;
        else
          ((float*)Cv)[(size_t)(orow + i*16 + r) * N + col] = v;
      }
    }
}

// ---------------------------------------------------------------------------
// x = LN(y + x) * s + b ; also emit bf16 copy xb.
// ---------------------------------------------------------------------------
__global__ __launch_bounds__(256) void ln_res_kernel(
    const float* __restrict__ y, float* __restrict__ x, __bf16* __restrict__ xb,
    const float* __restrict__ sc, const float* __restrict__ bs) {
  __shared__ float red[8];
  int row = blockIdx.x, t = threadIdx.x;
  const float4* y4 = (const float4*)(y + (size_t)row * EE);
  float4* x4 = (float4*)(x + (size_t)row * EE);
  float4 a = y4[t], c = x4[t];
  float v0 = a.x + c.x, v1 = a.y + c.y, v2 = a.z + c.z, v3 = a.w + c.w;
  float s = v0 + v1 + v2 + v3;
  float q = v0*v0 + v1*v1 + v2*v2 + v3*v3;
#pragma unroll
  for (int off = 32; off; off >>= 1) {
    s += __shfl_xor(s, off);
    q += __shfl_xor(q, off);
  }
  int w = t >> 6;
  if ((t & 63) == 0) { red[w] = s; red[4 + w] = q; }
  __syncthreads();
  s = red[0] + red[1] + red[2] + red[3];
  q = red[4] + red[5] + red[6] + red[7];
  float mean = s * (1.0f / EE);
  float var  = q * (1.0f / EE) - mean * mean;
  float r = 1.0f / sqrtf(var + 1e-6f);
  float4 ss = ((const float4*)sc)[t];
  float4 bb = ((const float4*)bs)[t];
  float4 o;
  o.x = (v0 - mean) * r * ss.x + bb.x;
  o.y = (v1 - mean) * r * ss.y + bb.y;
  o.z = (v2 - mean) * r * ss.z + bb.z;
  o.w = (v3 - mean) * r * ss.w + bb.w;
  x4[t] = o;
  bf16x4 ob4;
  ob4[0] = (__bf16)o.x; ob4[1] = (__bf16)o.y; ob4[2] = (__bf16)o.z; ob4[3] = (__bf16)o.w;
  *(bf16x4*)(xb + (size_t)row * EE + t * 4) = ob4;
}

// ---------------------------------------------------------------------------
// MFMA flash attention, bf16 qkv in / bf16 out (same verified structure).
// ---------------------------------------------------------------------------
__global__ __launch_bounds__(256) void attn_mfma(
    const __bf16* __restrict__ qkv, const int* __restrict__ ls,
    __bf16* __restrict__ out) {
  const int qt = 15 - blockIdx.x;
  const int h = blockIdx.y, b = blockIdx.z;
  __shared__ f32x4 lds4[2304];             // 36864 B
  char* lds = (char*)lds4;
  __bf16* Ks = (__bf16*)lds;               // [64][72]
  __bf16* Vs = (__bf16*)(lds + 9216);      // [64][72] transposed (d-major)
  __shared__ int redmin[4];
  const int t = threadIdx.x, w = t >> 6, l = t & 63;
  __bf16* Pq = (__bf16*)(lds + 18432 + w * 4608);  // [32][72] per wave
  const int r = l & 31, hi = l >> 5;
  const int qb = qt * 128, qw = qb + w * 32, qg = qw + r;
  const int Lq = ls[b*SS + qg];

  {
    int mn = Lq;
#pragma unroll
    for (int off = 1; off < 64; off <<= 1) mn = min(mn, __shfl_xor(mn, off));
    if (l == 0) redmin[w] = mn;
  }

  bf16x8 qf[4];
  {
    const __bf16* qrow = qkv + (size_t)(b*SS + qg) * 3*EE + EE + h*DD + 8*hi;
#pragma unroll
    for (int ds = 0; ds < 4; ++ds) qf[ds] = *(const bf16x8*)(qrow + 16*ds);
  }
  __syncthreads();
  const int ktmin = min(min(redmin[0], redmin[1]), min(redmin[2], redmin[3])) >> 6;
  const int ktmax = 2*qt + 1;

  f32x16 oacc[2] = {};
  float m_r = NEG_HUGE, lsum = 0.0f;

  for (int kt = ktmin; kt <= ktmax; ++kt) {
    __syncthreads();
    {
      const int kr = t >> 2, c0 = (t & 3) * 16;
      const __bf16* kg = qkv + (size_t)(b*SS + kt*64 + kr) * 3*EE + h*DD + c0;
      const __bf16* vg = kg + 2*EE;
      bf16x8 k0 = *(const bf16x8*)kg;
      bf16x8 k1 = *(const bf16x8*)(kg + 8);
      bf16x8 v0 = *(const bf16x8*)vg;
      bf16x8 v1 = *(const bf16x8*)(vg + 8);
      *(bf16x8*)&Ks[kr*72 + c0]     = k0;
      *(bf16x8*)&Ks[kr*72 + c0 + 8] = k1;
      const int vc = (kr + 8*(t & 3)) & 63;
#pragma unroll
      for (int j = 0; j < 8; ++j) {
        Vs[(c0 + j)*72 + vc]     = v0[j];
        Vs[(c0 + 8 + j)*72 + vc] = v1[j];
      }
    }
    __syncthreads();

    bool act0 = (kt*64)      <= (qw + 31);
    bool act1 = (kt*64 + 32) <= (qw + 31);
    if (!act0) continue;

    f32x16 st[2];
    st[0] = (f32x16){};
    st[1] = (f32x16){};
#pragma unroll
    for (int ds = 0; ds < 4; ++ds) {
      bf16x8 kf = *(const bf16x8*)&Ks[(r)*72 + 16*ds + 8*hi];
      st[0] = __builtin_amdgcn_mfma_f32_32x32x16_bf16(kf, qf[ds], st[0], 0, 0, 0);
    }
    if (act1) {
#pragma unroll
      for (int ds = 0; ds < 4; ++ds) {
        bf16x8 kf = *(const bf16x8*)&Ks[(32 + r)*72 + 16*ds + 8*hi];
        st[1] = __builtin_amdgcn_mfma_f32_32x32x16_bf16(kf, qf[ds], st[1], 0, 0, 0);
      }
    }

    float tmax = NEG_HUGE;
#pragma unroll
    for (int kt2 = 0; kt2 < 2; ++kt2) {
#pragma unroll
      for (int reg = 0; reg < 16; ++reg) {
        const int key = kt*64 + 32*kt2 + (reg & 3) + 8*(reg >> 2) + 4*hi;
        float s = (kt2 == 0 || act1) ? st[kt2][reg] * 0.125f : NEG_HUGE;
        const bool valid = (key >= Lq) && (key <= qg);
        s = valid ? s : NEG_HUGE;
        st[kt2][reg] = s;
        tmax = fmaxf(tmax, s);
      }
    }
    tmax = fmaxf(tmax, __shfl_xor(tmax, 32));
    const float m_new = fmaxf(m_r, tmax);
    const float alpha = __expf(m_r - m_new);
    m_r = m_new;

    float psum = 0.0f;
#pragma unroll
    for (int kt2 = 0; kt2 < 2; ++kt2) {
#pragma unroll
      for (int g2 = 0; g2 < 4; ++g2) {
        bf16x4 pk;
#pragma unroll
        for (int j = 0; j < 4; ++j) {
          float p = __expf(st[kt2][g2*4 + j] - m_new);
          psum += p;
          pk[j] = (__bf16)p;
        }
        *(bf16x4*)&Pq[r*72 + 32*kt2 + 8*g2 + 4*hi] = pk;
      }
    }
    psum += __shfl_xor(psum, 32);
    lsum = lsum * alpha + psum;
    oacc[0] *= alpha;
    oacc[1] *= alpha;

#pragma unroll
    for (int ks = 0; ks < 4; ++ks) {
      if (kt*64 + 16*ks > qw + 31) continue;
      bf16x8 pf = *(const bf16x8*)&Pq[r*72 + 16*ks + 8*hi];
#pragma unroll
      for (int mt = 0; mt < 2; ++mt) {
        const int d = 32*mt + r;
        const int vcol = (16*ks + 8*hi + 8*((d >> 4) & 3)) & 63;
        bf16x8 vf = *(const bf16x8*)&Vs[d*72 + vcol];
        oacc[mt] = __builtin_amdgcn_mfma_f32_32x32x16_bf16(vf, pf, oacc[mt], 0, 0, 0);
      }
    }
  }

  __syncthreads();
  float* Ot = (float*)(lds + w * 8448);        // [64][33] f32 per wave
  const float rinv = 1.0f / lsum;
#pragma unroll
  for (int mt = 0; mt < 2; ++mt)
#pragma unroll
    for (int reg = 0; reg < 16; ++reg) {
      const int d = 32*mt + (reg & 3) + 8*(reg >> 2) + 4*hi;
      Ot[d*33 + r] = oacc[mt][reg] * rinv;
    }
  __syncthreads();
  const int qr0 = l >> 4, dc = (l & 15) * 4;
#pragma unroll
  for (int it = 0; it < 8; ++it) {
    const int qr = qr0 + 4*it;
    bf16x4 ov;
    ov[0] = (__bf16)Ot[(dc+0)*33 + qr];
    ov[1] = (__bf16)Ot[(dc+1)*33 + qr];
    ov[2] = (__bf16)Ot[(dc+2)*33 + qr];
    ov[3] = (__bf16)Ot[(dc+3)*33 + qr];
    *(bf16x4*)(out + (size_t)(b*SS + qw + qr) * EE + h*DD + dc) = ov;
  }
}

// ---------------------------------------------------------------------------
extern "C" void kernel_launch(void* const* d_in, const int* in_sizes, int n_in,
                              void* d_out, int out_size, void* d_ws, size_t ws_size,
                              hipStream_t stream) {
  const int*   tokens     = (const int*)  d_in[0];
  const float* word_embed = (const float*)d_in[1];
  const float* pos_embed  = (const float*)d_in[2];
  const float* unembed_b  = (const float*)d_in[3];
  const float* kqv_w      = (const float*)d_in[4];
  const float* wo_w       = (const float*)d_in[5];
  const float* up_w       = (const float*)d_in[6];
  const float* up_b       = (const float*)d_in[7];
  const float* down_w     = (const float*)d_in[8];
  const float* down_b     = (const float*)d_in[9];
  const float* ln1_s      = (const float*)d_in[10];
  const float* ln1_b      = (const float*)d_in[11];
  const float* ln2_s      = (const float*)d_in[12];
  const float* ln2_b      = (const float*)d_in[13];
  float* logits = (float*)d_out;

  // d_out (524 MB) scratch map (all dead before the final GEMM writes logits):
  char* ob = (char*)d_out;
  __bf16* qkv  = (__bf16*)ob;                          // 24 MB
  __bf16* t0   = (__bf16*)(ob +  24ull*1024*1024);     //  8 MB
  __bf16* hbuf = (__bf16*)(ob +  32ull*1024*1024);     // 32 MB
  float*  ybuf = (float*) (ob +  64ull*1024*1024);     // 16 MB
  __bf16* wcvt = (__bf16*)(ob +  80ull*1024*1024);     // 50.4 MB bf16 weights
  float*  x    = (float*) (ob + 131ull*1024*1024);     // 16 MB fp32 residual
  __bf16* kqvb  = wcvt;
  __bf16* wob   = kqvb + (size_t)LL*3*EE*EE;
  __bf16* upb   = wob  + (size_t)LL*EE*EE;
  __bf16* downb = upb  + (size_t)LL*FF*EE;
  // ws: only what must survive the final GEMM (which overwrites all of d_out).
  int*    ls   = (int*)d_ws;                            // 64 KB
  __bf16* xb   = (__bf16*)((char*)d_ws + 65536);        // 8 MB
  __bf16* webf = (__bf16*)((char*)d_ws + 65536 + 8ull*1024*1024);
  const bool bigws = ws_size >= (size_t)(65536 + 8ull*1024*1024 + (size_t)VV*EE*2);

  lastart_kernel<<<1, 64, 0, stream>>>(tokens, ls);
  embed_kernel<<<BS, 256, 0, stream>>>(tokens, ls, word_embed, pos_embed, x, xb);

  // weight pre-conversion (fp32 -> bf16), ~150 MB of traffic
  cvt_bf16_kernel<<<LL*3*EE*EE/2048, 256, 0, stream>>>(kqv_w,  kqvb,  LL*3*EE*EE);
  cvt_bf16_kernel<<<LL*EE*EE/2048,   256, 0, stream>>>(wo_w,   wob,   LL*EE*EE);
  cvt_bf16_kernel<<<LL*FF*EE/2048,   256, 0, stream>>>(up_w,   upb,   LL*FF*EE);
  cvt_bf16_kernel<<<LL*EE*FF/2048,   256, 0, stream>>>(down_w, downb, LL*EE*FF);
  if (bigws)
    cvt_bf16_kernel<<<VV*EE/2048, 256, 0, stream>>>(word_embed, webf, VV*EE);

  for (int l = 0; l < LL; ++l) {
    gemm_fast<true,false,false,true><<<dim3(BS/128, 3*EE/128), 256, 0, stream>>>(
        xb, kqvb + (size_t)l*3*EE*EE, nullptr, qkv, 3*EE, EE);
    attn_mfma<<<dim3(16, HH, BB), 256, 0, stream>>>(qkv, ls, t0);
    gemm_fast<true,false,false,false><<<dim3(BS/128, EE/128), 256, 0, stream>>>(
        t0, wob + (size_t)l*EE*EE, nullptr, ybuf, EE, EE);
    ln_res_kernel<<<BS, 256, 0, stream>>>(ybuf, x, xb, ln1_s + l*EE, ln1_b + l*EE);
    gemm_fast<true,true,true,true><<<dim3(BS/128, FF/128), 256, 0, stream>>>(
        xb, upb + (size_t)l*FF*EE, up_b + (size_t)l*FF, hbuf, FF, EE);
    gemm_fast<true,true,false,false><<<dim3(BS/128, EE/128), 256, 0, stream>>>(
        hbuf, downb + (size_t)l*EE*FF, down_b + (size_t)l*EE, ybuf, EE, FF);
    ln_res_kernel<<<BS, 256, 0, stream>>>(ybuf, x, xb, ln2_s + l*EE, ln2_b + l*EE);
  }

  if (bigws)
    gemm_fast<true,true,false,false><<<dim3(BS/128, VV/128), 256, 0, stream>>>(
        xb, webf, unembed_b, logits, VV, EE);
  else
    gemm_fast<false,true,false,false><<<dim3(BS/128, VV/128), 256, 0, stream>>>(
        xb, word_embed, unembed_b, logits, VV, EE);
}

// Round 5
// 1156.569 us; speedup vs baseline: 12.0077x; 1.1316x over previous
//
#include <hip/hip_runtime.h>
#include <hip/hip_bf16.h>

#define BB 2
#define SS 2048
#define EE 1024
#define HH 16
#define DD 64
#define FF 4096
#define VV 32000
#define LL 2
#define BS (BB*SS)

#define NEG_HUGE (-3.402823466e+38f)

typedef __attribute__((ext_vector_type(4)))  float  f32x4;
typedef __attribute__((ext_vector_type(16))) float  f32x16;
typedef __attribute__((ext_vector_type(8)))  __bf16 bf16x8;
typedef __attribute__((ext_vector_type(4)))  __bf16 bf16x4;

__device__ inline bf16x8 to_bf8(float4 a, float4 b) {
  bf16x8 r;
  r[0] = (__bf16)a.x; r[1] = (__bf16)a.y; r[2] = (__bf16)a.z; r[3] = (__bf16)a.w;
  r[4] = (__bf16)b.x; r[5] = (__bf16)b.y; r[6] = (__bf16)b.z; r[7] = (__bf16)b.w;
  return r;
}

typedef const unsigned int __attribute__((address_space(1)))* gptr_t;
typedef unsigned int __attribute__((address_space(3)))* lptr_t;
__device__ inline void gload16(const void* g, void* l) {
  __builtin_amdgcn_global_load_lds((gptr_t)g, (lptr_t)l, 16, 0, 0);
}

// ---------------------------------------------------------------------------
// last_start via parallel max-scan (1 block per batch row).
// ---------------------------------------------------------------------------
__global__ __launch_bounds__(1024) void lastart_scan(
    const int* __restrict__ tokens, int* __restrict__ ls) {
  __shared__ int buf[SS];
  const int b = blockIdx.x, t = threadIdx.x;
#pragma unroll
  for (int j = 0; j < 2; ++j) {
    int i = t + j * 1024;
    buf[i] = (i > 0 && tokens[b*SS + i] == 1) ? i : 0;
  }
  __syncthreads();
  for (int off = 1; off < SS; off <<= 1) {
    int i0 = t, i1 = t + 1024;
    int v0 = (i0 >= off) ? max(buf[i0], buf[i0 - off]) : buf[i0];
    int v1 = (i1 >= off) ? max(buf[i1], buf[i1 - off]) : buf[i1];
    __syncthreads();
    buf[i0] = v0; buf[i1] = v1;
    __syncthreads();
  }
#pragma unroll
  for (int j = 0; j < 2; ++j) {
    int i = t + j * 1024;
    ls[b*SS + i] = buf[i];
  }
}

__global__ __launch_bounds__(256) void embed_kernel(
    const int* __restrict__ tokens, const int* __restrict__ ls,
    const float* __restrict__ we, const float* __restrict__ pe,
    float* __restrict__ x, __bf16* __restrict__ xb) {
  int row = blockIdx.x;
  int s = row & (SS - 1);
  int tok = tokens[row];
  int rp = s - ls[row];
  const float4* w4 = (const float4*)(we + (size_t)tok * EE);
  const float4* p4 = (const float4*)(pe + (size_t)rp * EE);
  float4 a = w4[threadIdx.x];
  float4 b = p4[threadIdx.x];
  float4 o; o.x = a.x + b.x; o.y = a.y + b.y; o.z = a.z + b.z; o.w = a.w + b.w;
  ((float4*)(x + (size_t)row * EE))[threadIdx.x] = o;
  bf16x4 ob4;
  ob4[0] = (__bf16)o.x; ob4[1] = (__bf16)o.y; ob4[2] = (__bf16)o.z; ob4[3] = (__bf16)o.w;
  *(bf16x4*)(xb + (size_t)row * EE + threadIdx.x * 4) = ob4;
}

// ---------------------------------------------------------------------------
__global__ __launch_bounds__(256) void cvt_bf16_kernel(
    const float* __restrict__ src, __bf16* __restrict__ dst, int n) {
  int i = (blockIdx.x * 256 + threadIdx.x) * 8;
  if (i + 8 > n) return;
  float4 a = *(const float4*)(src + i);
  float4 b = *(const float4*)(src + i + 4);
  *(bf16x8*)(dst + i) = to_bf8(a, b);
}

// ---------------------------------------------------------------------------
// 256x256 GEMM: C[M,N] = A[M,K] @ W[N,K]^T (+bias)(+relu). bf16 in, BK=32,
// 512 thr = 8 waves (2Mx4N), per-wave 128x64 out (acc[8][4]).
// LDS 64 KB double-buffered; swizzled layout: position (row, slot) holds
// col8 = slot ^ ((row>>1)&3)  -> ds_read_b128 frag reads are <=2-way (free).
// Staging: linear gload_lds dest + inverse-swizzled per-lane global source.
// Issue-early: tile T+1's 8 gloads issued before tile T's MFMAs; drained by
// the end-of-tile __syncthreads (one full 32-MFMA tile of latency cover).
// Grid: 1-D with bijective XCD chunk swizzle (m204).
// ---------------------------------------------------------------------------
__device__ inline void stage256(const __bf16* __restrict__ A,
                                const __bf16* __restrict__ W,
                                __bf16* ldsA, __bf16* ldsB,
                                int m0, int n0, int K, int k0, int t) {
  const int row = t >> 2;
  const int col8 = (t & 3) ^ ((t >> 3) & 3);   // inverse-swizzled source col
  const int csrc = k0 + col8 * 8;
  const int dst = (t >> 6) * 512;              // wave-uniform elem base (+HW lane*16B)
#pragma unroll
  for (int j = 0; j < 2; ++j) {
    gload16(A + (size_t)(m0 + j*128 + row) * K + csrc, ldsA + j*4096 + dst);
    gload16(W + (size_t)(n0 + j*128 + row) * K + csrc, ldsB + j*4096 + dst);
  }
}

template<bool BIAS, bool RELU, bool OUTBF16>
__global__ __launch_bounds__(512, 2) void gemm_256(
    const __bf16* __restrict__ A, const __bf16* __restrict__ W,
    const float* __restrict__ bias, void* __restrict__ Cv,
    int N, int K, int nbx) {
  __shared__ __bf16 lds[4][8192];              // [buf*2 + (A|B)], 64 KB
  const int t = threadIdx.x, l = t & 63, w = t >> 6;
  const int nwg = gridDim.x, orig = blockIdx.x;
  const int q = nwg >> 3, r = nwg & 7, xcd = orig & 7, pos = orig >> 3;
  const int wgid = (xcd < r ? xcd*(q+1) : r*(q+1) + (xcd-r)*q) + pos;
  const int m0 = (wgid % nbx) * 256, n0 = (wgid / nbx) * 256;
  const int wm = w >> 2, wn = w & 3;
  const int fr = l & 15, c8 = l >> 4;
  const int slot = (c8 ^ ((fr >> 1) & 3)) * 8; // swizzled read slot (elems)

  f32x4 acc[8][4] = {};

  stage256(A, W, lds[0], lds[1], m0, n0, K, 0, t);
  __syncthreads();
  const int nk = K >> 5;
  for (int kt = 0; kt < nk; ++kt) {
    const int cur = (kt & 1) * 2;
    if (kt + 1 < nk)
      stage256(A, W, lds[cur ^ 2], lds[(cur ^ 2) + 1], m0, n0, K, (kt + 1) * 32, t);
    const __bf16* La = lds[cur];
    const __bf16* Lb = lds[cur + 1];
    bf16x8 bfr[4];
#pragma unroll
    for (int j = 0; j < 4; ++j)
      bfr[j] = *(const bf16x8*)&Lb[(wn*64 + j*16 + fr) * 32 + slot];
#pragma unroll
    for (int i = 0; i < 8; ++i) {
      bf16x8 af = *(const bf16x8*)&La[(wm*128 + i*16 + fr) * 32 + slot];
#pragma unroll
      for (int j = 0; j < 4; ++j)
        acc[i][j] = __builtin_amdgcn_mfma_f32_16x16x32_bf16(af, bfr[j], acc[i][j], 0, 0, 0);
    }
    __syncthreads();   // vmcnt(0)+lgkmcnt(0)+barrier: next tile staged & safe
  }

  const int orow = m0 + wm*128 + (l >> 4) * 4;
  const int ocol = n0 + wn*64 + fr;
#pragma unroll
  for (int i = 0; i < 8; ++i)
#pragma unroll
    for (int j = 0; j < 4; ++j) {
      const int col = ocol + j * 16;
      const float bv = BIAS ? bias[col] : 0.0f;
#pragma unroll
      for (int rr = 0; rr < 4; ++rr) {
        float v = acc[i][j][rr] + bv;
        if (RELU) v = fmaxf(v, 0.0f);
        if (OUTBF16)
          ((__bf16*)Cv)[(size_t)(orow + i*16 + rr) * N + col] = (__bf16)v;
        else
          ((float*)Cv)[(size_t)(orow + i*16 + rr) * N + col] = v;
      }
    }
}

// ---------------------------------------------------------------------------
// 128x128 GEMM (unchanged, for small-N shapes: wo, down, fallback unembed).
// ---------------------------------------------------------------------------
template<bool WBF16, bool BIAS, bool RELU, bool OUTBF16>
__global__ __launch_bounds__(256) void gemm_fast(
    const __bf16* __restrict__ A, const void* __restrict__ Wv,
    const float* __restrict__ bias, void* __restrict__ Cv, int N, int K) {
  __shared__ __bf16 As[128][32];
  __shared__ __bf16 Bs[128][32];
  const int t = threadIdx.x;
  const int m0 = blockIdx.x * 128, n0 = blockIdx.y * 128;
  const int l = t & 63, w = t >> 6;
  const int wm = (w >> 1) * 64, wn = (w & 1) * 64;
  const int fr = l & 15, fk = (l >> 4) * 8;
  const int crow = l >> 2, ccol = (l & 3) * 8;
  const int wrow = t >> 1, wcol = (t & 1) * 16;

  const __bf16* Wb = (const __bf16*)Wv;
  const float*  Wf = (const float*)Wv;

  f32x4 acc[4][4] = {};

  for (int k0 = 0; k0 < K; k0 += 32) {
    float4 wf0, wf1, wf2, wf3;
    if (!WBF16) {
      const float* wp = Wf + (size_t)(n0 + wrow) * K + k0 + wcol;
      wf0 = *(const float4*)(wp);
      wf1 = *(const float4*)(wp + 4);
      wf2 = *(const float4*)(wp + 8);
      wf3 = *(const float4*)(wp + 12);
    }
    __syncthreads();
#pragma unroll
    for (int i = 0; i < 2; ++i) {
      const int c = 2 * w + i;
      gload16(A + (size_t)(m0 + c*16 + crow) * K + k0 + ccol, (__bf16*)As + c*512);
      if (WBF16)
        gload16(Wb + (size_t)(n0 + c*16 + crow) * K + k0 + ccol, (__bf16*)Bs + c*512);
    }
    if (!WBF16) {
      *(bf16x8*)&Bs[wrow][wcol]     = to_bf8(wf0, wf1);
      *(bf16x8*)&Bs[wrow][wcol + 8] = to_bf8(wf2, wf3);
    }
    __syncthreads();
    bf16x8 af[4], bf[4];
#pragma unroll
    for (int i = 0; i < 4; ++i) af[i] = *(const bf16x8*)&As[wm + i*16 + fr][fk];
#pragma unroll
    for (int j = 0; j < 4; ++j) bf[j] = *(const bf16x8*)&Bs[wn + j*16 + fr][fk];
#pragma unroll
    for (int i = 0; i < 4; ++i)
#pragma unroll
      for (int j = 0; j < 4; ++j)
        acc[i][j] = __builtin_amdgcn_mfma_f32_16x16x32_bf16(af[i], bf[j], acc[i][j], 0, 0, 0);
  }

  const int orow = m0 + wm + (l >> 4) * 4;
  const int ocol = n0 + wn + fr;
#pragma unroll
  for (int i = 0; i < 4; ++i)
#pragma unroll
    for (int j = 0; j < 4; ++j) {
      const int col = ocol + j * 16;
      const float bv = BIAS ? bias[col] : 0.0f;
#pragma unroll
      for (int r = 0; r < 4; ++r) {
        float v = acc[i][j][r] + bv;
        if (RELU) v = fmaxf(v, 0.0f);
        if (OUTBF16)
          ((__bf16*)Cv)[(size_t)(orow + i*16 + r) * N + col] = (__bf16)v;
        else
          ((float*)Cv)[(size_t)(orow + i*16 + r) * N + col] = v;
      }
    }
}

// ---------------------------------------------------------------------------
// x = LN(y + x) * s + b ; also emit bf16 copy xb.
// ---------------------------------------------------------------------------
__global__ __launch_bounds__(256) void ln_res_kernel(
    const float* __restrict__ y, float* __restrict__ x, __bf16* __restrict__ xb,
    const float* __restrict__ sc, const float* __restrict__ bs) {
  __shared__ float red[8];
  int row = blockIdx.x, t = threadIdx.x;
  const float4* y4 = (const float4*)(y + (size_t)row * EE);
  float4* x4 = (float4*)(x + (size_t)row * EE);
  float4 a = y4[t], c = x4[t];
  float v0 = a.x + c.x, v1 = a.y + c.y, v2 = a.z + c.z, v3 = a.w + c.w;
  float s = v0 + v1 + v2 + v3;
  float q = v0*v0 + v1*v1 + v2*v2 + v3*v3;
#pragma unroll
  for (int off = 32; off; off >>= 1) {
    s += __shfl_xor(s, off);
    q += __shfl_xor(q, off);
  }
  int w = t >> 6;
  if ((t & 63) == 0) { red[w] = s; red[4 + w] = q; }
  __syncthreads();
  s = red[0] + red[1] + red[2] + red[3];
  q = red[4] + red[5] + red[6] + red[7];
  float mean = s * (1.0f / EE);
  float var  = q * (1.0f / EE) - mean * mean;
  float r = 1.0f / sqrtf(var + 1e-6f);
  float4 ss = ((const float4*)sc)[t];
  float4 bb = ((const float4*)bs)[t];
  float4 o;
  o.x = (v0 - mean) * r * ss.x + bb.x;
  o.y = (v1 - mean) * r * ss.y + bb.y;
  o.z = (v2 - mean) * r * ss.z + bb.z;
  o.w = (v3 - mean) * r * ss.w + bb.w;
  x4[t] = o;
  bf16x4 ob4;
  ob4[0] = (__bf16)o.x; ob4[1] = (__bf16)o.y; ob4[2] = (__bf16)o.z; ob4[3] = (__bf16)o.w;
  *(bf16x4*)(xb + (size_t)row * EE + t * 4) = ob4;
}

// ---------------------------------------------------------------------------
// MFMA flash attention (unchanged, verified).
// ---------------------------------------------------------------------------
__global__ __launch_bounds__(256) void attn_mfma(
    const __bf16* __restrict__ qkv, const int* __restrict__ ls,
    __bf16* __restrict__ out) {
  const int qt = 15 - blockIdx.x;
  const int h = blockIdx.y, b = blockIdx.z;
  __shared__ f32x4 lds4[2304];             // 36864 B
  char* lds = (char*)lds4;
  __bf16* Ks = (__bf16*)lds;               // [64][72]
  __bf16* Vs = (__bf16*)(lds + 9216);      // [64][72] transposed (d-major)
  __shared__ int redmin[4];
  const int t = threadIdx.x, w = t >> 6, l = t & 63;
  __bf16* Pq = (__bf16*)(lds + 18432 + w * 4608);  // [32][72] per wave
  const int r = l & 31, hi = l >> 5;
  const int qb = qt * 128, qw = qb + w * 32, qg = qw + r;
  const int Lq = ls[b*SS + qg];

  {
    int mn = Lq;
#pragma unroll
    for (int off = 1; off < 64; off <<= 1) mn = min(mn, __shfl_xor(mn, off));
    if (l == 0) redmin[w] = mn;
  }

  bf16x8 qf[4];
  {
    const __bf16* qrow = qkv + (size_t)(b*SS + qg) * 3*EE + EE + h*DD + 8*hi;
#pragma unroll
    for (int ds = 0; ds < 4; ++ds) qf[ds] = *(const bf16x8*)(qrow + 16*ds);
  }
  __syncthreads();
  const int ktmin = min(min(redmin[0], redmin[1]), min(redmin[2], redmin[3])) >> 6;
  const int ktmax = 2*qt + 1;

  f32x16 oacc[2] = {};
  float m_r = NEG_HUGE, lsum = 0.0f;

  for (int kt = ktmin; kt <= ktmax; ++kt) {
    __syncthreads();
    {
      const int kr = t >> 2, c0 = (t & 3) * 16;
      const __bf16* kg = qkv + (size_t)(b*SS + kt*64 + kr) * 3*EE + h*DD + c0;
      const __bf16* vg = kg + 2*EE;
      bf16x8 k0 = *(const bf16x8*)kg;
      bf16x8 k1 = *(const bf16x8*)(kg + 8);
      bf16x8 v0 = *(const bf16x8*)vg;
      bf16x8 v1 = *(const bf16x8*)(vg + 8);
      *(bf16x8*)&Ks[kr*72 + c0]     = k0;
      *(bf16x8*)&Ks[kr*72 + c0 + 8] = k1;
      const int vc = (kr + 8*(t & 3)) & 63;
#pragma unroll
      for (int j = 0; j < 8; ++j) {
        Vs[(c0 + j)*72 + vc]     = v0[j];
        Vs[(c0 + 8 + j)*72 + vc] = v1[j];
      }
    }
    __syncthreads();

    bool act0 = (kt*64)      <= (qw + 31);
    bool act1 = (kt*64 + 32) <= (qw + 31);
    if (!act0) continue;

    f32x16 st[2];
    st[0] = (f32x16){};
    st[1] = (f32x16){};
#pragma unroll
    for (int ds = 0; ds < 4; ++ds) {
      bf16x8 kf = *(const bf16x8*)&Ks[(r)*72 + 16*ds + 8*hi];
      st[0] = __builtin_amdgcn_mfma_f32_32x32x16_bf16(kf, qf[ds], st[0], 0, 0, 0);
    }
    if (act1) {
#pragma unroll
      for (int ds = 0; ds < 4; ++ds) {
        bf16x8 kf = *(const bf16x8*)&Ks[(32 + r)*72 + 16*ds + 8*hi];
        st[1] = __builtin_amdgcn_mfma_f32_32x32x16_bf16(kf, qf[ds], st[1], 0, 0, 0);
      }
    }

    float tmax = NEG_HUGE;
#pragma unroll
    for (int kt2 = 0; kt2 < 2; ++kt2) {
#pragma unroll
      for (int reg = 0; reg < 16; ++reg) {
        const int key = kt*64 + 32*kt2 + (reg & 3) + 8*(reg >> 2) + 4*hi;
        float s = (kt2 == 0 || act1) ? st[kt2][reg] * 0.125f : NEG_HUGE;
        const bool valid = (key >= Lq) && (key <= qg);
        s = valid ? s : NEG_HUGE;
        st[kt2][reg] = s;
        tmax = fmaxf(tmax, s);
      }
    }
    tmax = fmaxf(tmax, __shfl_xor(tmax, 32));
    const float m_new = fmaxf(m_r, tmax);
    const float alpha = __expf(m_r - m_new);
    m_r = m_new;

    float psum = 0.0f;
#pragma unroll
    for (int kt2 = 0; kt2 < 2; ++kt2) {
#pragma unroll
      for (int g2 = 0; g2 < 4; ++g2) {
        bf16x4 pk;
#pragma unroll
        for (int j = 0; j < 4; ++j) {
          float p = __expf(st[kt2][g2*4 + j] - m_new);
          psum += p;
          pk[j] = (__bf16)p;
        }
        *(bf16x4*)&Pq[r*72 + 32*kt2 + 8*g2 + 4*hi] = pk;
      }
    }
    psum += __shfl_xor(psum, 32);
    lsum = lsum * alpha + psum;
    oacc[0] *= alpha;
    oacc[1] *= alpha;

#pragma unroll
    for (int ks = 0; ks < 4; ++ks) {
      if (kt*64 + 16*ks > qw + 31) continue;
      bf16x8 pf = *(const bf16x8*)&Pq[r*72 + 16*ks + 8*hi];
#pragma unroll
      for (int mt = 0; mt < 2; ++mt) {
        const int d = 32*mt + r;
        const int vcol = (16*ks + 8*hi + 8*((d >> 4) & 3)) & 63;
        bf16x8 vf = *(const bf16x8*)&Vs[d*72 + vcol];
        oacc[mt] = __builtin_amdgcn_mfma_f32_32x32x16_bf16(vf, pf, oacc[mt], 0, 0, 0);
      }
    }
  }

  __syncthreads();
  float* Ot = (float*)(lds + w * 8448);        // [64][33] f32 per wave
  const float rinv = 1.0f / lsum;
#pragma unroll
  for (int mt = 0; mt < 2; ++mt)
#pragma unroll
    for (int reg = 0; reg < 16; ++reg) {
      const int d = 32*mt + (reg & 3) + 8*(reg >> 2) + 4*hi;
      Ot[d*33 + r] = oacc[mt][reg] * rinv;
    }
  __syncthreads();
  const int qr0 = l >> 4, dc = (l & 15) * 4;
#pragma unroll
  for (int it = 0; it < 8; ++it) {
    const int qr = qr0 + 4*it;
    bf16x4 ov;
    ov[0] = (__bf16)Ot[(dc+0)*33 + qr];
    ov[1] = (__bf16)Ot[(dc+1)*33 + qr];
    ov[2] = (__bf16)Ot[(dc+2)*33 + qr];
    ov[3] = (__bf16)Ot[(dc+3)*33 + qr];
    *(bf16x4*)(out + (size_t)(b*SS + qw + qr) * EE + h*DD + dc) = ov;
  }
}

// ---------------------------------------------------------------------------
extern "C" void kernel_launch(void* const* d_in, const int* in_sizes, int n_in,
                              void* d_out, int out_size, void* d_ws, size_t ws_size,
                              hipStream_t stream) {
  const int*   tokens     = (const int*)  d_in[0];
  const float* word_embed = (const float*)d_in[1];
  const float* pos_embed  = (const float*)d_in[2];
  const float* unembed_b  = (const float*)d_in[3];
  const float* kqv_w      = (const float*)d_in[4];
  const float* wo_w       = (const float*)d_in[5];
  const float* up_w       = (const float*)d_in[6];
  const float* up_b       = (const float*)d_in[7];
  const float* down_w     = (const float*)d_in[8];
  const float* down_b     = (const float*)d_in[9];
  const float* ln1_s      = (const float*)d_in[10];
  const float* ln1_b      = (const float*)d_in[11];
  const float* ln2_s      = (const float*)d_in[12];
  const float* ln2_b      = (const float*)d_in[13];
  float* logits = (float*)d_out;

  // d_out (524 MB) scratch map (all dead before the final GEMM writes logits):
  char* ob = (char*)d_out;
  __bf16* qkv  = (__bf16*)ob;                          // 24 MB
  __bf16* t0   = (__bf16*)(ob +  24ull*1024*1024);     //  8 MB
  __bf16* hbuf = (__bf16*)(ob +  32ull*1024*1024);     // 32 MB
  float*  ybuf = (float*) (ob +  64ull*1024*1024);     // 16 MB
  __bf16* wcvt = (__bf16*)(ob +  80ull*1024*1024);     // 50.4 MB bf16 weights
  float*  x    = (float*) (ob + 131ull*1024*1024);     // 16 MB fp32 residual
  __bf16* kqvb  = wcvt;
  __bf16* wob   = kqvb + (size_t)LL*3*EE*EE;
  __bf16* upb   = wob  + (size_t)LL*EE*EE;
  __bf16* downb = upb  + (size_t)LL*FF*EE;
  // ws: only what must survive the final GEMM (which overwrites all of d_out).
  int*    ls   = (int*)d_ws;                            // 64 KB
  __bf16* xb   = (__bf16*)((char*)d_ws + 65536);        // 8 MB
  __bf16* webf = (__bf16*)((char*)d_ws + 65536 + 8ull*1024*1024);
  const bool bigws = ws_size >= (size_t)(65536 + 8ull*1024*1024 + (size_t)VV*EE*2);

  lastart_scan<<<BB, 1024, 0, stream>>>(tokens, ls);
  embed_kernel<<<BS, 256, 0, stream>>>(tokens, ls, word_embed, pos_embed, x, xb);

  // weight pre-conversion (fp32 -> bf16)
  cvt_bf16_kernel<<<LL*3*EE*EE/2048, 256, 0, stream>>>(kqv_w,  kqvb,  LL*3*EE*EE);
  cvt_bf16_kernel<<<LL*EE*EE/2048,   256, 0, stream>>>(wo_w,   wob,   LL*EE*EE);
  cvt_bf16_kernel<<<LL*FF*EE/2048,   256, 0, stream>>>(up_w,   upb,   LL*FF*EE);
  cvt_bf16_kernel<<<LL*EE*FF/2048,   256, 0, stream>>>(down_w, downb, LL*EE*FF);
  if (bigws)
    cvt_bf16_kernel<<<VV*EE/2048, 256, 0, stream>>>(word_embed, webf, VV*EE);

  for (int l = 0; l < LL; ++l) {
    gemm_256<false,false,true><<<(BS/256)*(3*EE/256), 512, 0, stream>>>(
        xb, kqvb + (size_t)l*3*EE*EE, nullptr, qkv, 3*EE, EE, BS/256);
    attn_mfma<<<dim3(16, HH, BB), 256, 0, stream>>>(qkv, ls, t0);
    gemm_fast<true,false,false,false><<<dim3(BS/128, EE/128), 256, 0, stream>>>(
        t0, wob + (size_t)l*EE*EE, nullptr, ybuf, EE, EE);
    ln_res_kernel<<<BS, 256, 0, stream>>>(ybuf, x, xb, ln1_s + l*EE, ln1_b + l*EE);
    gemm_256<true,true,true><<<(BS/256)*(FF/256), 512, 0, stream>>>(
        xb, upb + (size_t)l*FF*EE, up_b + (size_t)l*FF, hbuf, FF, EE, BS/256);
    gemm_fast<true,true,false,false><<<dim3(BS/128, EE/128), 256, 0, stream>>>(
        hbuf, downb + (size_t)l*EE*FF, down_b + (size_t)l*EE, ybuf, EE, FF);
    ln_res_kernel<<<BS, 256, 0, stream>>>(ybuf, x, xb, ln2_s + l*EE, ln2_b + l*EE);
  }

  if (bigws)
    gemm_256<true,false,false><<<(BS/256)*(VV/256), 512, 0, stream>>>(
        xb, webf, unembed_b, logits, VV, EE, BS/256);
  else
    gemm_fast<false,true,false,false><<<dim3(BS/128, VV/128), 256, 0, stream>>>(
        xb, word_embed, unembed_b, logits, VV, EE);
}

// Round 6
// 1011.384 us; speedup vs baseline: 13.7314x; 1.1436x over previous
//
#include <hip/hip_runtime.h>
#include <hip/hip_bf16.h>

#define BB 2
#define SS 2048
#define EE 1024
#define HH 16
#define DD 64
#define FF 4096
#define VV 32000
#define LL 2
#define BS (BB*SS)

#define NEG_HUGE (-3.402823466e+38f)

typedef __attribute__((ext_vector_type(4)))  float  f32x4;
typedef __attribute__((ext_vector_type(16))) float  f32x16;
typedef __attribute__((ext_vector_type(8)))  __bf16 bf16x8;
typedef __attribute__((ext_vector_type(4)))  __bf16 bf16x4;

__device__ inline bf16x8 to_bf8(float4 a, float4 b) {
  bf16x8 r;
  r[0] = (__bf16)a.x; r[1] = (__bf16)a.y; r[2] = (__bf16)a.z; r[3] = (__bf16)a.w;
  r[4] = (__bf16)b.x; r[5] = (__bf16)b.y; r[6] = (__bf16)b.z; r[7] = (__bf16)b.w;
  return r;
}

typedef const unsigned int __attribute__((address_space(1)))* gptr_t;
typedef unsigned int __attribute__((address_space(3)))* lptr_t;
__device__ inline void gload16(const void* g, void* l) {
  __builtin_amdgcn_global_load_lds((gptr_t)g, (lptr_t)l, 16, 0, 0);
}

// ---------------------------------------------------------------------------
// last_start via parallel max-scan (1 block per batch row).
// ---------------------------------------------------------------------------
__global__ __launch_bounds__(1024) void lastart_scan(
    const int* __restrict__ tokens, int* __restrict__ ls) {
  __shared__ int buf[SS];
  const int b = blockIdx.x, t = threadIdx.x;
#pragma unroll
  for (int j = 0; j < 2; ++j) {
    int i = t + j * 1024;
    buf[i] = (i > 0 && tokens[b*SS + i] == 1) ? i : 0;
  }
  __syncthreads();
  for (int off = 1; off < SS; off <<= 1) {
    int i0 = t, i1 = t + 1024;
    int v0 = (i0 >= off) ? max(buf[i0], buf[i0 - off]) : buf[i0];
    int v1 = (i1 >= off) ? max(buf[i1], buf[i1 - off]) : buf[i1];
    __syncthreads();
    buf[i0] = v0; buf[i1] = v1;
    __syncthreads();
  }
#pragma unroll
  for (int j = 0; j < 2; ++j) {
    int i = t + j * 1024;
    ls[b*SS + i] = buf[i];
  }
}

__global__ __launch_bounds__(256) void embed_kernel(
    const int* __restrict__ tokens, const int* __restrict__ ls,
    const float* __restrict__ we, const float* __restrict__ pe,
    float* __restrict__ x, __bf16* __restrict__ xb) {
  int row = blockIdx.x;
  int s = row & (SS - 1);
  int tok = tokens[row];
  int rp = s - ls[row];
  const float4* w4 = (const float4*)(we + (size_t)tok * EE);
  const float4* p4 = (const float4*)(pe + (size_t)rp * EE);
  float4 a = w4[threadIdx.x];
  float4 b = p4[threadIdx.x];
  float4 o; o.x = a.x + b.x; o.y = a.y + b.y; o.z = a.z + b.z; o.w = a.w + b.w;
  ((float4*)(x + (size_t)row * EE))[threadIdx.x] = o;
  bf16x4 ob4;
  ob4[0] = (__bf16)o.x; ob4[1] = (__bf16)o.y; ob4[2] = (__bf16)o.z; ob4[3] = (__bf16)o.w;
  *(bf16x4*)(xb + (size_t)row * EE + threadIdx.x * 4) = ob4;
}

// ---------------------------------------------------------------------------
__global__ __launch_bounds__(256) void cvt_bf16_kernel(
    const float* __restrict__ src, __bf16* __restrict__ dst, int n) {
  int i = (blockIdx.x * 256 + threadIdx.x) * 8;
  if (i + 8 > n) return;
  float4 a = *(const float4*)(src + i);
  float4 b = *(const float4*)(src + i + 4);
  *(bf16x8*)(dst + i) = to_bf8(a, b);
}

// ---------------------------------------------------------------------------
// Deep-prefetch GEMM: C[M,N] = A[M,K] @ W[N,K]^T (+bias)(+relu), bf16 in.
// BK=32, quad-buffered LDS, depth-3 prefetch, counted vmcnt(8) at the
// barrier (loads stay in flight across it - T4), setprio around MFMA (T5),
// swizzled LDS (verified 0-conflict), bijective XCD grid swizzle.
// Variants: RW=8,WM=2,WN=4 -> 256x256 tile, 512 thr, 128 KB LDS, 1 blk/CU.
//           RW=4,WM=2,WN=2 -> 128x128 tile, 256 thr,  64 KB LDS, 2 blk/CU.
// ---------------------------------------------------------------------------
template<int T, int BM>
__device__ inline void stage2(const __bf16* __restrict__ Ab,
                              const __bf16* __restrict__ Wb,
                              __bf16* la, __bf16* lb, int K, int k0, int t) {
  const int col8 = (t & 3) ^ ((t >> 3) & 3);   // inverse-swizzled source col
  const int cofs = k0 + col8 * 8;
  const int wbase = (t >> 6) * 512;            // wave-uniform LDS base (elems)
#pragma unroll
  for (int p = 0; p < (BM * 32) / (T * 8); ++p) {
    const int row = p * (T >> 2) + (t >> 2);
    gload16(Ab + (size_t)row * K + cofs, la + p * T * 8 + wbase);
    gload16(Wb + (size_t)row * K + cofs, lb + p * T * 8 + wbase);
  }
}

template<int RW, int WM, int WN, bool BIAS, bool RELU, bool OUTBF16>
__global__ __launch_bounds__(WM*WN*64, 2) void gemm_deep(
    const __bf16* __restrict__ A, const __bf16* __restrict__ W,
    const float* __restrict__ bias, void* __restrict__ Cv,
    int N, int K, int nbx) {
  constexpr int T  = WM * WN * 64;
  constexpr int BM = WM * RW * 16;             // == BN
  __shared__ __bf16 lds[4][2][BM * 32];
  const int t = threadIdx.x, l = t & 63, w = t >> 6;
  const int nwg = gridDim.x, orig = blockIdx.x;
  const int q = nwg >> 3, r = nwg & 7, xcd = orig & 7, pos = orig >> 3;
  const int wgid = (xcd < r ? xcd*(q+1) : r*(q+1) + (xcd-r)*q) + pos;
  const int m0 = (wgid % nbx) * BM, n0 = (wgid / nbx) * BM;
  const int wm = w / WN, wn = w % WN;
  const int fr = l & 15, c8 = l >> 4;
  const int slot = (c8 ^ ((fr >> 1) & 3)) * 8;

  const __bf16* Abase = A + (size_t)m0 * K;
  const __bf16* Wbase = W + (size_t)n0 * K;

  f32x4 acc[RW][4] = {};

  const int nk = K >> 5;
  stage2<T,BM>(Abase, Wbase, &lds[0][0][0], &lds[0][1][0], K, 0,  t);
  stage2<T,BM>(Abase, Wbase, &lds[1][0][0], &lds[1][1][0], K, 32, t);
  stage2<T,BM>(Abase, Wbase, &lds[2][0][0], &lds[2][1][0], K, 64, t);

  for (int kt = 0; kt < nk; ++kt) {
    const int cur = kt & 3;
    if (kt + 3 < nk) {
      const int nb = (kt + 3) & 3;
      stage2<T,BM>(Abase, Wbase, &lds[nb][0][0], &lds[nb][1][0], K, (kt+3)*32, t);
      asm volatile("s_waitcnt vmcnt(8)" ::: "memory");   // tile kt landed
    } else if (kt + 2 < nk) {
      asm volatile("s_waitcnt vmcnt(8)" ::: "memory");
    } else if (kt + 1 < nk) {
      asm volatile("s_waitcnt vmcnt(4)" ::: "memory");
    } else {
      asm volatile("s_waitcnt vmcnt(0)" ::: "memory");
    }
    __builtin_amdgcn_s_barrier();                // all waves' tile-kt data in LDS
    __builtin_amdgcn_sched_barrier(0);
    const __bf16* La = &lds[cur][0][0];
    const __bf16* Lb = &lds[cur][1][0];
    bf16x8 bfr[4];
#pragma unroll
    for (int j = 0; j < 4; ++j)
      bfr[j] = *(const bf16x8*)&Lb[(wn*64 + j*16 + fr) * 32 + slot];
    __builtin_amdgcn_s_setprio(1);
#pragma unroll
    for (int i = 0; i < RW; ++i) {
      bf16x8 af = *(const bf16x8*)&La[(wm*(RW*16) + i*16 + fr) * 32 + slot];
#pragma unroll
      for (int j = 0; j < 4; ++j)
        acc[i][j] = __builtin_amdgcn_mfma_f32_16x16x32_bf16(af, bfr[j], acc[i][j], 0, 0, 0);
    }
    __builtin_amdgcn_s_setprio(0);
    __builtin_amdgcn_sched_barrier(0);
    __builtin_amdgcn_s_barrier();                // reads done before buf reuse
    __builtin_amdgcn_sched_barrier(0);
  }

  const int orow = m0 + wm*(RW*16) + c8 * 4;
  const int ocol = n0 + wn*64 + fr;
#pragma unroll
  for (int i = 0; i < RW; ++i)
#pragma unroll
    for (int j = 0; j < 4; ++j) {
      const int col = ocol + j * 16;
      const float bv = BIAS ? bias[col] : 0.0f;
#pragma unroll
      for (int rr = 0; rr < 4; ++rr) {
        float v = acc[i][j][rr] + bv;
        if (RELU) v = fmaxf(v, 0.0f);
        if (OUTBF16)
          ((__bf16*)Cv)[(size_t)(orow + i*16 + rr) * N + col] = (__bf16)v;
        else
          ((float*)Cv)[(size_t)(orow + i*16 + rr) * N + col] = v;
      }
    }
}

// ---------------------------------------------------------------------------
// 128x128 2-phase GEMM (fallback unembed only: fp32 W reg-staged).
// ---------------------------------------------------------------------------
template<bool WBF16, bool BIAS, bool RELU, bool OUTBF16>
__global__ __launch_bounds__(256) void gemm_fast(
    const __bf16* __restrict__ A, const void* __restrict__ Wv,
    const float* __restrict__ bias, void* __restrict__ Cv, int N, int K) {
  __shared__ __bf16 As[128][32];
  __shared__ __bf16 Bs[128][32];
  const int t = threadIdx.x;
  const int m0 = blockIdx.x * 128, n0 = blockIdx.y * 128;
  const int l = t & 63, w = t >> 6;
  const int wm = (w >> 1) * 64, wn = (w & 1) * 64;
  const int fr = l & 15, fk = (l >> 4) * 8;
  const int crow = l >> 2, ccol = (l & 3) * 8;
  const int wrow = t >> 1, wcol = (t & 1) * 16;

  const __bf16* Wb = (const __bf16*)Wv;
  const float*  Wf = (const float*)Wv;

  f32x4 acc[4][4] = {};

  for (int k0 = 0; k0 < K; k0 += 32) {
    float4 wf0, wf1, wf2, wf3;
    if (!WBF16) {
      const float* wp = Wf + (size_t)(n0 + wrow) * K + k0 + wcol;
      wf0 = *(const float4*)(wp);
      wf1 = *(const float4*)(wp + 4);
      wf2 = *(const float4*)(wp + 8);
      wf3 = *(const float4*)(wp + 12);
    }
    __syncthreads();
#pragma unroll
    for (int i = 0; i < 2; ++i) {
      const int c = 2 * w + i;
      gload16(A + (size_t)(m0 + c*16 + crow) * K + k0 + ccol, (__bf16*)As + c*512);
      if (WBF16)
        gload16(Wb + (size_t)(n0 + c*16 + crow) * K + k0 + ccol, (__bf16*)Bs + c*512);
    }
    if (!WBF16) {
      *(bf16x8*)&Bs[wrow][wcol]     = to_bf8(wf0, wf1);
      *(bf16x8*)&Bs[wrow][wcol + 8] = to_bf8(wf2, wf3);
    }
    __syncthreads();
    bf16x8 af[4], bf[4];
#pragma unroll
    for (int i = 0; i < 4; ++i) af[i] = *(const bf16x8*)&As[wm + i*16 + fr][fk];
#pragma unroll
    for (int j = 0; j < 4; ++j) bf[j] = *(const bf16x8*)&Bs[wn + j*16 + fr][fk];
#pragma unroll
    for (int i = 0; i < 4; ++i)
#pragma unroll
      for (int j = 0; j < 4; ++j)
        acc[i][j] = __builtin_amdgcn_mfma_f32_16x16x32_bf16(af[i], bf[j], acc[i][j], 0, 0, 0);
  }

  const int orow = m0 + wm + (l >> 4) * 4;
  const int ocol = n0 + wn + fr;
#pragma unroll
  for (int i = 0; i < 4; ++i)
#pragma unroll
    for (int j = 0; j < 4; ++j) {
      const int col = ocol + j * 16;
      const float bv = BIAS ? bias[col] : 0.0f;
#pragma unroll
      for (int r = 0; r < 4; ++r) {
        float v = acc[i][j][r] + bv;
        if (RELU) v = fmaxf(v, 0.0f);
        if (OUTBF16)
          ((__bf16*)Cv)[(size_t)(orow + i*16 + r) * N + col] = (__bf16)v;
        else
          ((float*)Cv)[(size_t)(orow + i*16 + r) * N + col] = v;
      }
    }
}

// ---------------------------------------------------------------------------
// x = LN(y + x) * s + b ; also emit bf16 copy xb.
// ---------------------------------------------------------------------------
__global__ __launch_bounds__(256) void ln_res_kernel(
    const float* __restrict__ y, float* __restrict__ x, __bf16* __restrict__ xb,
    const float* __restrict__ sc, const float* __restrict__ bs) {
  __shared__ float red[8];
  int row = blockIdx.x, t = threadIdx.x;
  const float4* y4 = (const float4*)(y + (size_t)row * EE);
  float4* x4 = (float4*)(x + (size_t)row * EE);
  float4 a = y4[t], c = x4[t];
  float v0 = a.x + c.x, v1 = a.y + c.y, v2 = a.z + c.z, v3 = a.w + c.w;
  float s = v0 + v1 + v2 + v3;
  float q = v0*v0 + v1*v1 + v2*v2 + v3*v3;
#pragma unroll
  for (int off = 32; off; off >>= 1) {
    s += __shfl_xor(s, off);
    q += __shfl_xor(q, off);
  }
  int w = t >> 6;
  if ((t & 63) == 0) { red[w] = s; red[4 + w] = q; }
  __syncthreads();
  s = red[0] + red[1] + red[2] + red[3];
  q = red[4] + red[5] + red[6] + red[7];
  float mean = s * (1.0f / EE);
  float var  = q * (1.0f / EE) - mean * mean;
  float r = 1.0f / sqrtf(var + 1e-6f);
  float4 ss = ((const float4*)sc)[t];
  float4 bb = ((const float4*)bs)[t];
  float4 o;
  o.x = (v0 - mean) * r * ss.x + bb.x;
  o.y = (v1 - mean) * r * ss.y + bb.y;
  o.z = (v2 - mean) * r * ss.z + bb.z;
  o.w = (v3 - mean) * r * ss.w + bb.w;
  x4[t] = o;
  bf16x4 ob4;
  ob4[0] = (__bf16)o.x; ob4[1] = (__bf16)o.y; ob4[2] = (__bf16)o.z; ob4[3] = (__bf16)o.w;
  *(bf16x4*)(xb + (size_t)row * EE + t * 4) = ob4;
}

// ---------------------------------------------------------------------------
// MFMA flash attention (unchanged, verified).
// ---------------------------------------------------------------------------
__global__ __launch_bounds__(256) void attn_mfma(
    const __bf16* __restrict__ qkv, const int* __restrict__ ls,
    __bf16* __restrict__ out) {
  const int qt = 15 - blockIdx.x;
  const int h = blockIdx.y, b = blockIdx.z;
  __shared__ f32x4 lds4[2304];             // 36864 B
  char* lds = (char*)lds4;
  __bf16* Ks = (__bf16*)lds;               // [64][72]
  __bf16* Vs = (__bf16*)(lds + 9216);      // [64][72] transposed (d-major)
  __shared__ int redmin[4];
  const int t = threadIdx.x, w = t >> 6, l = t & 63;
  __bf16* Pq = (__bf16*)(lds + 18432 + w * 4608);  // [32][72] per wave
  const int r = l & 31, hi = l >> 5;
  const int qb = qt * 128, qw = qb + w * 32, qg = qw + r;
  const int Lq = ls[b*SS + qg];

  {
    int mn = Lq;
#pragma unroll
    for (int off = 1; off < 64; off <<= 1) mn = min(mn, __shfl_xor(mn, off));
    if (l == 0) redmin[w] = mn;
  }

  bf16x8 qf[4];
  {
    const __bf16* qrow = qkv + (size_t)(b*SS + qg) * 3*EE + EE + h*DD + 8*hi;
#pragma unroll
    for (int ds = 0; ds < 4; ++ds) qf[ds] = *(const bf16x8*)(qrow + 16*ds);
  }
  __syncthreads();
  const int ktmin = min(min(redmin[0], redmin[1]), min(redmin[2], redmin[3])) >> 6;
  const int ktmax = 2*qt + 1;

  f32x16 oacc[2] = {};
  float m_r = NEG_HUGE, lsum = 0.0f;

  for (int kt = ktmin; kt <= ktmax; ++kt) {
    __syncthreads();
    {
      const int kr = t >> 2, c0 = (t & 3) * 16;
      const __bf16* kg = qkv + (size_t)(b*SS + kt*64 + kr) * 3*EE + h*DD + c0;
      const __bf16* vg = kg + 2*EE;
      bf16x8 k0 = *(const bf16x8*)kg;
      bf16x8 k1 = *(const bf16x8*)(kg + 8);
      bf16x8 v0 = *(const bf16x8*)vg;
      bf16x8 v1 = *(const bf16x8*)(vg + 8);
      *(bf16x8*)&Ks[kr*72 + c0]     = k0;
      *(bf16x8*)&Ks[kr*72 + c0 + 8] = k1;
      const int vc = (kr + 8*(t & 3)) & 63;
#pragma unroll
      for (int j = 0; j < 8; ++j) {
        Vs[(c0 + j)*72 + vc]     = v0[j];
        Vs[(c0 + 8 + j)*72 + vc] = v1[j];
      }
    }
    __syncthreads();

    bool act0 = (kt*64)      <= (qw + 31);
    bool act1 = (kt*64 + 32) <= (qw + 31);
    if (!act0) continue;

    f32x16 st[2];
    st[0] = (f32x16){};
    st[1] = (f32x16){};
#pragma unroll
    for (int ds = 0; ds < 4; ++ds) {
      bf16x8 kf = *(const bf16x8*)&Ks[(r)*72 + 16*ds + 8*hi];
      st[0] = __builtin_amdgcn_mfma_f32_32x32x16_bf16(kf, qf[ds], st[0], 0, 0, 0);
    }
    if (act1) {
#pragma unroll
      for (int ds = 0; ds < 4; ++ds) {
        bf16x8 kf = *(const bf16x8*)&Ks[(32 + r)*72 + 16*ds + 8*hi];
        st[1] = __builtin_amdgcn_mfma_f32_32x32x16_bf16(kf, qf[ds], st[1], 0, 0, 0);
      }
    }

    float tmax = NEG_HUGE;
#pragma unroll
    for (int kt2 = 0; kt2 < 2; ++kt2) {
#pragma unroll
      for (int reg = 0; reg < 16; ++reg) {
        const int key = kt*64 + 32*kt2 + (reg & 3) + 8*(reg >> 2) + 4*hi;
        float s = (kt2 == 0 || act1) ? st[kt2][reg] * 0.125f : NEG_HUGE;
        const bool valid = (key >= Lq) && (key <= qg);
        s = valid ? s : NEG_HUGE;
        st[kt2][reg] = s;
        tmax = fmaxf(tmax, s);
      }
    }
    tmax = fmaxf(tmax, __shfl_xor(tmax, 32));
    const float m_new = fmaxf(m_r, tmax);
    const float alpha = __expf(m_r - m_new);
    m_r = m_new;

    float psum = 0.0f;
#pragma unroll
    for (int kt2 = 0; kt2 < 2; ++kt2) {
#pragma unroll
      for (int g2 = 0; g2 < 4; ++g2) {
        bf16x4 pk;
#pragma unroll
        for (int j = 0; j < 4; ++j) {
          float p = __expf(st[kt2][g2*4 + j] - m_new);
          psum += p;
          pk[j] = (__bf16)p;
        }
        *(bf16x4*)&Pq[r*72 + 32*kt2 + 8*g2 + 4*hi] = pk;
      }
    }
    psum += __shfl_xor(psum, 32);
    lsum = lsum * alpha + psum;
    oacc[0] *= alpha;
    oacc[1] *= alpha;

#pragma unroll
    for (int ks = 0; ks < 4; ++ks) {
      if (kt*64 + 16*ks > qw + 31) continue;
      bf16x8 pf = *(const bf16x8*)&Pq[r*72 + 16*ks + 8*hi];
#pragma unroll
      for (int mt = 0; mt < 2; ++mt) {
        const int d = 32*mt + r;
        const int vcol = (16*ks + 8*hi + 8*((d >> 4) & 3)) & 63;
        bf16x8 vf = *(const bf16x8*)&Vs[d*72 + vcol];
        oacc[mt] = __builtin_amdgcn_mfma_f32_32x32x16_bf16(vf, pf, oacc[mt], 0, 0, 0);
      }
    }
  }

  __syncthreads();
  float* Ot = (float*)(lds + w * 8448);        // [64][33] f32 per wave
  const float rinv = 1.0f / lsum;
#pragma unroll
  for (int mt = 0; mt < 2; ++mt)
#pragma unroll
    for (int reg = 0; reg < 16; ++reg) {
      const int d = 32*mt + (reg & 3) + 8*(reg >> 2) + 4*hi;
      Ot[d*33 + r] = oacc[mt][reg] * rinv;
    }
  __syncthreads();
  const int qr0 = l >> 4, dc = (l & 15) * 4;
#pragma unroll
  for (int it = 0; it < 8; ++it) {
    const int qr = qr0 + 4*it;
    bf16x4 ov;
    ov[0] = (__bf16)Ot[(dc+0)*33 + qr];
    ov[1] = (__bf16)Ot[(dc+1)*33 + qr];
    ov[2] = (__bf16)Ot[(dc+2)*33 + qr];
    ov[3] = (__bf16)Ot[(dc+3)*33 + qr];
    *(bf16x4*)(out + (size_t)(b*SS + qw + qr) * EE + h*DD + dc) = ov;
  }
}

// ---------------------------------------------------------------------------
extern "C" void kernel_launch(void* const* d_in, const int* in_sizes, int n_in,
                              void* d_out, int out_size, void* d_ws, size_t ws_size,
                              hipStream_t stream) {
  const int*   tokens     = (const int*)  d_in[0];
  const float* word_embed = (const float*)d_in[1];
  const float* pos_embed  = (const float*)d_in[2];
  const float* unembed_b  = (const float*)d_in[3];
  const float* kqv_w      = (const float*)d_in[4];
  const float* wo_w       = (const float*)d_in[5];
  const float* up_w       = (const float*)d_in[6];
  const float* up_b       = (const float*)d_in[7];
  const float* down_w     = (const float*)d_in[8];
  const float* down_b     = (const float*)d_in[9];
  const float* ln1_s      = (const float*)d_in[10];
  const float* ln1_b      = (const float*)d_in[11];
  const float* ln2_s      = (const float*)d_in[12];
  const float* ln2_b      = (const float*)d_in[13];
  float* logits = (float*)d_out;

  // d_out (524 MB) scratch map (all dead before the final GEMM writes logits):
  char* ob = (char*)d_out;
  __bf16* qkv  = (__bf16*)ob;                          // 24 MB
  __bf16* t0   = (__bf16*)(ob +  24ull*1024*1024);     //  8 MB
  __bf16* hbuf = (__bf16*)(ob +  32ull*1024*1024);     // 32 MB
  float*  ybuf = (float*) (ob +  64ull*1024*1024);     // 16 MB
  __bf16* wcvt = (__bf16*)(ob +  80ull*1024*1024);     // 50.4 MB bf16 weights
  float*  x    = (float*) (ob + 131ull*1024*1024);     // 16 MB fp32 residual
  __bf16* kqvb  = wcvt;
  __bf16* wob   = kqvb + (size_t)LL*3*EE*EE;
  __bf16* upb   = wob  + (size_t)LL*EE*EE;
  __bf16* downb = upb  + (size_t)LL*FF*EE;
  // ws: only what must survive the final GEMM (which overwrites all of d_out).
  int*    ls   = (int*)d_ws;                            // 64 KB
  __bf16* xb   = (__bf16*)((char*)d_ws + 65536);        // 8 MB
  __bf16* webf = (__bf16*)((char*)d_ws + 65536 + 8ull*1024*1024);
  const bool bigws = ws_size >= (size_t)(65536 + 8ull*1024*1024 + (size_t)VV*EE*2);

  lastart_scan<<<BB, 1024, 0, stream>>>(tokens, ls);
  embed_kernel<<<BS, 256, 0, stream>>>(tokens, ls, word_embed, pos_embed, x, xb);

  // weight pre-conversion (fp32 -> bf16)
  cvt_bf16_kernel<<<LL*3*EE*EE/2048, 256, 0, stream>>>(kqv_w,  kqvb,  LL*3*EE*EE);
  cvt_bf16_kernel<<<LL*EE*EE/2048,   256, 0, stream>>>(wo_w,   wob,   LL*EE*EE);
  cvt_bf16_kernel<<<LL*FF*EE/2048,   256, 0, stream>>>(up_w,   upb,   LL*FF*EE);
  cvt_bf16_kernel<<<LL*EE*FF/2048,   256, 0, stream>>>(down_w, downb, LL*EE*FF);
  if (bigws)
    cvt_bf16_kernel<<<VV*EE/2048, 256, 0, stream>>>(word_embed, webf, VV*EE);

  for (int l = 0; l < LL; ++l) {
    gemm_deep<8,2,4,false,false,true><<<(BS/256)*(3*EE/256), 512, 0, stream>>>(
        xb, kqvb + (size_t)l*3*EE*EE, nullptr, qkv, 3*EE, EE, BS/256);
    attn_mfma<<<dim3(16, HH, BB), 256, 0, stream>>>(qkv, ls, t0);
    gemm_deep<4,2,2,false,false,false><<<(BS/128)*(EE/128), 256, 0, stream>>>(
        t0, wob + (size_t)l*EE*EE, nullptr, ybuf, EE, EE, BS/128);
    ln_res_kernel<<<BS, 256, 0, stream>>>(ybuf, x, xb, ln1_s + l*EE, ln1_b + l*EE);
    gemm_deep<8,2,4,true,true,true><<<(BS/256)*(FF/256), 512, 0, stream>>>(
        xb, upb + (size_t)l*FF*EE, up_b + (size_t)l*FF, hbuf, FF, EE, BS/256);
    gemm_deep<4,2,2,true,false,false><<<(BS/128)*(EE/128), 256, 0, stream>>>(
        hbuf, downb + (size_t)l*EE*FF, down_b + (size_t)l*EE, ybuf, EE, FF, BS/128);
    ln_res_kernel<<<BS, 256, 0, stream>>>(ybuf, x, xb, ln2_s + l*EE, ln2_b + l*EE);
  }

  if (bigws)
    gemm_deep<8,2,4,true,false,false><<<(BS/256)*(VV/256), 512, 0, stream>>>(
        xb, webf, unembed_b, logits, VV, EE, BS/256);
  else
    gemm_fast<false,true,false,false><<<dim3(BS/128, VV/128), 256, 0, stream>>>(
        xb, word_embed, unembed_b, logits, VV, EE);
}

// Round 7
// 982.996 us; speedup vs baseline: 14.1279x; 1.0289x over previous
//
#include <hip/hip_runtime.h>
#include <hip/hip_bf16.h>

#define BB 2
#define SS 2048
#define EE 1024
#define HH 16
#define DD 64
#define FF 4096
#define VV 32000
#define LL 2
#define BS (BB*SS)

#define NEG_HUGE (-3.402823466e+38f)

typedef __attribute__((ext_vector_type(4)))  float  f32x4;
typedef __attribute__((ext_vector_type(16))) float  f32x16;
typedef __attribute__((ext_vector_type(8)))  __bf16 bf16x8;
typedef __attribute__((ext_vector_type(4)))  __bf16 bf16x4;

__device__ inline bf16x8 to_bf8(float4 a, float4 b) {
  bf16x8 r;
  r[0] = (__bf16)a.x; r[1] = (__bf16)a.y; r[2] = (__bf16)a.z; r[3] = (__bf16)a.w;
  r[4] = (__bf16)b.x; r[5] = (__bf16)b.y; r[6] = (__bf16)b.z; r[7] = (__bf16)b.w;
  return r;
}

typedef const unsigned int __attribute__((address_space(1)))* gptr_t;
typedef unsigned int __attribute__((address_space(3)))* lptr_t;
__device__ inline void gload16(const void* g, void* l) {
  __builtin_amdgcn_global_load_lds((gptr_t)g, (lptr_t)l, 16, 0, 0);
}

// ---------------------------------------------------------------------------
// last_start via parallel max-scan (1 block per batch row).
// ---------------------------------------------------------------------------
__global__ __launch_bounds__(1024) void lastart_scan(
    const int* __restrict__ tokens, int* __restrict__ ls) {
  __shared__ int buf[SS];
  const int b = blockIdx.x, t = threadIdx.x;
#pragma unroll
  for (int j = 0; j < 2; ++j) {
    int i = t + j * 1024;
    buf[i] = (i > 0 && tokens[b*SS + i] == 1) ? i : 0;
  }
  __syncthreads();
  for (int off = 1; off < SS; off <<= 1) {
    int i0 = t, i1 = t + 1024;
    int v0 = (i0 >= off) ? max(buf[i0], buf[i0 - off]) : buf[i0];
    int v1 = (i1 >= off) ? max(buf[i1], buf[i1 - off]) : buf[i1];
    __syncthreads();
    buf[i0] = v0; buf[i1] = v1;
    __syncthreads();
  }
#pragma unroll
  for (int j = 0; j < 2; ++j) {
    int i = t + j * 1024;
    ls[b*SS + i] = buf[i];
  }
}

__global__ __launch_bounds__(256) void embed_kernel(
    const int* __restrict__ tokens, const int* __restrict__ ls,
    const float* __restrict__ we, const float* __restrict__ pe,
    float* __restrict__ x, __bf16* __restrict__ xb) {
  int row = blockIdx.x;
  int s = row & (SS - 1);
  int tok = tokens[row];
  int rp = s - ls[row];
  const float4* w4 = (const float4*)(we + (size_t)tok * EE);
  const float4* p4 = (const float4*)(pe + (size_t)rp * EE);
  float4 a = w4[threadIdx.x];
  float4 b = p4[threadIdx.x];
  float4 o; o.x = a.x + b.x; o.y = a.y + b.y; o.z = a.z + b.z; o.w = a.w + b.w;
  ((float4*)(x + (size_t)row * EE))[threadIdx.x] = o;
  bf16x4 ob4;
  ob4[0] = (__bf16)o.x; ob4[1] = (__bf16)o.y; ob4[2] = (__bf16)o.z; ob4[3] = (__bf16)o.w;
  *(bf16x4*)(xb + (size_t)row * EE + threadIdx.x * 4) = ob4;
}

// ---------------------------------------------------------------------------
__global__ __launch_bounds__(256) void cvt_bf16_kernel(
    const float* __restrict__ src, __bf16* __restrict__ dst, int n) {
  int i = (blockIdx.x * 256 + threadIdx.x) * 8;
  if (i + 8 > n) return;
  float4 a = *(const float4*)(src + i);
  float4 b = *(const float4*)(src + i + 4);
  *(bf16x8*)(dst + i) = to_bf8(a, b);
}

// ---------------------------------------------------------------------------
// 8-phase 256x256 GEMM (m201 schedule): C = A[M,K] @ W[N,K]^T (+bias)(+relu).
// BK=64. LDS = 2 dbuf x {A,B} x {kh0,kh1} regions of 256x32 bf16 (128 KB).
// 512 thr = 8 waves (2M x 4N), per-wave C 128x64 = acc[8][4].
// Per K-tile, 4 phases of 16 MFMA: {ds_read (8 or 4 b128) | stage one half |
// barrier | setprio MFMA x16 | barrier}. Stage targets are dead regions:
// tile kt stages [A1(kt+1), B1(kt+1), A0(kt+2), B0(kt+2)] in phases 1-4.
// Counted vmcnt(8) at phase-2/phase-4 ends only (4 halves in flight);
// tail: 8 -> 4 -> 0. Swizzle per region verified 0-conflict (r5/r6).
// ---------------------------------------------------------------------------
__device__ inline void stage_half(const __bf16* __restrict__ base,
                                  __bf16* region, int K, int kofs, int t) {
  const int col8 = (t & 3) ^ ((t >> 3) & 3);   // inverse-swizzled source chunk
  const int csrc = kofs + col8 * 8;
  const int wbase = (t >> 6) * 512;            // wave-uniform dest base (elems)
#pragma unroll
  for (int p = 0; p < 2; ++p)
    gload16(base + (size_t)(p * 128 + (t >> 2)) * K + csrc, region + p * 4096 + wbase);
}

#define SWZ(row) ((c8 ^ (((row) >> 1) & 3)) * 8)

template<bool BIAS, bool RELU, bool OUTBF16>
__global__ __launch_bounds__(512, 2) void gemm_8ph(
    const __bf16* __restrict__ A, const __bf16* __restrict__ W,
    const float* __restrict__ bias, void* __restrict__ Cv,
    int N, int K, int nbx) {
  __shared__ __bf16 lds[2][2][2][8192];        // [dbuf][A|B][khalf][256*32]
  const int t = threadIdx.x, l = t & 63, w = t >> 6;
  const int nwg = gridDim.x, orig = blockIdx.x;
  const int q = nwg >> 3, r = nwg & 7, xcd = orig & 7, pos = orig >> 3;
  const int wgid = (xcd < r ? xcd*(q+1) : r*(q+1) + (xcd-r)*q) + pos;
  const int m0 = (wgid % nbx) * 256, n0 = (wgid / nbx) * 256;
  const int wm = w >> 2, wn = w & 3;
  const int fr = l & 15, c8 = l >> 4;

  const __bf16* Ab = A + (size_t)m0 * K;
  const __bf16* Wb = W + (size_t)n0 * K;

  f32x4 acc[8][4] = {};
  const int nk = K >> 6;

  // prologue: halves h0..h5 = tile0{A0,B0,A1,B1} + tile1{A0,B0}
  stage_half(Ab, &lds[0][0][0][0], K, 0,  t);
  stage_half(Wb, &lds[0][1][0][0], K, 0,  t);
  stage_half(Ab, &lds[0][0][1][0], K, 32, t);
  stage_half(Wb, &lds[0][1][1][0], K, 32, t);
  stage_half(Ab, &lds[1][0][0][0], K, 64, t);
  stage_half(Wb, &lds[1][1][0][0], K, 64, t);
  asm volatile("s_waitcnt vmcnt(4)" ::: "memory");  // tile0 fully landed
  __builtin_amdgcn_s_barrier();
  __builtin_amdgcn_sched_barrier(0);

  for (int kt = 0; kt < nk; ++kt) {
    const int c = kt & 1;
    bf16x8 afr[4], bfr[4];
    // ---- P1: kh0, i 0-3 ---------------------------------------------------
#pragma unroll
    for (int j = 0; j < 4; ++j) {
      const int row = wn*64 + j*16 + fr;
      bfr[j] = *(const bf16x8*)&lds[c][1][0][row*32 + SWZ(row)];
    }
#pragma unroll
    for (int i = 0; i < 4; ++i) {
      const int row = wm*128 + i*16 + fr;
      afr[i] = *(const bf16x8*)&lds[c][0][0][row*32 + SWZ(row)];
    }
    if (kt + 1 < nk) stage_half(Ab, &lds[c^1][0][1][0], K, (kt+1)*64 + 32, t);
    __builtin_amdgcn_s_barrier();
    __builtin_amdgcn_sched_barrier(0);
    __builtin_amdgcn_s_setprio(1);
#pragma unroll
    for (int i = 0; i < 4; ++i)
#pragma unroll
      for (int j = 0; j < 4; ++j)
        acc[i][j] = __builtin_amdgcn_mfma_f32_16x16x32_bf16(afr[i], bfr[j], acc[i][j], 0, 0, 0);
    __builtin_amdgcn_s_setprio(0);
    __builtin_amdgcn_sched_barrier(0);
    __builtin_amdgcn_s_barrier();
    __builtin_amdgcn_sched_barrier(0);
    // ---- P2: kh0, i 4-7 ---------------------------------------------------
#pragma unroll
    for (int i = 0; i < 4; ++i) {
      const int row = wm*128 + (i+4)*16 + fr;
      afr[i] = *(const bf16x8*)&lds[c][0][0][row*32 + SWZ(row)];
    }
    if (kt + 1 < nk) stage_half(Wb, &lds[c^1][1][1][0], K, (kt+1)*64 + 32, t);
    __builtin_amdgcn_s_barrier();
    __builtin_amdgcn_sched_barrier(0);
    __builtin_amdgcn_s_setprio(1);
#pragma unroll
    for (int i = 0; i < 4; ++i)
#pragma unroll
      for (int j = 0; j < 4; ++j)
        acc[i+4][j] = __builtin_amdgcn_mfma_f32_16x16x32_bf16(afr[i], bfr[j], acc[i+4][j], 0, 0, 0);
    __builtin_amdgcn_s_setprio(0);
    __builtin_amdgcn_sched_barrier(0);
    if (kt < nk - 1) { asm volatile("s_waitcnt vmcnt(8)" ::: "memory"); }
    else             { asm volatile("s_waitcnt vmcnt(0)" ::: "memory"); }
    __builtin_amdgcn_s_barrier();
    __builtin_amdgcn_sched_barrier(0);
    // ---- P3: kh1, i 0-3 ---------------------------------------------------
#pragma unroll
    for (int j = 0; j < 4; ++j) {
      const int row = wn*64 + j*16 + fr;
      bfr[j] = *(const bf16x8*)&lds[c][1][1][row*32 + SWZ(row)];
    }
#pragma unroll
    for (int i = 0; i < 4; ++i) {
      const int row = wm*128 + i*16 + fr;
      afr[i] = *(const bf16x8*)&lds[c][0][1][row*32 + SWZ(row)];
    }
    if (kt + 2 < nk) stage_half(Ab, &lds[c][0][0][0], K, (kt+2)*64, t);
    __builtin_amdgcn_s_barrier();
    __builtin_amdgcn_sched_barrier(0);
    __builtin_amdgcn_s_setprio(1);
#pragma unroll
    for (int i = 0; i < 4; ++i)
#pragma unroll
      for (int j = 0; j < 4; ++j)
        acc[i][j] = __builtin_amdgcn_mfma_f32_16x16x32_bf16(afr[i], bfr[j], acc[i][j], 0, 0, 0);
    __builtin_amdgcn_s_setprio(0);
    __builtin_amdgcn_sched_barrier(0);
    __builtin_amdgcn_s_barrier();
    __builtin_amdgcn_sched_barrier(0);
    // ---- P4: kh1, i 4-7 ---------------------------------------------------
#pragma unroll
    for (int i = 0; i < 4; ++i) {
      const int row = wm*128 + (i+4)*16 + fr;
      afr[i] = *(const bf16x8*)&lds[c][0][1][row*32 + SWZ(row)];
    }
    if (kt + 2 < nk) stage_half(Wb, &lds[c][1][0][0], K, (kt+2)*64, t);
    __builtin_amdgcn_s_barrier();
    __builtin_amdgcn_sched_barrier(0);
    __builtin_amdgcn_s_setprio(1);
#pragma unroll
    for (int i = 0; i < 4; ++i)
#pragma unroll
      for (int j = 0; j < 4; ++j)
        acc[i+4][j] = __builtin_amdgcn_mfma_f32_16x16x32_bf16(afr[i], bfr[j], acc[i+4][j], 0, 0, 0);
    __builtin_amdgcn_s_setprio(0);
    __builtin_amdgcn_sched_barrier(0);
    if (kt < nk - 2)       { asm volatile("s_waitcnt vmcnt(8)" ::: "memory"); }
    else if (kt == nk - 2) { asm volatile("s_waitcnt vmcnt(4)" ::: "memory"); }
    __builtin_amdgcn_s_barrier();
    __builtin_amdgcn_sched_barrier(0);
  }

  const int orow = m0 + wm*128 + c8 * 4;
  const int ocol = n0 + wn*64 + fr;
#pragma unroll
  for (int i = 0; i < 8; ++i)
#pragma unroll
    for (int j = 0; j < 4; ++j) {
      const int col = ocol + j * 16;
      const float bv = BIAS ? bias[col] : 0.0f;
#pragma unroll
      for (int rr = 0; rr < 4; ++rr) {
        float v = acc[i][j][rr] + bv;
        if (RELU) v = fmaxf(v, 0.0f);
        if (OUTBF16)
          ((__bf16*)Cv)[(size_t)(orow + i*16 + rr) * N + col] = (__bf16)v;
        else
          ((float*)Cv)[(size_t)(orow + i*16 + rr) * N + col] = v;
      }
    }
}

// ---------------------------------------------------------------------------
// Deep-prefetch 128x128 GEMM (round-6 verified; wo/down shapes).
// ---------------------------------------------------------------------------
template<int T, int BM>
__device__ inline void stage2(const __bf16* __restrict__ Ab,
                              const __bf16* __restrict__ Wb,
                              __bf16* la, __bf16* lb, int K, int k0, int t) {
  const int col8 = (t & 3) ^ ((t >> 3) & 3);
  const int cofs = k0 + col8 * 8;
  const int wbase = (t >> 6) * 512;
#pragma unroll
  for (int p = 0; p < (BM * 32) / (T * 8); ++p) {
    const int row = p * (T >> 2) + (t >> 2);
    gload16(Ab + (size_t)row * K + cofs, la + p * T * 8 + wbase);
    gload16(Wb + (size_t)row * K + cofs, lb + p * T * 8 + wbase);
  }
}

template<int RW, int WM, int WN, bool BIAS, bool RELU, bool OUTBF16>
__global__ __launch_bounds__(WM*WN*64, 2) void gemm_deep(
    const __bf16* __restrict__ A, const __bf16* __restrict__ W,
    const float* __restrict__ bias, void* __restrict__ Cv,
    int N, int K, int nbx) {
  constexpr int T  = WM * WN * 64;
  constexpr int BM = WM * RW * 16;
  __shared__ __bf16 lds[4][2][BM * 32];
  const int t = threadIdx.x, l = t & 63, w = t >> 6;
  const int nwg = gridDim.x, orig = blockIdx.x;
  const int q = nwg >> 3, r = nwg & 7, xcd = orig & 7, pos = orig >> 3;
  const int wgid = (xcd < r ? xcd*(q+1) : r*(q+1) + (xcd-r)*q) + pos;
  const int m0 = (wgid % nbx) * BM, n0 = (wgid / nbx) * BM;
  const int wm = w / WN, wn = w % WN;
  const int fr = l & 15, c8 = l >> 4;
  const int slot = (c8 ^ ((fr >> 1) & 3)) * 8;

  const __bf16* Abase = A + (size_t)m0 * K;
  const __bf16* Wbase = W + (size_t)n0 * K;

  f32x4 acc[RW][4] = {};

  const int nk = K >> 5;
  stage2<T,BM>(Abase, Wbase, &lds[0][0][0], &lds[0][1][0], K, 0,  t);
  stage2<T,BM>(Abase, Wbase, &lds[1][0][0], &lds[1][1][0], K, 32, t);
  stage2<T,BM>(Abase, Wbase, &lds[2][0][0], &lds[2][1][0], K, 64, t);

  for (int kt = 0; kt < nk; ++kt) {
    const int cur = kt & 3;
    if (kt + 3 < nk) {
      const int nb = (kt + 3) & 3;
      stage2<T,BM>(Abase, Wbase, &lds[nb][0][0], &lds[nb][1][0], K, (kt+3)*32, t);
      asm volatile("s_waitcnt vmcnt(8)" ::: "memory");
    } else if (kt + 2 < nk) {
      asm volatile("s_waitcnt vmcnt(8)" ::: "memory");
    } else if (kt + 1 < nk) {
      asm volatile("s_waitcnt vmcnt(4)" ::: "memory");
    } else {
      asm volatile("s_waitcnt vmcnt(0)" ::: "memory");
    }
    __builtin_amdgcn_s_barrier();
    __builtin_amdgcn_sched_barrier(0);
    const __bf16* La = &lds[cur][0][0];
    const __bf16* Lb = &lds[cur][1][0];
    bf16x8 bfr[4];
#pragma unroll
    for (int j = 0; j < 4; ++j)
      bfr[j] = *(const bf16x8*)&Lb[(wn*64 + j*16 + fr) * 32 + slot];
    __builtin_amdgcn_s_setprio(1);
#pragma unroll
    for (int i = 0; i < RW; ++i) {
      bf16x8 af = *(const bf16x8*)&La[(wm*(RW*16) + i*16 + fr) * 32 + slot];
#pragma unroll
      for (int j = 0; j < 4; ++j)
        acc[i][j] = __builtin_amdgcn_mfma_f32_16x16x32_bf16(af, bfr[j], acc[i][j], 0, 0, 0);
    }
    __builtin_amdgcn_s_setprio(0);
    __builtin_amdgcn_sched_barrier(0);
    __builtin_amdgcn_s_barrier();
    __builtin_amdgcn_sched_barrier(0);
  }

  const int orow = m0 + wm*(RW*16) + c8 * 4;
  const int ocol = n0 + wn*64 + fr;
#pragma unroll
  for (int i = 0; i < RW; ++i)
#pragma unroll
    for (int j = 0; j < 4; ++j) {
      const int col = ocol + j * 16;
      const float bv = BIAS ? bias[col] : 0.0f;
#pragma unroll
      for (int rr = 0; rr < 4; ++rr) {
        float v = acc[i][j][rr] + bv;
        if (RELU) v = fmaxf(v, 0.0f);
        if (OUTBF16)
          ((__bf16*)Cv)[(size_t)(orow + i*16 + rr) * N + col] = (__bf16)v;
        else
          ((float*)Cv)[(size_t)(orow + i*16 + rr) * N + col] = v;
      }
    }
}

// ---------------------------------------------------------------------------
// 128x128 2-phase GEMM (fallback unembed only: fp32 W reg-staged).
// ---------------------------------------------------------------------------
template<bool WBF16, bool BIAS, bool RELU, bool OUTBF16>
__global__ __launch_bounds__(256) void gemm_fast(
    const __bf16* __restrict__ A, const void* __restrict__ Wv,
    const float* __restrict__ bias, void* __restrict__ Cv, int N, int K) {
  __shared__ __bf16 As[128][32];
  __shared__ __bf16 Bs[128][32];
  const int t = threadIdx.x;
  const int m0 = blockIdx.x * 128, n0 = blockIdx.y * 128;
  const int l = t & 63, w = t >> 6;
  const int wm = (w >> 1) * 64, wn = (w & 1) * 64;
  const int fr = l & 15, fk = (l >> 4) * 8;
  const int crow = l >> 2, ccol = (l & 3) * 8;
  const int wrow = t >> 1, wcol = (t & 1) * 16;

  const __bf16* Wb = (const __bf16*)Wv;
  const float*  Wf = (const float*)Wv;

  f32x4 acc[4][4] = {};

  for (int k0 = 0; k0 < K; k0 += 32) {
    float4 wf0, wf1, wf2, wf3;
    if (!WBF16) {
      const float* wp = Wf + (size_t)(n0 + wrow) * K + k0 + wcol;
      wf0 = *(const float4*)(wp);
      wf1 = *(const float4*)(wp + 4);
      wf2 = *(const float4*)(wp + 8);
      wf3 = *(const float4*)(wp + 12);
    }
    __syncthreads();
#pragma unroll
    for (int i = 0; i < 2; ++i) {
      const int c = 2 * w + i;
      gload16(A + (size_t)(m0 + c*16 + crow) * K + k0 + ccol, (__bf16*)As + c*512);
      if (WBF16)
        gload16(Wb + (size_t)(n0 + c*16 + crow) * K + k0 + ccol, (__bf16*)Bs + c*512);
    }
    if (!WBF16) {
      *(bf16x8*)&Bs[wrow][wcol]     = to_bf8(wf0, wf1);
      *(bf16x8*)&Bs[wrow][wcol + 8] = to_bf8(wf2, wf3);
    }
    __syncthreads();
    bf16x8 af[4], bf[4];
#pragma unroll
    for (int i = 0; i < 4; ++i) af[i] = *(const bf16x8*)&As[wm + i*16 + fr][fk];
#pragma unroll
    for (int j = 0; j < 4; ++j) bf[j] = *(const bf16x8*)&Bs[wn + j*16 + fr][fk];
#pragma unroll
    for (int i = 0; i < 4; ++i)
#pragma unroll
      for (int j = 0; j < 4; ++j)
        acc[i][j] = __builtin_amdgcn_mfma_f32_16x16x32_bf16(af[i], bf[j], acc[i][j], 0, 0, 0);
  }

  const int orow = m0 + wm + (l >> 4) * 4;
  const int ocol = n0 + wn + fr;
#pragma unroll
  for (int i = 0; i < 4; ++i)
#pragma unroll
    for (int j = 0; j < 4; ++j) {
      const int col = ocol + j * 16;
      const float bv = BIAS ? bias[col] : 0.0f;
#pragma unroll
      for (int r = 0; r < 4; ++r) {
        float v = acc[i][j][r] + bv;
        if (RELU) v = fmaxf(v, 0.0f);
        if (OUTBF16)
          ((__bf16*)Cv)[(size_t)(orow + i*16 + r) * N + col] = (__bf16)v;
        else
          ((float*)Cv)[(size_t)(orow + i*16 + r) * N + col] = v;
      }
    }
}

// ---------------------------------------------------------------------------
// x = LN(y + x) * s + b ; also emit bf16 copy xb.
// ---------------------------------------------------------------------------
__global__ __launch_bounds__(256) void ln_res_kernel(
    const float* __restrict__ y, float* __restrict__ x, __bf16* __restrict__ xb,
    const float* __restrict__ sc, const float* __restrict__ bs) {
  __shared__ float red[8];
  int row = blockIdx.x, t = threadIdx.x;
  const float4* y4 = (const float4*)(y + (size_t)row * EE);
  float4* x4 = (float4*)(x + (size_t)row * EE);
  float4 a = y4[t], c = x4[t];
  float v0 = a.x + c.x, v1 = a.y + c.y, v2 = a.z + c.z, v3 = a.w + c.w;
  float s = v0 + v1 + v2 + v3;
  float q = v0*v0 + v1*v1 + v2*v2 + v3*v3;
#pragma unroll
  for (int off = 32; off; off >>= 1) {
    s += __shfl_xor(s, off);
    q += __shfl_xor(q, off);
  }
  int w = t >> 6;
  if ((t & 63) == 0) { red[w] = s; red[4 + w] = q; }
  __syncthreads();
  s = red[0] + red[1] + red[2] + red[3];
  q = red[4] + red[5] + red[6] + red[7];
  float mean = s * (1.0f / EE);
  float var  = q * (1.0f / EE) - mean * mean;
  float r = 1.0f / sqrtf(var + 1e-6f);
  float4 ss = ((const float4*)sc)[t];
  float4 bb = ((const float4*)bs)[t];
  float4 o;
  o.x = (v0 - mean) * r * ss.x + bb.x;
  o.y = (v1 - mean) * r * ss.y + bb.y;
  o.z = (v2 - mean) * r * ss.z + bb.z;
  o.w = (v3 - mean) * r * ss.w + bb.w;
  x4[t] = o;
  bf16x4 ob4;
  ob4[0] = (__bf16)o.x; ob4[1] = (__bf16)o.y; ob4[2] = (__bf16)o.z; ob4[3] = (__bf16)o.w;
  *(bf16x4*)(xb + (size_t)row * EE + t * 4) = ob4;
}

// ---------------------------------------------------------------------------
// MFMA flash attention (unchanged, verified).
// ---------------------------------------------------------------------------
__global__ __launch_bounds__(256) void attn_mfma(
    const __bf16* __restrict__ qkv, const int* __restrict__ ls,
    __bf16* __restrict__ out) {
  const int qt = 15 - blockIdx.x;
  const int h = blockIdx.y, b = blockIdx.z;
  __shared__ f32x4 lds4[2304];             // 36864 B
  char* lds = (char*)lds4;
  __bf16* Ks = (__bf16*)lds;               // [64][72]
  __bf16* Vs = (__bf16*)(lds + 9216);      // [64][72] transposed (d-major)
  __shared__ int redmin[4];
  const int t = threadIdx.x, w = t >> 6, l = t & 63;
  __bf16* Pq = (__bf16*)(lds + 18432 + w * 4608);  // [32][72] per wave
  const int r = l & 31, hi = l >> 5;
  const int qb = qt * 128, qw = qb + w * 32, qg = qw + r;
  const int Lq = ls[b*SS + qg];

  {
    int mn = Lq;
#pragma unroll
    for (int off = 1; off < 64; off <<= 1) mn = min(mn, __shfl_xor(mn, off));
    if (l == 0) redmin[w] = mn;
  }

  bf16x8 qf[4];
  {
    const __bf16* qrow = qkv + (size_t)(b*SS + qg) * 3*EE + EE + h*DD + 8*hi;
#pragma unroll
    for (int ds = 0; ds < 4; ++ds) qf[ds] = *(const bf16x8*)(qrow + 16*ds);
  }
  __syncthreads();
  const int ktmin = min(min(redmin[0], redmin[1]), min(redmin[2], redmin[3])) >> 6;
  const int ktmax = 2*qt + 1;

  f32x16 oacc[2] = {};
  float m_r = NEG_HUGE, lsum = 0.0f;

  for (int kt = ktmin; kt <= ktmax; ++kt) {
    __syncthreads();
    {
      const int kr = t >> 2, c0 = (t & 3) * 16;
      const __bf16* kg = qkv + (size_t)(b*SS + kt*64 + kr) * 3*EE + h*DD + c0;
      const __bf16* vg = kg + 2*EE;
      bf16x8 k0 = *(const bf16x8*)kg;
      bf16x8 k1 = *(const bf16x8*)(kg + 8);
      bf16x8 v0 = *(const bf16x8*)vg;
      bf16x8 v1 = *(const bf16x8*)(vg + 8);
      *(bf16x8*)&Ks[kr*72 + c0]     = k0;
      *(bf16x8*)&Ks[kr*72 + c0 + 8] = k1;
      const int vc = (kr + 8*(t & 3)) & 63;
#pragma unroll
      for (int j = 0; j < 8; ++j) {
        Vs[(c0 + j)*72 + vc]     = v0[j];
        Vs[(c0 + 8 + j)*72 + vc] = v1[j];
      }
    }
    __syncthreads();

    bool act0 = (kt*64)      <= (qw + 31);
    bool act1 = (kt*64 + 32) <= (qw + 31);
    if (!act0) continue;

    f32x16 st[2];
    st[0] = (f32x16){};
    st[1] = (f32x16){};
#pragma unroll
    for (int ds = 0; ds < 4; ++ds) {
      bf16x8 kf = *(const bf16x8*)&Ks[(r)*72 + 16*ds + 8*hi];
      st[0] = __builtin_amdgcn_mfma_f32_32x32x16_bf16(kf, qf[ds], st[0], 0, 0, 0);
    }
    if (act1) {
#pragma unroll
      for (int ds = 0; ds < 4; ++ds) {
        bf16x8 kf = *(const bf16x8*)&Ks[(32 + r)*72 + 16*ds + 8*hi];
        st[1] = __builtin_amdgcn_mfma_f32_32x32x16_bf16(kf, qf[ds], st[1], 0, 0, 0);
      }
    }

    float tmax = NEG_HUGE;
#pragma unroll
    for (int kt2 = 0; kt2 < 2; ++kt2) {
#pragma unroll
      for (int reg = 0; reg < 16; ++reg) {
        const int key = kt*64 + 32*kt2 + (reg & 3) + 8*(reg >> 2) + 4*hi;
        float s = (kt2 == 0 || act1) ? st[kt2][reg] * 0.125f : NEG_HUGE;
        const bool valid = (key >= Lq) && (key <= qg);
        s = valid ? s : NEG_HUGE;
        st[kt2][reg] = s;
        tmax = fmaxf(tmax, s);
      }
    }
    tmax = fmaxf(tmax, __shfl_xor(tmax, 32));
    const float m_new = fmaxf(m_r, tmax);
    const float alpha = __expf(m_r - m_new);
    m_r = m_new;

    float psum = 0.0f;
#pragma unroll
    for (int kt2 = 0; kt2 < 2; ++kt2) {
#pragma unroll
      for (int g2 = 0; g2 < 4; ++g2) {
        bf16x4 pk;
#pragma unroll
        for (int j = 0; j < 4; ++j) {
          float p = __expf(st[kt2][g2*4 + j] - m_new);
          psum += p;
          pk[j] = (__bf16)p;
        }
        *(bf16x4*)&Pq[r*72 + 32*kt2 + 8*g2 + 4*hi] = pk;
      }
    }
    psum += __shfl_xor(psum, 32);
    lsum = lsum * alpha + psum;
    oacc[0] *= alpha;
    oacc[1] *= alpha;

#pragma unroll
    for (int ks = 0; ks < 4; ++ks) {
      if (kt*64 + 16*ks > qw + 31) continue;
      bf16x8 pf = *(const bf16x8*)&Pq[r*72 + 16*ks + 8*hi];
#pragma unroll
      for (int mt = 0; mt < 2; ++mt) {
        const int d = 32*mt + r;
        const int vcol = (16*ks + 8*hi + 8*((d >> 4) & 3)) & 63;
        bf16x8 vf = *(const bf16x8*)&Vs[d*72 + vcol];
        oacc[mt] = __builtin_amdgcn_mfma_f32_32x32x16_bf16(vf, pf, oacc[mt], 0, 0, 0);
      }
    }
  }

  __syncthreads();
  float* Ot = (float*)(lds + w * 8448);        // [64][33] f32 per wave
  const float rinv = 1.0f / lsum;
#pragma unroll
  for (int mt = 0; mt < 2; ++mt)
#pragma unroll
    for (int reg = 0; reg < 16; ++reg) {
      const int d = 32*mt + (reg & 3) + 8*(reg >> 2) + 4*hi;
      Ot[d*33 + r] = oacc[mt][reg] * rinv;
    }
  __syncthreads();
  const int qr0 = l >> 4, dc = (l & 15) * 4;
#pragma unroll
  for (int it = 0; it < 8; ++it) {
    const int qr = qr0 + 4*it;
    bf16x4 ov;
    ov[0] = (__bf16)Ot[(dc+0)*33 + qr];
    ov[1] = (__bf16)Ot[(dc+1)*33 + qr];
    ov[2] = (__bf16)Ot[(dc+2)*33 + qr];
    ov[3] = (__bf16)Ot[(dc+3)*33 + qr];
    *(bf16x4*)(out + (size_t)(b*SS + qw + qr) * EE + h*DD + dc) = ov;
  }
}

// ---------------------------------------------------------------------------
extern "C" void kernel_launch(void* const* d_in, const int* in_sizes, int n_in,
                              void* d_out, int out_size, void* d_ws, size_t ws_size,
                              hipStream_t stream) {
  const int*   tokens     = (const int*)  d_in[0];
  const float* word_embed = (const float*)d_in[1];
  const float* pos_embed  = (const float*)d_in[2];
  const float* unembed_b  = (const float*)d_in[3];
  const float* kqv_w      = (const float*)d_in[4];
  const float* wo_w       = (const float*)d_in[5];
  const float* up_w       = (const float*)d_in[6];
  const float* up_b       = (const float*)d_in[7];
  const float* down_w     = (const float*)d_in[8];
  const float* down_b     = (const float*)d_in[9];
  const float* ln1_s      = (const float*)d_in[10];
  const float* ln1_b      = (const float*)d_in[11];
  const float* ln2_s      = (const float*)d_in[12];
  const float* ln2_b      = (const float*)d_in[13];
  float* logits = (float*)d_out;

  // d_out (524 MB) scratch map (all dead before the final GEMM writes logits):
  char* ob = (char*)d_out;
  __bf16* qkv  = (__bf16*)ob;                          // 24 MB
  __bf16* t0   = (__bf16*)(ob +  24ull*1024*1024);     //  8 MB
  __bf16* hbuf = (__bf16*)(ob +  32ull*1024*1024);     // 32 MB
  float*  ybuf = (float*) (ob +  64ull*1024*1024);     // 16 MB
  __bf16* wcvt = (__bf16*)(ob +  80ull*1024*1024);     // 50.4 MB bf16 weights
  float*  x    = (float*) (ob + 131ull*1024*1024);     // 16 MB fp32 residual
  __bf16* kqvb  = wcvt;
  __bf16* wob   = kqvb + (size_t)LL*3*EE*EE;
  __bf16* upb   = wob  + (size_t)LL*EE*EE;
  __bf16* downb = upb  + (size_t)LL*FF*EE;
  // ws: only what must survive the final GEMM (which overwrites all of d_out).
  int*    ls   = (int*)d_ws;                            // 64 KB
  __bf16* xb   = (__bf16*)((char*)d_ws + 65536);        // 8 MB
  __bf16* webf = (__bf16*)((char*)d_ws + 65536 + 8ull*1024*1024);
  const bool bigws = ws_size >= (size_t)(65536 + 8ull*1024*1024 + (size_t)VV*EE*2);

  lastart_scan<<<BB, 1024, 0, stream>>>(tokens, ls);
  embed_kernel<<<BS, 256, 0, stream>>>(tokens, ls, word_embed, pos_embed, x, xb);

  // weight pre-conversion (fp32 -> bf16)
  cvt_bf16_kernel<<<LL*3*EE*EE/2048, 256, 0, stream>>>(kqv_w,  kqvb,  LL*3*EE*EE);
  cvt_bf16_kernel<<<LL*EE*EE/2048,   256, 0, stream>>>(wo_w,   wob,   LL*EE*EE);
  cvt_bf16_kernel<<<LL*FF*EE/2048,   256, 0, stream>>>(up_w,   upb,   LL*FF*EE);
  cvt_bf16_kernel<<<LL*EE*FF/2048,   256, 0, stream>>>(down_w, downb, LL*EE*FF);
  if (bigws)
    cvt_bf16_kernel<<<VV*EE/2048, 256, 0, stream>>>(word_embed, webf, VV*EE);

  for (int l = 0; l < LL; ++l) {
    gemm_8ph<false,false,true><<<(BS/256)*(3*EE/256), 512, 0, stream>>>(
        xb, kqvb + (size_t)l*3*EE*EE, nullptr, qkv, 3*EE, EE, BS/256);
    attn_mfma<<<dim3(16, HH, BB), 256, 0, stream>>>(qkv, ls, t0);
    gemm_deep<4,2,2,false,false,false><<<(BS/128)*(EE/128), 256, 0, stream>>>(
        t0, wob + (size_t)l*EE*EE, nullptr, ybuf, EE, EE, BS/128);
    ln_res_kernel<<<BS, 256, 0, stream>>>(ybuf, x, xb, ln1_s + l*EE, ln1_b + l*EE);
    gemm_8ph<true,true,true><<<(BS/256)*(FF/256), 512, 0, stream>>>(
        xb, upb + (size_t)l*FF*EE, up_b + (size_t)l*FF, hbuf, FF, EE, BS/256);
    gemm_deep<4,2,2,true,false,false><<<(BS/128)*(EE/128), 256, 0, stream>>>(
        hbuf, downb + (size_t)l*EE*FF, down_b + (size_t)l*EE, ybuf, EE, FF, BS/128);
    ln_res_kernel<<<BS, 256, 0, stream>>>(ybuf, x, xb, ln2_s + l*EE, ln2_b + l*EE);
  }

  if (bigws)
    gemm_8ph<true,false,false><<<(BS/256)*(VV/256), 512, 0, stream>>>(
        xb, webf, unembed_b, logits, VV, EE, BS/256);
  else
    gemm_fast<false,true,false,false><<<dim3(BS/128, VV/128), 256, 0, stream>>>(
        xb, word_embed, unembed_b, logits, VV, EE);
}

// Round 8
// 915.160 us; speedup vs baseline: 15.1752x; 1.0741x over previous
//
#include <hip/hip_runtime.h>
#include <hip/hip_bf16.h>

#define BB 2
#define SS 2048
#define EE 1024
#define HH 16
#define DD 64
#define FF 4096
#define VV 32000
#define LL 2
#define BS (BB*SS)

#define NEG_HUGE (-3.402823466e+38f)

typedef __attribute__((ext_vector_type(4)))  float  f32x4;
typedef __attribute__((ext_vector_type(16))) float  f32x16;
typedef __attribute__((ext_vector_type(8)))  __bf16 bf16x8;
typedef __attribute__((ext_vector_type(4)))  __bf16 bf16x4;

__device__ inline bf16x8 to_bf8(float4 a, float4 b) {
  bf16x8 r;
  r[0] = (__bf16)a.x; r[1] = (__bf16)a.y; r[2] = (__bf16)a.z; r[3] = (__bf16)a.w;
  r[4] = (__bf16)b.x; r[5] = (__bf16)b.y; r[6] = (__bf16)b.z; r[7] = (__bf16)b.w;
  return r;
}

typedef const unsigned int __attribute__((address_space(1)))* gptr_t;
typedef unsigned int __attribute__((address_space(3)))* lptr_t;
__device__ inline void gload16(const void* g, void* l) {
  __builtin_amdgcn_global_load_lds((gptr_t)g, (lptr_t)l, 16, 0, 0);
}

// ---------------------------------------------------------------------------
// last_start via parallel max-scan (1 block per batch row).
// ---------------------------------------------------------------------------
__global__ __launch_bounds__(1024) void lastart_scan(
    const int* __restrict__ tokens, int* __restrict__ ls) {
  __shared__ int buf[SS];
  const int b = blockIdx.x, t = threadIdx.x;
#pragma unroll
  for (int j = 0; j < 2; ++j) {
    int i = t + j * 1024;
    buf[i] = (i > 0 && tokens[b*SS + i] == 1) ? i : 0;
  }
  __syncthreads();
  for (int off = 1; off < SS; off <<= 1) {
    int i0 = t, i1 = t + 1024;
    int v0 = (i0 >= off) ? max(buf[i0], buf[i0 - off]) : buf[i0];
    int v1 = (i1 >= off) ? max(buf[i1], buf[i1 - off]) : buf[i1];
    __syncthreads();
    buf[i0] = v0; buf[i1] = v1;
    __syncthreads();
  }
#pragma unroll
  for (int j = 0; j < 2; ++j) {
    int i = t + j * 1024;
    ls[b*SS + i] = buf[i];
  }
}

__global__ __launch_bounds__(256) void embed_kernel(
    const int* __restrict__ tokens, const int* __restrict__ ls,
    const float* __restrict__ we, const float* __restrict__ pe,
    float* __restrict__ x, __bf16* __restrict__ xb) {
  int row = blockIdx.x;
  int s = row & (SS - 1);
  int tok = tokens[row];
  int rp = s - ls[row];
  const float4* w4 = (const float4*)(we + (size_t)tok * EE);
  const float4* p4 = (const float4*)(pe + (size_t)rp * EE);
  float4 a = w4[threadIdx.x];
  float4 b = p4[threadIdx.x];
  float4 o; o.x = a.x + b.x; o.y = a.y + b.y; o.z = a.z + b.z; o.w = a.w + b.w;
  ((float4*)(x + (size_t)row * EE))[threadIdx.x] = o;
  bf16x4 ob4;
  ob4[0] = (__bf16)o.x; ob4[1] = (__bf16)o.y; ob4[2] = (__bf16)o.z; ob4[3] = (__bf16)o.w;
  *(bf16x4*)(xb + (size_t)row * EE + threadIdx.x * 4) = ob4;
}

// ---------------------------------------------------------------------------
__global__ __launch_bounds__(256) void cvt_bf16_kernel(
    const float* __restrict__ src, __bf16* __restrict__ dst, int n) {
  int i = (blockIdx.x * 256 + threadIdx.x) * 8;
  if (i + 8 > n) return;
  float4 a = *(const float4*)(src + i);
  float4 b = *(const float4*)(src + i + 4);
  *(bf16x8*)(dst + i) = to_bf8(a, b);
}

// ---------------------------------------------------------------------------
// Persistent 8-phase 256x256 GEMM. C = A[M,K] @ W[N,K]^T (+bias)(+relu).
// Requires K == 1024 (16 K-tiles of BK=64). NMT = M-tiles walked per block;
// each block owns ONE N-strip (W panel L2-resident) and runs a seamless
// global iteration g = tile*16 + kt: staging crosses tile boundaries so the
// pipeline never drains. Epilogue stores fire between iterations; the next
// counted vmcnt(8) also drains them (in-order vmcnt retire -> correct).
// LDS = [c][A|B][khalf] regions of 256x32 (128 KB); swizzle 0-conflict (r5+).
// Schedule per K-tile (4 phases, r7-verified ledger):
//   P1: read A0/B0 frags | stage A-h1(g+1) | bar | 16 MFMA | bar
//   P2: read A0 hi-frags | stage B-h1(g+1) | bar | 16 MFMA | vmcnt(8) bar
//   P3: read A1/B1 frags | stage A-h0(g+2) | bar | 16 MFMA | bar
//   P4: read A1 hi-frags | stage B-h0(g+2) | bar | 16 MFMA | vmcnt(8) bar
// ---------------------------------------------------------------------------
__device__ inline void stage_half8(const __bf16* __restrict__ base,
                                   __bf16* region, int K, int kofs,
                                   int col8, int srow, int sdst) {
#pragma unroll
  for (int p = 0; p < 2; ++p)
    gload16(base + (size_t)(p * 128 + srow) * K + kofs + col8,
            region + p * 4096 + sdst);
}

template<int NMT, bool BIAS, bool RELU, bool OUTBF16>
__global__ __launch_bounds__(512, 2) void gemm_8ph(
    const __bf16* __restrict__ A, const __bf16* __restrict__ W,
    const float* __restrict__ bias, void* __restrict__ Cv,
    int N, int K, int nmg) {
  __shared__ __bf16 lds[8][8192];              // [c*4 + ab*2 + kh][256*32]
  const int t = threadIdx.x, l = t & 63, w = t >> 6;
  const int nwg = gridDim.x, orig = blockIdx.x;
  const int q = nwg >> 3, r = nwg & 7, xcd = orig & 7, pos = orig >> 3;
  const int wgid = (xcd < r ? xcd*(q+1) : r*(q+1) + (xcd-r)*q) + pos;
  const int mgrp = wgid % nmg, n0 = (wgid / nmg) * 256;
  const int wm = w >> 2, wn = w & 3;
  const int fr = l & 15, c8 = l >> 4;
  const int swz = (c8 ^ ((fr >> 1) & 3)) * 8;  // thread-constant (i-indep)
  const int roA = (wm*128 + fr) * 32 + swz;    // hoisted read offsets (elems)
  const int roB = (wn*64  + fr) * 32 + swz;
  const int col8 = ((t & 3) ^ ((t >> 3) & 3)) * 8;  // stage: inv-swz source
  const int srow = t >> 2;
  const int sdst = (t >> 6) * 512;             // wave-uniform dest base

  const __bf16* Wb = W + (size_t)n0 * K;       // N-strip fixed per block
  const int ng = NMT * 16;                     // global K-iterations

  float bv[4];
#pragma unroll
  for (int j = 0; j < 4; ++j) bv[j] = BIAS ? bias[n0 + wn*64 + fr + j*16] : 0.0f;

  f32x4 acc[8][4] = {};

  // A base for global iteration g' (tile = g'>>4, kofs = (g'&15)*64)
#define ABASE(g2) (A + (size_t)(mgrp*NMT + ((g2) >> 4)) * 256 * K)
#define KOFS(g2)  (((g2) & 15) * 64)

  // prologue: h0/h1 of g=0, h0 of g=1
  stage_half8(ABASE(0), &lds[0][0], K, 0,  col8, srow, sdst);
  stage_half8(Wb,       &lds[2][0], K, 0,  col8, srow, sdst);
  stage_half8(ABASE(0), &lds[1][0], K, 32, col8, srow, sdst);
  stage_half8(Wb,       &lds[3][0], K, 32, col8, srow, sdst);
  stage_half8(ABASE(1), &lds[4][0], K, 64, col8, srow, sdst);
  stage_half8(Wb,       &lds[6][0], K, 64, col8, srow, sdst);
  asm volatile("s_waitcnt vmcnt(4)" ::: "memory");
  __builtin_amdgcn_s_barrier();
  __builtin_amdgcn_sched_barrier(0);

  for (int g = 0; g < ng; ++g) {
    const int c = g & 1;
    const int rA = c*4, rB = c*4 + 2;
    bf16x8 afr[4], bfr[4];
    // ---- P1: kh0 lo ----
#pragma unroll
    for (int j = 0; j < 4; ++j) bfr[j] = *(const bf16x8*)&lds[rB][roB + j*512];
#pragma unroll
    for (int i = 0; i < 4; ++i) afr[i] = *(const bf16x8*)&lds[rA][roA + i*512];
    if (g + 1 < ng)
      stage_half8(ABASE(g+1), &lds[(c^1)*4 + 1][0], K, KOFS(g+1) + 32, col8, srow, sdst);
    __builtin_amdgcn_s_barrier();
    __builtin_amdgcn_sched_barrier(0);
    __builtin_amdgcn_s_setprio(1);
#pragma unroll
    for (int i = 0; i < 4; ++i)
#pragma unroll
      for (int j = 0; j < 4; ++j)
        acc[i][j] = __builtin_amdgcn_mfma_f32_16x16x32_bf16(afr[i], bfr[j], acc[i][j], 0, 0, 0);
    __builtin_amdgcn_s_setprio(0);
    __builtin_amdgcn_sched_barrier(0);
    __builtin_amdgcn_s_barrier();
    __builtin_amdgcn_sched_barrier(0);
    // ---- P2: kh0 hi ----
#pragma unroll
    for (int i = 0; i < 4; ++i) afr[i] = *(const bf16x8*)&lds[rA][roA + (i+4)*512];
    if (g + 1 < ng)
      stage_half8(Wb, &lds[(c^1)*4 + 3][0], K, KOFS(g+1) + 32, col8, srow, sdst);
    __builtin_amdgcn_s_barrier();
    __builtin_amdgcn_sched_barrier(0);
    __builtin_amdgcn_s_setprio(1);
#pragma unroll
    for (int i = 0; i < 4; ++i)
#pragma unroll
      for (int j = 0; j < 4; ++j)
        acc[i+4][j] = __builtin_amdgcn_mfma_f32_16x16x32_bf16(afr[i], bfr[j], acc[i+4][j], 0, 0, 0);
    __builtin_amdgcn_s_setprio(0);
    __builtin_amdgcn_sched_barrier(0);
    if (g < ng - 1) { asm volatile("s_waitcnt vmcnt(8)" ::: "memory"); }
    else            { asm volatile("s_waitcnt vmcnt(0)" ::: "memory"); }
    __builtin_amdgcn_s_barrier();
    __builtin_amdgcn_sched_barrier(0);
    // ---- P3: kh1 lo ----
#pragma unroll
    for (int j = 0; j < 4; ++j) bfr[j] = *(const bf16x8*)&lds[rB + 1][roB + j*512];
#pragma unroll
    for (int i = 0; i < 4; ++i) afr[i] = *(const bf16x8*)&lds[rA + 1][roA + i*512];
    if (g + 2 < ng)
      stage_half8(ABASE(g+2), &lds[c*4][0], K, KOFS(g+2), col8, srow, sdst);
    __builtin_amdgcn_s_barrier();
    __builtin_amdgcn_sched_barrier(0);
    __builtin_amdgcn_s_setprio(1);
#pragma unroll
    for (int i = 0; i < 4; ++i)
#pragma unroll
      for (int j = 0; j < 4; ++j)
        acc[i][j] = __builtin_amdgcn_mfma_f32_16x16x32_bf16(afr[i], bfr[j], acc[i][j], 0, 0, 0);
    __builtin_amdgcn_s_setprio(0);
    __builtin_amdgcn_sched_barrier(0);
    __builtin_amdgcn_s_barrier();
    __builtin_amdgcn_sched_barrier(0);
    // ---- P4: kh1 hi ----
#pragma unroll
    for (int i = 0; i < 4; ++i) afr[i] = *(const bf16x8*)&lds[rA + 1][roA + (i+4)*512];
    if (g + 2 < ng)
      stage_half8(Wb, &lds[c*4 + 2][0], K, KOFS(g+2), col8, srow, sdst);
    __builtin_amdgcn_s_barrier();
    __builtin_amdgcn_sched_barrier(0);
    __builtin_amdgcn_s_setprio(1);
#pragma unroll
    for (int i = 0; i < 4; ++i)
#pragma unroll
      for (int j = 0; j < 4; ++j)
        acc[i+4][j] = __builtin_amdgcn_mfma_f32_16x16x32_bf16(afr[i], bfr[j], acc[i+4][j], 0, 0, 0);
    __builtin_amdgcn_s_setprio(0);
    __builtin_amdgcn_sched_barrier(0);
    if (g < ng - 2)       { asm volatile("s_waitcnt vmcnt(8)" ::: "memory"); }
    else if (g == ng - 2) { asm volatile("s_waitcnt vmcnt(4)" ::: "memory"); }
    __builtin_amdgcn_s_barrier();
    __builtin_amdgcn_sched_barrier(0);
    // ---- per-tile epilogue (regs only; no LDS/barrier interaction) ----
    if ((g & 15) == 15) {
      const int orow = (mgrp*NMT + (g >> 4)) * 256 + wm*128 + c8 * 4;
      const int ocol = n0 + wn*64 + fr;
#pragma unroll
      for (int i = 0; i < 8; ++i)
#pragma unroll
        for (int j = 0; j < 4; ++j) {
#pragma unroll
          for (int rr = 0; rr < 4; ++rr) {
            float v = acc[i][j][rr] + bv[j];
            if (RELU) v = fmaxf(v, 0.0f);
            if (OUTBF16)
              ((__bf16*)Cv)[(size_t)(orow + i*16 + rr) * N + ocol + j*16] = (__bf16)v;
            else
              ((float*)Cv)[(size_t)(orow + i*16 + rr) * N + ocol + j*16] = v;
          }
          acc[i][j] = (f32x4){};
        }
    }
  }
#undef ABASE
#undef KOFS
}

// ---------------------------------------------------------------------------
// Deep-prefetch 128x128 GEMM (round-6 verified; wo/down shapes).
// ---------------------------------------------------------------------------
template<int T, int BM>
__device__ inline void stage2(const __bf16* __restrict__ Ab,
                              const __bf16* __restrict__ Wb,
                              __bf16* la, __bf16* lb, int K, int k0, int t) {
  const int col8 = (t & 3) ^ ((t >> 3) & 3);
  const int cofs = k0 + col8 * 8;
  const int wbase = (t >> 6) * 512;
#pragma unroll
  for (int p = 0; p < (BM * 32) / (T * 8); ++p) {
    const int row = p * (T >> 2) + (t >> 2);
    gload16(Ab + (size_t)row * K + cofs, la + p * T * 8 + wbase);
    gload16(Wb + (size_t)row * K + cofs, lb + p * T * 8 + wbase);
  }
}

template<int RW, int WM, int WN, bool BIAS, bool RELU, bool OUTBF16>
__global__ __launch_bounds__(WM*WN*64, 2) void gemm_deep(
    const __bf16* __restrict__ A, const __bf16* __restrict__ W,
    const float* __restrict__ bias, void* __restrict__ Cv,
    int N, int K, int nbx) {
  constexpr int T  = WM * WN * 64;
  constexpr int BM = WM * RW * 16;
  __shared__ __bf16 lds[4][2][BM * 32];
  const int t = threadIdx.x, l = t & 63, w = t >> 6;
  const int nwg = gridDim.x, orig = blockIdx.x;
  const int q = nwg >> 3, r = nwg & 7, xcd = orig & 7, pos = orig >> 3;
  const int wgid = (xcd < r ? xcd*(q+1) : r*(q+1) + (xcd-r)*q) + pos;
  const int m0 = (wgid % nbx) * BM, n0 = (wgid / nbx) * BM;
  const int wm = w / WN, wn = w % WN;
  const int fr = l & 15, c8 = l >> 4;
  const int slot = (c8 ^ ((fr >> 1) & 3)) * 8;

  const __bf16* Abase = A + (size_t)m0 * K;
  const __bf16* Wbase = W + (size_t)n0 * K;

  f32x4 acc[RW][4] = {};

  const int nk = K >> 5;
  stage2<T,BM>(Abase, Wbase, &lds[0][0][0], &lds[0][1][0], K, 0,  t);
  stage2<T,BM>(Abase, Wbase, &lds[1][0][0], &lds[1][1][0], K, 32, t);
  stage2<T,BM>(Abase, Wbase, &lds[2][0][0], &lds[2][1][0], K, 64, t);

  for (int kt = 0; kt < nk; ++kt) {
    const int cur = kt & 3;
    if (kt + 3 < nk) {
      const int nb = (kt + 3) & 3;
      stage2<T,BM>(Abase, Wbase, &lds[nb][0][0], &lds[nb][1][0], K, (kt+3)*32, t);
      asm volatile("s_waitcnt vmcnt(8)" ::: "memory");
    } else if (kt + 2 < nk) {
      asm volatile("s_waitcnt vmcnt(8)" ::: "memory");
    } else if (kt + 1 < nk) {
      asm volatile("s_waitcnt vmcnt(4)" ::: "memory");
    } else {
      asm volatile("s_waitcnt vmcnt(0)" ::: "memory");
    }
    __builtin_amdgcn_s_barrier();
    __builtin_amdgcn_sched_barrier(0);
    const __bf16* La = &lds[cur][0][0];
    const __bf16* Lb = &lds[cur][1][0];
    bf16x8 bfr[4];
#pragma unroll
    for (int j = 0; j < 4; ++j)
      bfr[j] = *(const bf16x8*)&Lb[(wn*64 + j*16 + fr) * 32 + slot];
    __builtin_amdgcn_s_setprio(1);
#pragma unroll
    for (int i = 0; i < RW; ++i) {
      bf16x8 af = *(const bf16x8*)&La[(wm*(RW*16) + i*16 + fr) * 32 + slot];
#pragma unroll
      for (int j = 0; j < 4; ++j)
        acc[i][j] = __builtin_amdgcn_mfma_f32_16x16x32_bf16(af, bfr[j], acc[i][j], 0, 0, 0);
    }
    __builtin_amdgcn_s_setprio(0);
    __builtin_amdgcn_sched_barrier(0);
    __builtin_amdgcn_s_barrier();
    __builtin_amdgcn_sched_barrier(0);
  }

  const int orow = m0 + wm*(RW*16) + c8 * 4;
  const int ocol = n0 + wn*64 + fr;
#pragma unroll
  for (int i = 0; i < RW; ++i)
#pragma unroll
    for (int j = 0; j < 4; ++j) {
      const int col = ocol + j * 16;
      const float bv = BIAS ? bias[col] : 0.0f;
#pragma unroll
      for (int rr = 0; rr < 4; ++rr) {
        float v = acc[i][j][rr] + bv;
        if (RELU) v = fmaxf(v, 0.0f);
        if (OUTBF16)
          ((__bf16*)Cv)[(size_t)(orow + i*16 + rr) * N + col] = (__bf16)v;
        else
          ((float*)Cv)[(size_t)(orow + i*16 + rr) * N + col] = v;
      }
    }
}

// ---------------------------------------------------------------------------
// 128x128 2-phase GEMM (fallback unembed only: fp32 W reg-staged).
// ---------------------------------------------------------------------------
template<bool WBF16, bool BIAS, bool RELU, bool OUTBF16>
__global__ __launch_bounds__(256) void gemm_fast(
    const __bf16* __restrict__ A, const void* __restrict__ Wv,
    const float* __restrict__ bias, void* __restrict__ Cv, int N, int K) {
  __shared__ __bf16 As[128][32];
  __shared__ __bf16 Bs[128][32];
  const int t = threadIdx.x;
  const int m0 = blockIdx.x * 128, n0 = blockIdx.y * 128;
  const int l = t & 63, w = t >> 6;
  const int wm = (w >> 1) * 64, wn = (w & 1) * 64;
  const int fr = l & 15, fk = (l >> 4) * 8;
  const int crow = l >> 2, ccol = (l & 3) * 8;
  const int wrow = t >> 1, wcol = (t & 1) * 16;

  const __bf16* Wb = (const __bf16*)Wv;
  const float*  Wf = (const float*)Wv;

  f32x4 acc[4][4] = {};

  for (int k0 = 0; k0 < K; k0 += 32) {
    float4 wf0, wf1, wf2, wf3;
    if (!WBF16) {
      const float* wp = Wf + (size_t)(n0 + wrow) * K + k0 + wcol;
      wf0 = *(const float4*)(wp);
      wf1 = *(const float4*)(wp + 4);
      wf2 = *(const float4*)(wp + 8);
      wf3 = *(const float4*)(wp + 12);
    }
    __syncthreads();
#pragma unroll
    for (int i = 0; i < 2; ++i) {
      const int c = 2 * w + i;
      gload16(A + (size_t)(m0 + c*16 + crow) * K + k0 + ccol, (__bf16*)As + c*512);
      if (WBF16)
        gload16(Wb + (size_t)(n0 + c*16 + crow) * K + k0 + ccol, (__bf16*)Bs + c*512);
    }
    if (!WBF16) {
      *(bf16x8*)&Bs[wrow][wcol]     = to_bf8(wf0, wf1);
      *(bf16x8*)&Bs[wrow][wcol + 8] = to_bf8(wf2, wf3);
    }
    __syncthreads();
    bf16x8 af[4], bf[4];
#pragma unroll
    for (int i = 0; i < 4; ++i) af[i] = *(const bf16x8*)&As[wm + i*16 + fr][fk];
#pragma unroll
    for (int j = 0; j < 4; ++j) bf[j] = *(const bf16x8*)&Bs[wn + j*16 + fr][fk];
#pragma unroll
    for (int i = 0; i < 4; ++i)
#pragma unroll
      for (int j = 0; j < 4; ++j)
        acc[i][j] = __builtin_amdgcn_mfma_f32_16x16x32_bf16(af[i], bf[j], acc[i][j], 0, 0, 0);
  }

  const int orow = m0 + wm + (l >> 4) * 4;
  const int ocol = n0 + wn + fr;
#pragma unroll
  for (int i = 0; i < 4; ++i)
#pragma unroll
    for (int j = 0; j < 4; ++j) {
      const int col = ocol + j * 16;
      const float bv = BIAS ? bias[col] : 0.0f;
#pragma unroll
      for (int r = 0; r < 4; ++r) {
        float v = acc[i][j][r] + bv;
        if (RELU) v = fmaxf(v, 0.0f);
        if (OUTBF16)
          ((__bf16*)Cv)[(size_t)(orow + i*16 + r) * N + col] = (__bf16)v;
        else
          ((float*)Cv)[(size_t)(orow + i*16 + r) * N + col] = v;
      }
    }
}

// ---------------------------------------------------------------------------
// x = LN(y + x) * s + b ; also emit bf16 copy xb.
// ---------------------------------------------------------------------------
__global__ __launch_bounds__(256) void ln_res_kernel(
    const float* __restrict__ y, float* __restrict__ x, __bf16* __restrict__ xb,
    const float* __restrict__ sc, const float* __restrict__ bs) {
  __shared__ float red[8];
  int row = blockIdx.x, t = threadIdx.x;
  const float4* y4 = (const float4*)(y + (size_t)row * EE);
  float4* x4 = (float4*)(x + (size_t)row * EE);
  float4 a = y4[t], c = x4[t];
  float v0 = a.x + c.x, v1 = a.y + c.y, v2 = a.z + c.z, v3 = a.w + c.w;
  float s = v0 + v1 + v2 + v3;
  float q = v0*v0 + v1*v1 + v2*v2 + v3*v3;
#pragma unroll
  for (int off = 32; off; off >>= 1) {
    s += __shfl_xor(s, off);
    q += __shfl_xor(q, off);
  }
  int w = t >> 6;
  if ((t & 63) == 0) { red[w] = s; red[4 + w] = q; }
  __syncthreads();
  s = red[0] + red[1] + red[2] + red[3];
  q = red[4] + red[5] + red[6] + red[7];
  float mean = s * (1.0f / EE);
  float var  = q * (1.0f / EE) - mean * mean;
  float r = 1.0f / sqrtf(var + 1e-6f);
  float4 ss = ((const float4*)sc)[t];
  float4 bb = ((const float4*)bs)[t];
  float4 o;
  o.x = (v0 - mean) * r * ss.x + bb.x;
  o.y = (v1 - mean) * r * ss.y + bb.y;
  o.z = (v2 - mean) * r * ss.z + bb.z;
  o.w = (v3 - mean) * r * ss.w + bb.w;
  x4[t] = o;
  bf16x4 ob4;
  ob4[0] = (__bf16)o.x; ob4[1] = (__bf16)o.y; ob4[2] = (__bf16)o.z; ob4[3] = (__bf16)o.w;
  *(bf16x4*)(xb + (size_t)row * EE + t * 4) = ob4;
}

// ---------------------------------------------------------------------------
// MFMA flash attention (unchanged, verified).
// ---------------------------------------------------------------------------
__global__ __launch_bounds__(256) void attn_mfma(
    const __bf16* __restrict__ qkv, const int* __restrict__ ls,
    __bf16* __restrict__ out) {
  const int qt = 15 - blockIdx.x;
  const int h = blockIdx.y, b = blockIdx.z;
  __shared__ f32x4 lds4[2304];             // 36864 B
  char* lds = (char*)lds4;
  __bf16* Ks = (__bf16*)lds;               // [64][72]
  __bf16* Vs = (__bf16*)(lds + 9216);      // [64][72] transposed (d-major)
  __shared__ int redmin[4];
  const int t = threadIdx.x, w = t >> 6, l = t & 63;
  __bf16* Pq = (__bf16*)(lds + 18432 + w * 4608);  // [32][72] per wave
  const int r = l & 31, hi = l >> 5;
  const int qb = qt * 128, qw = qb + w * 32, qg = qw + r;
  const int Lq = ls[b*SS + qg];

  {
    int mn = Lq;
#pragma unroll
    for (int off = 1; off < 64; off <<= 1) mn = min(mn, __shfl_xor(mn, off));
    if (l == 0) redmin[w] = mn;
  }

  bf16x8 qf[4];
  {
    const __bf16* qrow = qkv + (size_t)(b*SS + qg) * 3*EE + EE + h*DD + 8*hi;
#pragma unroll
    for (int ds = 0; ds < 4; ++ds) qf[ds] = *(const bf16x8*)(qrow + 16*ds);
  }
  __syncthreads();
  const int ktmin = min(min(redmin[0], redmin[1]), min(redmin[2], redmin[3])) >> 6;
  const int ktmax = 2*qt + 1;

  f32x16 oacc[2] = {};
  float m_r = NEG_HUGE, lsum = 0.0f;

  for (int kt = ktmin; kt <= ktmax; ++kt) {
    __syncthreads();
    {
      const int kr = t >> 2, c0 = (t & 3) * 16;
      const __bf16* kg = qkv + (size_t)(b*SS + kt*64 + kr) * 3*EE + h*DD + c0;
      const __bf16* vg = kg + 2*EE;
      bf16x8 k0 = *(const bf16x8*)kg;
      bf16x8 k1 = *(const bf16x8*)(kg + 8);
      bf16x8 v0 = *(const bf16x8*)vg;
      bf16x8 v1 = *(const bf16x8*)(vg + 8);
      *(bf16x8*)&Ks[kr*72 + c0]     = k0;
      *(bf16x8*)&Ks[kr*72 + c0 + 8] = k1;
      const int vc = (kr + 8*(t & 3)) & 63;
#pragma unroll
      for (int j = 0; j < 8; ++j) {
        Vs[(c0 + j)*72 + vc]     = v0[j];
        Vs[(c0 + 8 + j)*72 + vc] = v1[j];
      }
    }
    __syncthreads();

    bool act0 = (kt*64)      <= (qw + 31);
    bool act1 = (kt*64 + 32) <= (qw + 31);
    if (!act0) continue;

    f32x16 st[2];
    st[0] = (f32x16){};
    st[1] = (f32x16){};
#pragma unroll
    for (int ds = 0; ds < 4; ++ds) {
      bf16x8 kf = *(const bf16x8*)&Ks[(r)*72 + 16*ds + 8*hi];
      st[0] = __builtin_amdgcn_mfma_f32_32x32x16_bf16(kf, qf[ds], st[0], 0, 0, 0);
    }
    if (act1) {
#pragma unroll
      for (int ds = 0; ds < 4; ++ds) {
        bf16x8 kf = *(const bf16x8*)&Ks[(32 + r)*72 + 16*ds + 8*hi];
        st[1] = __builtin_amdgcn_mfma_f32_32x32x16_bf16(kf, qf[ds], st[1], 0, 0, 0);
      }
    }

    float tmax = NEG_HUGE;
#pragma unroll
    for (int kt2 = 0; kt2 < 2; ++kt2) {
#pragma unroll
      for (int reg = 0; reg < 16; ++reg) {
        const int key = kt*64 + 32*kt2 + (reg & 3) + 8*(reg >> 2) + 4*hi;
        float s = (kt2 == 0 || act1) ? st[kt2][reg] * 0.125f : NEG_HUGE;
        const bool valid = (key >= Lq) && (key <= qg);
        s = valid ? s : NEG_HUGE;
        st[kt2][reg] = s;
        tmax = fmaxf(tmax, s);
      }
    }
    tmax = fmaxf(tmax, __shfl_xor(tmax, 32));
    const float m_new = fmaxf(m_r, tmax);
    const float alpha = __expf(m_r - m_new);
    m_r = m_new;

    float psum = 0.0f;
#pragma unroll
    for (int kt2 = 0; kt2 < 2; ++kt2) {
#pragma unroll
      for (int g2 = 0; g2 < 4; ++g2) {
        bf16x4 pk;
#pragma unroll
        for (int j = 0; j < 4; ++j) {
          float p = __expf(st[kt2][g2*4 + j] - m_new);
          psum += p;
          pk[j] = (__bf16)p;
        }
        *(bf16x4*)&Pq[r*72 + 32*kt2 + 8*g2 + 4*hi] = pk;
      }
    }
    psum += __shfl_xor(psum, 32);
    lsum = lsum * alpha + psum;
    oacc[0] *= alpha;
    oacc[1] *= alpha;

#pragma unroll
    for (int ks = 0; ks < 4; ++ks) {
      if (kt*64 + 16*ks > qw + 31) continue;
      bf16x8 pf = *(const bf16x8*)&Pq[r*72 + 16*ks + 8*hi];
#pragma unroll
      for (int mt = 0; mt < 2; ++mt) {
        const int d = 32*mt + r;
        const int vcol = (16*ks + 8*hi + 8*((d >> 4) & 3)) & 63;
        bf16x8 vf = *(const bf16x8*)&Vs[d*72 + vcol];
        oacc[mt] = __builtin_amdgcn_mfma_f32_32x32x16_bf16(vf, pf, oacc[mt], 0, 0, 0);
      }
    }
  }

  __syncthreads();
  float* Ot = (float*)(lds + w * 8448);        // [64][33] f32 per wave
  const float rinv = 1.0f / lsum;
#pragma unroll
  for (int mt = 0; mt < 2; ++mt)
#pragma unroll
    for (int reg = 0; reg < 16; ++reg) {
      const int d = 32*mt + (reg & 3) + 8*(reg >> 2) + 4*hi;
      Ot[d*33 + r] = oacc[mt][reg] * rinv;
    }
  __syncthreads();
  const int qr0 = l >> 4, dc = (l & 15) * 4;
#pragma unroll
  for (int it = 0; it < 8; ++it) {
    const int qr = qr0 + 4*it;
    bf16x4 ov;
    ov[0] = (__bf16)Ot[(dc+0)*33 + qr];
    ov[1] = (__bf16)Ot[(dc+1)*33 + qr];
    ov[2] = (__bf16)Ot[(dc+2)*33 + qr];
    ov[3] = (__bf16)Ot[(dc+3)*33 + qr];
    *(bf16x4*)(out + (size_t)(b*SS + qw + qr) * EE + h*DD + dc) = ov;
  }
}

// ---------------------------------------------------------------------------
extern "C" void kernel_launch(void* const* d_in, const int* in_sizes, int n_in,
                              void* d_out, int out_size, void* d_ws, size_t ws_size,
                              hipStream_t stream) {
  const int*   tokens     = (const int*)  d_in[0];
  const float* word_embed = (const float*)d_in[1];
  const float* pos_embed  = (const float*)d_in[2];
  const float* unembed_b  = (const float*)d_in[3];
  const float* kqv_w      = (const float*)d_in[4];
  const float* wo_w       = (const float*)d_in[5];
  const float* up_w       = (const float*)d_in[6];
  const float* up_b       = (const float*)d_in[7];
  const float* down_w     = (const float*)d_in[8];
  const float* down_b     = (const float*)d_in[9];
  const float* ln1_s      = (const float*)d_in[10];
  const float* ln1_b      = (const float*)d_in[11];
  const float* ln2_s      = (const float*)d_in[12];
  const float* ln2_b      = (const float*)d_in[13];
  float* logits = (float*)d_out;

  // d_out (524 MB) scratch map (all dead before the final GEMM writes logits):
  char* ob = (char*)d_out;
  __bf16* qkv  = (__bf16*)ob;                          // 24 MB
  __bf16* t0   = (__bf16*)(ob +  24ull*1024*1024);     //  8 MB
  __bf16* hbuf = (__bf16*)(ob +  32ull*1024*1024);     // 32 MB
  float*  ybuf = (float*) (ob +  64ull*1024*1024);     // 16 MB
  __bf16* wcvt = (__bf16*)(ob +  80ull*1024*1024);     // 50.4 MB bf16 weights
  float*  x    = (float*) (ob + 131ull*1024*1024);     // 16 MB fp32 residual
  __bf16* kqvb  = wcvt;
  __bf16* wob   = kqvb + (size_t)LL*3*EE*EE;
  __bf16* upb   = wob  + (size_t)LL*EE*EE;
  __bf16* downb = upb  + (size_t)LL*FF*EE;
  // ws: only what must survive the final GEMM (which overwrites all of d_out).
  int*    ls   = (int*)d_ws;                            // 64 KB
  __bf16* xb   = (__bf16*)((char*)d_ws + 65536);        // 8 MB
  __bf16* webf = (__bf16*)((char*)d_ws + 65536 + 8ull*1024*1024);
  const bool bigws = ws_size >= (size_t)(65536 + 8ull*1024*1024 + (size_t)VV*EE*2);

  lastart_scan<<<BB, 1024, 0, stream>>>(tokens, ls);
  embed_kernel<<<BS, 256, 0, stream>>>(tokens, ls, word_embed, pos_embed, x, xb);

  // weight pre-conversion (fp32 -> bf16)
  cvt_bf16_kernel<<<LL*3*EE*EE/2048, 256, 0, stream>>>(kqv_w,  kqvb,  LL*3*EE*EE);
  cvt_bf16_kernel<<<LL*EE*EE/2048,   256, 0, stream>>>(wo_w,   wob,   LL*EE*EE);
  cvt_bf16_kernel<<<LL*FF*EE/2048,   256, 0, stream>>>(up_w,   upb,   LL*FF*EE);
  cvt_bf16_kernel<<<LL*EE*FF/2048,   256, 0, stream>>>(down_w, downb, LL*EE*FF);
  if (bigws)
    cvt_bf16_kernel<<<VV*EE/2048, 256, 0, stream>>>(word_embed, webf, VV*EE);

  for (int l = 0; l < LL; ++l) {
    gemm_8ph<1,false,false,true><<<(BS/256)*(3*EE/256), 512, 0, stream>>>(
        xb, kqvb + (size_t)l*3*EE*EE, nullptr, qkv, 3*EE, EE, BS/256);
    attn_mfma<<<dim3(16, HH, BB), 256, 0, stream>>>(qkv, ls, t0);
    gemm_deep<4,2,2,false,false,false><<<(BS/128)*(EE/128), 256, 0, stream>>>(
        t0, wob + (size_t)l*EE*EE, nullptr, ybuf, EE, EE, BS/128);
    ln_res_kernel<<<BS, 256, 0, stream>>>(ybuf, x, xb, ln1_s + l*EE, ln1_b + l*EE);
    gemm_8ph<1,true,true,true><<<(BS/256)*(FF/256), 512, 0, stream>>>(
        xb, upb + (size_t)l*FF*EE, up_b + (size_t)l*FF, hbuf, FF, EE, BS/256);
    gemm_deep<4,2,2,true,false,false><<<(BS/128)*(EE/128), 256, 0, stream>>>(
        hbuf, downb + (size_t)l*EE*FF, down_b + (size_t)l*EE, ybuf, EE, FF, BS/128);
    ln_res_kernel<<<BS, 256, 0, stream>>>(ybuf, x, xb, ln2_s + l*EE, ln2_b + l*EE);
  }

  if (bigws) {
    // persistent: 125 N-strips x 2 M-groups of 8 tiles; W panel L2-resident.
    gemm_8ph<8,true,false,false><<<(VV/256)*2, 512, 0, stream>>>(
        xb, webf, unembed_b, logits, VV, EE, 2);
  } else {
    gemm_fast<false,true,false,false><<<dim3(BS/128, VV/128), 256, 0, stream>>>(
        xb, word_embed, unembed_b, logits, VV, EE);
  }
}

// Round 9
// 897.093 us; speedup vs baseline: 15.4808x; 1.0201x over previous
//
#include <hip/hip_runtime.h>
#include <hip/hip_bf16.h>

#define BB 2
#define SS 2048
#define EE 1024
#define HH 16
#define DD 64
#define FF 4096
#define VV 32000
#define LL 2
#define BS (BB*SS)

#define NEG_HUGE (-3.402823466e+38f)

typedef __attribute__((ext_vector_type(4)))  float  f32x4;
typedef __attribute__((ext_vector_type(16))) float  f32x16;
typedef __attribute__((ext_vector_type(8)))  __bf16 bf16x8;
typedef __attribute__((ext_vector_type(4)))  __bf16 bf16x4;

__device__ inline bf16x8 to_bf8(float4 a, float4 b) {
  bf16x8 r;
  r[0] = (__bf16)a.x; r[1] = (__bf16)a.y; r[2] = (__bf16)a.z; r[3] = (__bf16)a.w;
  r[4] = (__bf16)b.x; r[5] = (__bf16)b.y; r[6] = (__bf16)b.z; r[7] = (__bf16)b.w;
  return r;
}

typedef const unsigned int __attribute__((address_space(1)))* gptr_t;
typedef unsigned int __attribute__((address_space(3)))* lptr_t;
__device__ inline void gload16(const void* g, void* l) {
  __builtin_amdgcn_global_load_lds((gptr_t)g, (lptr_t)l, 16, 0, 0);
}

// ---------------------------------------------------------------------------
// last_start via parallel max-scan (1 block per batch row).
// ---------------------------------------------------------------------------
__global__ __launch_bounds__(1024) void lastart_scan(
    const int* __restrict__ tokens, int* __restrict__ ls) {
  __shared__ int buf[SS];
  const int b = blockIdx.x, t = threadIdx.x;
#pragma unroll
  for (int j = 0; j < 2; ++j) {
    int i = t + j * 1024;
    buf[i] = (i > 0 && tokens[b*SS + i] == 1) ? i : 0;
  }
  __syncthreads();
  for (int off = 1; off < SS; off <<= 1) {
    int i0 = t, i1 = t + 1024;
    int v0 = (i0 >= off) ? max(buf[i0], buf[i0 - off]) : buf[i0];
    int v1 = (i1 >= off) ? max(buf[i1], buf[i1 - off]) : buf[i1];
    __syncthreads();
    buf[i0] = v0; buf[i1] = v1;
    __syncthreads();
  }
#pragma unroll
  for (int j = 0; j < 2; ++j) {
    int i = t + j * 1024;
    ls[b*SS + i] = buf[i];
  }
}

__global__ __launch_bounds__(256) void embed_kernel(
    const int* __restrict__ tokens, const int* __restrict__ ls,
    const float* __restrict__ we, const float* __restrict__ pe,
    float* __restrict__ x, __bf16* __restrict__ xb) {
  int row = blockIdx.x;
  int s = row & (SS - 1);
  int tok = tokens[row];
  int rp = s - ls[row];
  const float4* w4 = (const float4*)(we + (size_t)tok * EE);
  const float4* p4 = (const float4*)(pe + (size_t)rp * EE);
  float4 a = w4[threadIdx.x];
  float4 b = p4[threadIdx.x];
  float4 o; o.x = a.x + b.x; o.y = a.y + b.y; o.z = a.z + b.z; o.w = a.w + b.w;
  ((float4*)(x + (size_t)row * EE))[threadIdx.x] = o;
  bf16x4 ob4;
  ob4[0] = (__bf16)o.x; ob4[1] = (__bf16)o.y; ob4[2] = (__bf16)o.z; ob4[3] = (__bf16)o.w;
  *(bf16x4*)(xb + (size_t)row * EE + threadIdx.x * 4) = ob4;
}

// ---------------------------------------------------------------------------
__global__ __launch_bounds__(256) void cvt_bf16_kernel(
    const float* __restrict__ src, __bf16* __restrict__ dst, int n) {
  int i = (blockIdx.x * 256 + threadIdx.x) * 8;
  if (i + 8 > n) return;
  float4 a = *(const float4*)(src + i);
  float4 b = *(const float4*)(src + i + 4);
  *(bf16x8*)(dst + i) = to_bf8(a, b);
}

// ---------------------------------------------------------------------------
// Persistent 8-phase 256x256 GEMM (r7/r8-verified ledger; sched_barrier pins
// removed this round — cross-phase hoists are bounded by the asm-"memory"
// vmcnt fences at P2/P4, which is exactly where data-landing is guaranteed).
// ---------------------------------------------------------------------------
__device__ inline void stage_half8(const __bf16* __restrict__ base,
                                   __bf16* region, int K, int kofs,
                                   int col8, int srow, int sdst) {
#pragma unroll
  for (int p = 0; p < 2; ++p)
    gload16(base + (size_t)(p * 128 + srow) * K + kofs + col8,
            region + p * 4096 + sdst);
}

template<int NMT, bool BIAS, bool RELU, bool OUTBF16>
__global__ __launch_bounds__(512, 2) void gemm_8ph(
    const __bf16* __restrict__ A, const __bf16* __restrict__ W,
    const float* __restrict__ bias, void* __restrict__ Cv,
    int N, int K, int nmg) {
  __shared__ __bf16 lds[8][8192];              // [c*4 + ab*2 + kh][256*32]
  const int t = threadIdx.x, l = t & 63, w = t >> 6;
  const int nwg = gridDim.x, orig = blockIdx.x;
  const int q = nwg >> 3, r = nwg & 7, xcd = orig & 7, pos = orig >> 3;
  const int wgid = (xcd < r ? xcd*(q+1) : r*(q+1) + (xcd-r)*q) + pos;
  const int mgrp = wgid % nmg, n0 = (wgid / nmg) * 256;
  const int wm = w >> 2, wn = w & 3;
  const int fr = l & 15, c8 = l >> 4;
  const int swz = (c8 ^ ((fr >> 1) & 3)) * 8;
  const int roA = (wm*128 + fr) * 32 + swz;
  const int roB = (wn*64  + fr) * 32 + swz;
  const int col8 = ((t & 3) ^ ((t >> 3) & 3)) * 8;
  const int srow = t >> 2;
  const int sdst = (t >> 6) * 512;

  const __bf16* Wb = W + (size_t)n0 * K;
  const int ng = NMT * 16;

  float bv[4];
#pragma unroll
  for (int j = 0; j < 4; ++j) bv[j] = BIAS ? bias[n0 + wn*64 + fr + j*16] : 0.0f;

  f32x4 acc[8][4] = {};

#define ABASE(g2) (A + (size_t)(mgrp*NMT + ((g2) >> 4)) * 256 * K)
#define KOFS(g2)  (((g2) & 15) * 64)

  stage_half8(ABASE(0), &lds[0][0], K, 0,  col8, srow, sdst);
  stage_half8(Wb,       &lds[2][0], K, 0,  col8, srow, sdst);
  stage_half8(ABASE(0), &lds[1][0], K, 32, col8, srow, sdst);
  stage_half8(Wb,       &lds[3][0], K, 32, col8, srow, sdst);
  stage_half8(ABASE(1), &lds[4][0], K, 64, col8, srow, sdst);
  stage_half8(Wb,       &lds[6][0], K, 64, col8, srow, sdst);
  asm volatile("s_waitcnt vmcnt(4)" ::: "memory");
  __builtin_amdgcn_s_barrier();

  for (int g = 0; g < ng; ++g) {
    const int c = g & 1;
    const int rA = c*4, rB = c*4 + 2;
    bf16x8 afr[4], bfr[4];
    // ---- P1: kh0 lo ----
#pragma unroll
    for (int j = 0; j < 4; ++j) bfr[j] = *(const bf16x8*)&lds[rB][roB + j*512];
#pragma unroll
    for (int i = 0; i < 4; ++i) afr[i] = *(const bf16x8*)&lds[rA][roA + i*512];
    if (g + 1 < ng)
      stage_half8(ABASE(g+1), &lds[(c^1)*4 + 1][0], K, KOFS(g+1) + 32, col8, srow, sdst);
    __builtin_amdgcn_s_barrier();
    __builtin_amdgcn_s_setprio(1);
#pragma unroll
    for (int i = 0; i < 4; ++i)
#pragma unroll
      for (int j = 0; j < 4; ++j)
        acc[i][j] = __builtin_amdgcn_mfma_f32_16x16x32_bf16(afr[i], bfr[j], acc[i][j], 0, 0, 0);
    __builtin_amdgcn_s_setprio(0);
    __builtin_amdgcn_s_barrier();
    // ---- P2: kh0 hi ----
#pragma unroll
    for (int i = 0; i < 4; ++i) afr[i] = *(const bf16x8*)&lds[rA][roA + (i+4)*512];
    if (g + 1 < ng)
      stage_half8(Wb, &lds[(c^1)*4 + 3][0], K, KOFS(g+1) + 32, col8, srow, sdst);
    __builtin_amdgcn_s_barrier();
    __builtin_amdgcn_s_setprio(1);
#pragma unroll
    for (int i = 0; i < 4; ++i)
#pragma unroll
      for (int j = 0; j < 4; ++j)
        acc[i+4][j] = __builtin_amdgcn_mfma_f32_16x16x32_bf16(afr[i], bfr[j], acc[i+4][j], 0, 0, 0);
    __builtin_amdgcn_s_setprio(0);
    if (g < ng - 1) { asm volatile("s_waitcnt vmcnt(8)" ::: "memory"); }
    else            { asm volatile("s_waitcnt vmcnt(0)" ::: "memory"); }
    __builtin_amdgcn_s_barrier();
    // ---- P3: kh1 lo ----
#pragma unroll
    for (int j = 0; j < 4; ++j) bfr[j] = *(const bf16x8*)&lds[rB + 1][roB + j*512];
#pragma unroll
    for (int i = 0; i < 4; ++i) afr[i] = *(const bf16x8*)&lds[rA + 1][roA + i*512];
    if (g + 2 < ng)
      stage_half8(ABASE(g+2), &lds[c*4][0], K, KOFS(g+2), col8, srow, sdst);
    __builtin_amdgcn_s_barrier();
    __builtin_amdgcn_s_setprio(1);
#pragma unroll
    for (int i = 0; i < 4; ++i)
#pragma unroll
      for (int j = 0; j < 4; ++j)
        acc[i][j] = __builtin_amdgcn_mfma_f32_16x16x32_bf16(afr[i], bfr[j], acc[i][j], 0, 0, 0);
    __builtin_amdgcn_s_setprio(0);
    __builtin_amdgcn_s_barrier();
    // ---- P4: kh1 hi ----
#pragma unroll
    for (int i = 0; i < 4; ++i) afr[i] = *(const bf16x8*)&lds[rA + 1][roA + (i+4)*512];
    if (g + 2 < ng)
      stage_half8(Wb, &lds[c*4 + 2][0], K, KOFS(g+2), col8, srow, sdst);
    __builtin_amdgcn_s_barrier();
    __builtin_amdgcn_s_setprio(1);
#pragma unroll
    for (int i = 0; i < 4; ++i)
#pragma unroll
      for (int j = 0; j < 4; ++j)
        acc[i+4][j] = __builtin_amdgcn_mfma_f32_16x16x32_bf16(afr[i], bfr[j], acc[i+4][j], 0, 0, 0);
    __builtin_amdgcn_s_setprio(0);
    if (g < ng - 2)       { asm volatile("s_waitcnt vmcnt(8)" ::: "memory"); }
    else if (g == ng - 2) { asm volatile("s_waitcnt vmcnt(4)" ::: "memory"); }
    __builtin_amdgcn_s_barrier();
    // ---- per-tile epilogue (regs only) ----
    if ((g & 15) == 15) {
      const int orow = (mgrp*NMT + (g >> 4)) * 256 + wm*128 + c8 * 4;
      const int ocol = n0 + wn*64 + fr;
#pragma unroll
      for (int i = 0; i < 8; ++i)
#pragma unroll
        for (int j = 0; j < 4; ++j) {
#pragma unroll
          for (int rr = 0; rr < 4; ++rr) {
            float v = acc[i][j][rr] + bv[j];
            if (RELU) v = fmaxf(v, 0.0f);
            if (OUTBF16)
              ((__bf16*)Cv)[(size_t)(orow + i*16 + rr) * N + ocol + j*16] = (__bf16)v;
            else
              ((float*)Cv)[(size_t)(orow + i*16 + rr) * N + ocol + j*16] = v;
          }
          acc[i][j] = (f32x4){};
        }
    }
  }
#undef ABASE
#undef KOFS
}

// ---------------------------------------------------------------------------
// Deep-prefetch 128x128 GEMM (r6-verified, untouched; wo/down shapes).
// ---------------------------------------------------------------------------
template<int T, int BM>
__device__ inline void stage2(const __bf16* __restrict__ Ab,
                              const __bf16* __restrict__ Wb,
                              __bf16* la, __bf16* lb, int K, int k0, int t) {
  const int col8 = (t & 3) ^ ((t >> 3) & 3);
  const int cofs = k0 + col8 * 8;
  const int wbase = (t >> 6) * 512;
#pragma unroll
  for (int p = 0; p < (BM * 32) / (T * 8); ++p) {
    const int row = p * (T >> 2) + (t >> 2);
    gload16(Ab + (size_t)row * K + cofs, la + p * T * 8 + wbase);
    gload16(Wb + (size_t)row * K + cofs, lb + p * T * 8 + wbase);
  }
}

template<int RW, int WM, int WN, bool BIAS, bool RELU, bool OUTBF16>
__global__ __launch_bounds__(WM*WN*64, 2) void gemm_deep(
    const __bf16* __restrict__ A, const __bf16* __restrict__ W,
    const float* __restrict__ bias, void* __restrict__ Cv,
    int N, int K, int nbx) {
  constexpr int T  = WM * WN * 64;
  constexpr int BM = WM * RW * 16;
  __shared__ __bf16 lds[4][2][BM * 32];
  const int t = threadIdx.x, l = t & 63, w = t >> 6;
  const int nwg = gridDim.x, orig = blockIdx.x;
  const int q = nwg >> 3, r = nwg & 7, xcd = orig & 7, pos = orig >> 3;
  const int wgid = (xcd < r ? xcd*(q+1) : r*(q+1) + (xcd-r)*q) + pos;
  const int m0 = (wgid % nbx) * BM, n0 = (wgid / nbx) * BM;
  const int wm = w / WN, wn = w % WN;
  const int fr = l & 15, c8 = l >> 4;
  const int slot = (c8 ^ ((fr >> 1) & 3)) * 8;

  const __bf16* Abase = A + (size_t)m0 * K;
  const __bf16* Wbase = W + (size_t)n0 * K;

  f32x4 acc[RW][4] = {};

  const int nk = K >> 5;
  stage2<T,BM>(Abase, Wbase, &lds[0][0][0], &lds[0][1][0], K, 0,  t);
  stage2<T,BM>(Abase, Wbase, &lds[1][0][0], &lds[1][1][0], K, 32, t);
  stage2<T,BM>(Abase, Wbase, &lds[2][0][0], &lds[2][1][0], K, 64, t);

  for (int kt = 0; kt < nk; ++kt) {
    const int cur = kt & 3;
    if (kt + 3 < nk) {
      const int nb = (kt + 3) & 3;
      stage2<T,BM>(Abase, Wbase, &lds[nb][0][0], &lds[nb][1][0], K, (kt+3)*32, t);
      asm volatile("s_waitcnt vmcnt(8)" ::: "memory");
    } else if (kt + 2 < nk) {
      asm volatile("s_waitcnt vmcnt(8)" ::: "memory");
    } else if (kt + 1 < nk) {
      asm volatile("s_waitcnt vmcnt(4)" ::: "memory");
    } else {
      asm volatile("s_waitcnt vmcnt(0)" ::: "memory");
    }
    __builtin_amdgcn_s_barrier();
    __builtin_amdgcn_sched_barrier(0);
    const __bf16* La = &lds[cur][0][0];
    const __bf16* Lb = &lds[cur][1][0];
    bf16x8 bfr[4];
#pragma unroll
    for (int j = 0; j < 4; ++j)
      bfr[j] = *(const bf16x8*)&Lb[(wn*64 + j*16 + fr) * 32 + slot];
    __builtin_amdgcn_s_setprio(1);
#pragma unroll
    for (int i = 0; i < RW; ++i) {
      bf16x8 af = *(const bf16x8*)&La[(wm*(RW*16) + i*16 + fr) * 32 + slot];
#pragma unroll
      for (int j = 0; j < 4; ++j)
        acc[i][j] = __builtin_amdgcn_mfma_f32_16x16x32_bf16(af, bfr[j], acc[i][j], 0, 0, 0);
    }
    __builtin_amdgcn_s_setprio(0);
    __builtin_amdgcn_sched_barrier(0);
    __builtin_amdgcn_s_barrier();
    __builtin_amdgcn_sched_barrier(0);
  }

  const int orow = m0 + wm*(RW*16) + c8 * 4;
  const int ocol = n0 + wn*64 + fr;
#pragma unroll
  for (int i = 0; i < RW; ++i)
#pragma unroll
    for (int j = 0; j < 4; ++j) {
      const int col = ocol + j * 16;
      const float bv = BIAS ? bias[col] : 0.0f;
#pragma unroll
      for (int rr = 0; rr < 4; ++rr) {
        float v = acc[i][j][rr] + bv;
        if (RELU) v = fmaxf(v, 0.0f);
        if (OUTBF16)
          ((__bf16*)Cv)[(size_t)(orow + i*16 + rr) * N + col] = (__bf16)v;
        else
          ((float*)Cv)[(size_t)(orow + i*16 + rr) * N + col] = v;
      }
    }
}

// ---------------------------------------------------------------------------
// 128x128 2-phase GEMM (fallback unembed only: fp32 W reg-staged).
// ---------------------------------------------------------------------------
template<bool WBF16, bool BIAS, bool RELU, bool OUTBF16>
__global__ __launch_bounds__(256) void gemm_fast(
    const __bf16* __restrict__ A, const void* __restrict__ Wv,
    const float* __restrict__ bias, void* __restrict__ Cv, int N, int K) {
  __shared__ __bf16 As[128][32];
  __shared__ __bf16 Bs[128][32];
  const int t = threadIdx.x;
  const int m0 = blockIdx.x * 128, n0 = blockIdx.y * 128;
  const int l = t & 63, w = t >> 6;
  const int wm = (w >> 1) * 64, wn = (w & 1) * 64;
  const int fr = l & 15, fk = (l >> 4) * 8;
  const int crow = l >> 2, ccol = (l & 3) * 8;
  const int wrow = t >> 1, wcol = (t & 1) * 16;

  const __bf16* Wb = (const __bf16*)Wv;
  const float*  Wf = (const float*)Wv;

  f32x4 acc[4][4] = {};

  for (int k0 = 0; k0 < K; k0 += 32) {
    float4 wf0, wf1, wf2, wf3;
    if (!WBF16) {
      const float* wp = Wf + (size_t)(n0 + wrow) * K + k0 + wcol;
      wf0 = *(const float4*)(wp);
      wf1 = *(const float4*)(wp + 4);
      wf2 = *(const float4*)(wp + 8);
      wf3 = *(const float4*)(wp + 12);
    }
    __syncthreads();
#pragma unroll
    for (int i = 0; i < 2; ++i) {
      const int c = 2 * w + i;
      gload16(A + (size_t)(m0 + c*16 + crow) * K + k0 + ccol, (__bf16*)As + c*512);
      if (WBF16)
        gload16(Wb + (size_t)(n0 + c*16 + crow) * K + k0 + ccol, (__bf16*)Bs + c*512);
    }
    if (!WBF16) {
      *(bf16x8*)&Bs[wrow][wcol]     = to_bf8(wf0, wf1);
      *(bf16x8*)&Bs[wrow][wcol + 8] = to_bf8(wf2, wf3);
    }
    __syncthreads();
    bf16x8 af[4], bf[4];
#pragma unroll
    for (int i = 0; i < 4; ++i) af[i] = *(const bf16x8*)&As[wm + i*16 + fr][fk];
#pragma unroll
    for (int j = 0; j < 4; ++j) bf[j] = *(const bf16x8*)&Bs[wn + j*16 + fr][fk];
#pragma unroll
    for (int i = 0; i < 4; ++i)
#pragma unroll
      for (int j = 0; j < 4; ++j)
        acc[i][j] = __builtin_amdgcn_mfma_f32_16x16x32_bf16(af[i], bf[j], acc[i][j], 0, 0, 0);
  }

  const int orow = m0 + wm + (l >> 4) * 4;
  const int ocol = n0 + wn + fr;
#pragma unroll
  for (int i = 0; i < 4; ++i)
#pragma unroll
    for (int j = 0; j < 4; ++j) {
      const int col = ocol + j * 16;
      const float bv = BIAS ? bias[col] : 0.0f;
#pragma unroll
      for (int r = 0; r < 4; ++r) {
        float v = acc[i][j][r] + bv;
        if (RELU) v = fmaxf(v, 0.0f);
        if (OUTBF16)
          ((__bf16*)Cv)[(size_t)(orow + i*16 + r) * N + col] = (__bf16)v;
        else
          ((float*)Cv)[(size_t)(orow + i*16 + r) * N + col] = v;
      }
    }
}

// ---------------------------------------------------------------------------
// x = LN(y + x) * s + b ; also emit bf16 copy xb.
// ---------------------------------------------------------------------------
__global__ __launch_bounds__(256) void ln_res_kernel(
    const float* __restrict__ y, float* __restrict__ x, __bf16* __restrict__ xb,
    const float* __restrict__ sc, const float* __restrict__ bs) {
  __shared__ float red[8];
  int row = blockIdx.x, t = threadIdx.x;
  const float4* y4 = (const float4*)(y + (size_t)row * EE);
  float4* x4 = (float4*)(x + (size_t)row * EE);
  float4 a = y4[t], c = x4[t];
  float v0 = a.x + c.x, v1 = a.y + c.y, v2 = a.z + c.z, v3 = a.w + c.w;
  float s = v0 + v1 + v2 + v3;
  float q = v0*v0 + v1*v1 + v2*v2 + v3*v3;
#pragma unroll
  for (int off = 32; off; off >>= 1) {
    s += __shfl_xor(s, off);
    q += __shfl_xor(q, off);
  }
  int w = t >> 6;
  if ((t & 63) == 0) { red[w] = s; red[4 + w] = q; }
  __syncthreads();
  s = red[0] + red[1] + red[2] + red[3];
  q = red[4] + red[5] + red[6] + red[7];
  float mean = s * (1.0f / EE);
  float var  = q * (1.0f / EE) - mean * mean;
  float r = 1.0f / sqrtf(var + 1e-6f);
  float4 ss = ((const float4*)sc)[t];
  float4 bb = ((const float4*)bs)[t];
  float4 o;
  o.x = (v0 - mean) * r * ss.x + bb.x;
  o.y = (v1 - mean) * r * ss.y + bb.y;
  o.z = (v2 - mean) * r * ss.z + bb.z;
  o.w = (v3 - mean) * r * ss.w + bb.w;
  x4[t] = o;
  bf16x4 ob4;
  ob4[0] = (__bf16)o.x; ob4[1] = (__bf16)o.y; ob4[2] = (__bf16)o.z; ob4[3] = (__bf16)o.w;
  *(bf16x4*)(xb + (size_t)row * EE + t * 4) = ob4;
}

// ---------------------------------------------------------------------------
// MFMA flash attention. 1-D grid 512; CU-pairing balance: blocks id and
// id+256 co-resident on a CU get complementary qt (work/CU = 34 kt const).
// ---------------------------------------------------------------------------
__global__ __launch_bounds__(256) void attn_mfma(
    const __bf16* __restrict__ qkv, const int* __restrict__ ls,
    __bf16* __restrict__ out) {
  const int id = blockIdx.x;
  const int z = id >> 8, rem = id & 255;
  const int qt0 = rem & 15, h = rem >> 4, b = z;
  const int qt = z ? (15 - qt0) : qt0;
  __shared__ f32x4 lds4[2304];             // 36864 B
  char* lds = (char*)lds4;
  __bf16* Ks = (__bf16*)lds;               // [64][72]
  __bf16* Vs = (__bf16*)(lds + 9216);      // [64][72] transposed (d-major)
  __shared__ int redmin[4];
  const int t = threadIdx.x, w = t >> 6, l = t & 63;
  __bf16* Pq = (__bf16*)(lds + 18432 + w * 4608);  // [32][72] per wave
  const int r = l & 31, hi = l >> 5;
  const int qb = qt * 128, qw = qb + w * 32, qg = qw + r;
  const int Lq = ls[b*SS + qg];

  {
    int mn = Lq;
#pragma unroll
    for (int off = 1; off < 64; off <<= 1) mn = min(mn, __shfl_xor(mn, off));
    if (l == 0) redmin[w] = mn;
  }

  bf16x8 qf[4];
  {
    const __bf16* qrow = qkv + (size_t)(b*SS + qg) * 3*EE + EE + h*DD + 8*hi;
#pragma unroll
    for (int ds = 0; ds < 4; ++ds) qf[ds] = *(const bf16x8*)(qrow + 16*ds);
  }
  __syncthreads();
  const int ktmin = min(min(redmin[0], redmin[1]), min(redmin[2], redmin[3])) >> 6;
  const int ktmax = 2*qt + 1;

  f32x16 oacc[2] = {};
  float m_r = NEG_HUGE, lsum = 0.0f;

  for (int kt = ktmin; kt <= ktmax; ++kt) {
    __syncthreads();
    {
      const int kr = t >> 2, c0 = (t & 3) * 16;
      const __bf16* kg = qkv + (size_t)(b*SS + kt*64 + kr) * 3*EE + h*DD + c0;
      const __bf16* vg = kg + 2*EE;
      bf16x8 k0 = *(const bf16x8*)kg;
      bf16x8 k1 = *(const bf16x8*)(kg + 8);
      bf16x8 v0 = *(const bf16x8*)vg;
      bf16x8 v1 = *(const bf16x8*)(vg + 8);
      *(bf16x8*)&Ks[kr*72 + c0]     = k0;
      *(bf16x8*)&Ks[kr*72 + c0 + 8] = k1;
      const int vc = (kr + 8*(t & 3)) & 63;
#pragma unroll
      for (int j = 0; j < 8; ++j) {
        Vs[(c0 + j)*72 + vc]     = v0[j];
        Vs[(c0 + 8 + j)*72 + vc] = v1[j];
      }
    }
    __syncthreads();

    bool act0 = (kt*64)      <= (qw + 31);
    bool act1 = (kt*64 + 32) <= (qw + 31);
    if (!act0) continue;

    f32x16 st[2];
    st[0] = (f32x16){};
    st[1] = (f32x16){};
#pragma unroll
    for (int ds = 0; ds < 4; ++ds) {
      bf16x8 kf = *(const bf16x8*)&Ks[(r)*72 + 16*ds + 8*hi];
      st[0] = __builtin_amdgcn_mfma_f32_32x32x16_bf16(kf, qf[ds], st[0], 0, 0, 0);
    }
    if (act1) {
#pragma unroll
      for (int ds = 0; ds < 4; ++ds) {
        bf16x8 kf = *(const bf16x8*)&Ks[(32 + r)*72 + 16*ds + 8*hi];
        st[1] = __builtin_amdgcn_mfma_f32_32x32x16_bf16(kf, qf[ds], st[1], 0, 0, 0);
      }
    }

    float tmax = NEG_HUGE;
#pragma unroll
    for (int kt2 = 0; kt2 < 2; ++kt2) {
#pragma unroll
      for (int reg = 0; reg < 16; ++reg) {
        const int key = kt*64 + 32*kt2 + (reg & 3) + 8*(reg >> 2) + 4*hi;
        float s = (kt2 == 0 || act1) ? st[kt2][reg] * 0.125f : NEG_HUGE;
        const bool valid = (key >= Lq) && (key <= qg);
        s = valid ? s : NEG_HUGE;
        st[kt2][reg] = s;
        tmax = fmaxf(tmax, s);
      }
    }
    tmax = fmaxf(tmax, __shfl_xor(tmax, 32));
    const float m_new = fmaxf(m_r, tmax);
    const float alpha = __expf(m_r - m_new);
    m_r = m_new;

    float psum = 0.0f;
#pragma unroll
    for (int kt2 = 0; kt2 < 2; ++kt2) {
#pragma unroll
      for (int g2 = 0; g2 < 4; ++g2) {
        bf16x4 pk;
#pragma unroll
        for (int j = 0; j < 4; ++j) {
          float p = __expf(st[kt2][g2*4 + j] - m_new);
          psum += p;
          pk[j] = (__bf16)p;
        }
        *(bf16x4*)&Pq[r*72 + 32*kt2 + 8*g2 + 4*hi] = pk;
      }
    }
    psum += __shfl_xor(psum, 32);
    lsum = lsum * alpha + psum;
    oacc[0] *= alpha;
    oacc[1] *= alpha;

#pragma unroll
    for (int ks = 0; ks < 4; ++ks) {
      if (kt*64 + 16*ks > qw + 31) continue;
      bf16x8 pf = *(const bf16x8*)&Pq[r*72 + 16*ks + 8*hi];
#pragma unroll
      for (int mt = 0; mt < 2; ++mt) {
        const int d = 32*mt + r;
        const int vcol = (16*ks + 8*hi + 8*((d >> 4) & 3)) & 63;
        bf16x8 vf = *(const bf16x8*)&Vs[d*72 + vcol];
        oacc[mt] = __builtin_amdgcn_mfma_f32_32x32x16_bf16(vf, pf, oacc[mt], 0, 0, 0);
      }
    }
  }

  __syncthreads();
  float* Ot = (float*)(lds + w * 8448);        // [64][33] f32 per wave
  const float rinv = 1.0f / lsum;
#pragma unroll
  for (int mt = 0; mt < 2; ++mt)
#pragma unroll
    for (int reg = 0; reg < 16; ++reg) {
      const int d = 32*mt + (reg & 3) + 8*(reg >> 2) + 4*hi;
      Ot[d*33 + r] = oacc[mt][reg] * rinv;
    }
  __syncthreads();
  const int qr0 = l >> 4, dc = (l & 15) * 4;
#pragma unroll
  for (int it = 0; it < 8; ++it) {
    const int qr = qr0 + 4*it;
    bf16x4 ov;
    ov[0] = (__bf16)Ot[(dc+0)*33 + qr];
    ov[1] = (__bf16)Ot[(dc+1)*33 + qr];
    ov[2] = (__bf16)Ot[(dc+2)*33 + qr];
    ov[3] = (__bf16)Ot[(dc+3)*33 + qr];
    *(bf16x4*)(out + (size_t)(b*SS + qw + qr) * EE + h*DD + dc) = ov;
  }
}

// ---------------------------------------------------------------------------
extern "C" void kernel_launch(void* const* d_in, const int* in_sizes, int n_in,
                              void* d_out, int out_size, void* d_ws, size_t ws_size,
                              hipStream_t stream) {
  const int*   tokens     = (const int*)  d_in[0];
  const float* word_embed = (const float*)d_in[1];
  const float* pos_embed  = (const float*)d_in[2];
  const float* unembed_b  = (const float*)d_in[3];
  const float* kqv_w      = (const float*)d_in[4];
  const float* wo_w       = (const float*)d_in[5];
  const float* up_w       = (const float*)d_in[6];
  const float* up_b       = (const float*)d_in[7];
  const float* down_w     = (const float*)d_in[8];
  const float* down_b     = (const float*)d_in[9];
  const float* ln1_s      = (const float*)d_in[10];
  const float* ln1_b      = (const float*)d_in[11];
  const float* ln2_s      = (const float*)d_in[12];
  const float* ln2_b      = (const float*)d_in[13];
  float* logits = (float*)d_out;

  // d_out (524 MB) scratch map (all dead before the final GEMM writes logits):
  char* ob = (char*)d_out;
  __bf16* qkv  = (__bf16*)ob;                          // 24 MB
  __bf16* t0   = (__bf16*)(ob +  24ull*1024*1024);     //  8 MB
  __bf16* hbuf = (__bf16*)(ob +  32ull*1024*1024);     // 32 MB
  float*  ybuf = (float*) (ob +  64ull*1024*1024);     // 16 MB
  __bf16* wcvt = (__bf16*)(ob +  80ull*1024*1024);     // 50.4 MB bf16 weights
  float*  x    = (float*) (ob + 131ull*1024*1024);     // 16 MB fp32 residual
  __bf16* kqvb  = wcvt;
  __bf16* wob   = kqvb + (size_t)LL*3*EE*EE;
  __bf16* upb   = wob  + (size_t)LL*EE*EE;
  __bf16* downb = upb  + (size_t)LL*FF*EE;
  // ws: only what must survive the final GEMM (which overwrites all of d_out).
  int*    ls   = (int*)d_ws;                            // 64 KB
  __bf16* xb   = (__bf16*)((char*)d_ws + 65536);        // 8 MB
  __bf16* webf = (__bf16*)((char*)d_ws + 65536 + 8ull*1024*1024);
  const bool bigws = ws_size >= (size_t)(65536 + 8ull*1024*1024 + (size_t)VV*EE*2);

  lastart_scan<<<BB, 1024, 0, stream>>>(tokens, ls);
  embed_kernel<<<BS, 256, 0, stream>>>(tokens, ls, word_embed, pos_embed, x, xb);

  // weight pre-conversion (fp32 -> bf16)
  cvt_bf16_kernel<<<LL*3*EE*EE/2048, 256, 0, stream>>>(kqv_w,  kqvb,  LL*3*EE*EE);
  cvt_bf16_kernel<<<LL*EE*EE/2048,   256, 0, stream>>>(wo_w,   wob,   LL*EE*EE);
  cvt_bf16_kernel<<<LL*FF*EE/2048,   256, 0, stream>>>(up_w,   upb,   LL*FF*EE);
  cvt_bf16_kernel<<<LL*EE*FF/2048,   256, 0, stream>>>(down_w, downb, LL*EE*FF);
  if (bigws)
    cvt_bf16_kernel<<<VV*EE/2048, 256, 0, stream>>>(word_embed, webf, VV*EE);

  for (int l = 0; l < LL; ++l) {
    gemm_8ph<1,false,false,true><<<(BS/256)*(3*EE/256), 512, 0, stream>>>(
        xb, kqvb + (size_t)l*3*EE*EE, nullptr, qkv, 3*EE, EE, BS/256);
    attn_mfma<<<512, 256, 0, stream>>>(qkv, ls, t0);
    gemm_deep<4,2,2,false,false,false><<<(BS/128)*(EE/128), 256, 0, stream>>>(
        t0, wob + (size_t)l*EE*EE, nullptr, ybuf, EE, EE, BS/128);
    ln_res_kernel<<<BS, 256, 0, stream>>>(ybuf, x, xb, ln1_s + l*EE, ln1_b + l*EE);
    gemm_8ph<1,true,true,true><<<(BS/256)*(FF/256), 512, 0, stream>>>(
        xb, upb + (size_t)l*FF*EE, up_b + (size_t)l*FF, hbuf, FF, EE, BS/256);
    gemm_deep<4,2,2,true,false,false><<<(BS/128)*(EE/128), 256, 0, stream>>>(
        hbuf, downb + (size_t)l*EE*FF, down_b + (size_t)l*EE, ybuf, EE, FF, BS/128);
    ln_res_kernel<<<BS, 256, 0, stream>>>(ybuf, x, xb, ln2_s + l*EE, ln2_b + l*EE);
  }

  if (bigws) {
    gemm_8ph<8,true,false,false><<<(VV/256)*2, 512, 0, stream>>>(
        xb, webf, unembed_b, logits, VV, EE, 2);
  } else {
    gemm_fast<false,true,false,false><<<dim3(BS/128, VV/128), 256, 0, stream>>>(
        xb, word_embed, unembed_b, logits, VV, EE);
  }
}